// Round 13
// baseline (1561.900 us; speedup 1.0000x reference)
//
#include <hip/hip_runtime.h>
#include <hip/hip_bf16.h>
#include <math.h>

#define N_NODES 50000
#define N_EDGES 800000
#define DH 32
#define IN_DIM 256
#define OUTC 160
#define LS 570400     // int(0.713 * 800000) -> exactly 570400
#define RANK0 (LS - 1)
#define DEG_CAP 160   // max in-degree supported (Poisson(16))
#define BCAP 65536    // boundary-candidate cap (expect ~1K)
#define MARG 3.0e-4   // relative margin around thd32 (~30x worst f32 error)

typedef unsigned long long u64;
#define SC_FX 1099511627776.0   // 2^40 fixed-point scale (f64 sums)
#define SC_32 4294967296.0      // 2^32 fixed-point scale (f32 softmax denom)

// ======== CSR build ========
__global__ void k_deg(const int* __restrict__ dst, unsigned* __restrict__ A){
  int e = blockIdx.x * 256 + threadIdx.x;
  if (e < N_EDGES) atomicAdd(&A[dst[e]], 1u);
}

__global__ __launch_bounds__(1024) void k_scan(unsigned* __restrict__ A){
  __shared__ unsigned ps[1024];
  int t = threadIdx.x;
  const int CH = (N_NODES + 1023) / 1024;
  int base = t * CH;
  unsigned s = 0;
  for (int i = 0; i < CH; i++){ int n = base + i; if (n < N_NODES) s += A[n]; }
  ps[t] = s;
  __syncthreads();
  for (int off = 1; off < 1024; off <<= 1){
    unsigned v = (t >= off) ? ps[t - off] : 0;
    __syncthreads();
    ps[t] += v;
    __syncthreads();
  }
  unsigned ex = (t == 0) ? 0 : ps[t - 1];
  for (int i = 0; i < CH; i++){
    int n = base + i;
    if (n < N_NODES){ unsigned dv = A[n]; A[n] = ex; ex += dv; }
  }
}

__global__ void k_fill(const int* __restrict__ dst, unsigned* __restrict__ A,
                       unsigned* __restrict__ eidx){
  int e = blockIdx.x * 256 + threadIdx.x;
  if (e < N_EDGES) eidx[atomicAdd(&A[dst[e]], 1u)] = (unsigned)e;
}
// post-fill: A[d] == offsets[d+1]; node d range = [d? A[d-1]:0, A[d])

__global__ void k_init(unsigned* __restrict__ sel32, unsigned* __restrict__ krem,
                       unsigned* __restrict__ cnt, unsigned* __restrict__ done,
                       unsigned* __restrict__ ccnt, unsigned* __restrict__ cbelow,
                       unsigned* __restrict__ bcnt, unsigned* __restrict__ cntless,
                       u64* __restrict__ gsums){
  int t = threadIdx.x;
  if (t < 4){ sel32[t]=0; krem[t]=RANK0; cnt[t]=0; ccnt[t]=0; cbelow[t]=0; cntless[t]=0; }
  if (t < 8) gsums[t] = 0;
  if (t == 0){ done[0] = 0; bcnt[0] = 0; }
}

// ======== single f32 GEMM: fcq[50000][384] = h @ [Wl^T | fc | fq] ========
#define BM 128
#define BK 16
__global__ __launch_bounds__(256) void k_gemm384(const float* __restrict__ A,
    const float* __restrict__ Wl, const float* __restrict__ fc,
    const float* __restrict__ fq, float* __restrict__ C){
  __shared__ float As[BK][BM + 4];
  __shared__ float Bs[BK][128 + 4];
  int tid = threadIdx.x;
  int m0 = blockIdx.x * BM;
  int n0 = blockIdx.y * 128;               // 0:ft(Wl^T)  128:fc  256:fq
  int ty = tid / 16, tx = tid % 16;
  float acc[8][8];
  #pragma unroll
  for (int i = 0; i < 8; i++)
    #pragma unroll
    for (int j = 0; j < 8; j++) acc[i][j] = 0.f;

  for (int k0 = 0; k0 < IN_DIM; k0 += BK){
    #pragma unroll
    for (int i = 0; i < 2; i++){
      int s = tid * 2 + i;
      int row = s >> 2, c4 = s & 3;
      int r = m0 + row;
      float4 v = make_float4(0.f, 0.f, 0.f, 0.f);
      if (r < N_NODES) v = *(const float4*)&A[(size_t)r * IN_DIM + k0 + c4 * 4];
      As[c4 * 4 + 0][row] = v.x; As[c4 * 4 + 1][row] = v.y;
      As[c4 * 4 + 2][row] = v.z; As[c4 * 4 + 3][row] = v.w;
    }
    if (n0 == 0){
      #pragma unroll
      for (int i = 0; i < 2; i++){
        int s = tid * 2 + i;
        int j = s >> 2, c4 = s & 3;        // Bs[k][j] = Wl[j][k0+k]
        float4 v = *(const float4*)&Wl[(size_t)j * IN_DIM + k0 + c4 * 4];
        Bs[c4 * 4 + 0][j] = v.x; Bs[c4 * 4 + 1][j] = v.y;
        Bs[c4 * 4 + 2][j] = v.z; Bs[c4 * 4 + 3][j] = v.w;
      }
    } else {
      const float* Bsrc = (n0 == 128) ? fc : fq;
      #pragma unroll
      for (int i = 0; i < 2; i++){
        int s = tid * 2 + i;
        int kr = s >> 5, c4 = s & 31;
        *(float4*)&Bs[kr][c4 * 4] = *(const float4*)&Bsrc[(size_t)(k0 + kr) * 128 + c4 * 4];
      }
    }
    __syncthreads();
    #pragma unroll
    for (int kk = 0; kk < BK; kk++){
      float4 a0 = *(const float4*)&As[kk][ty * 4];
      float4 a1 = *(const float4*)&As[kk][64 + ty * 4];
      float4 b0 = *(const float4*)&Bs[kk][tx * 4];
      float4 b1 = *(const float4*)&Bs[kk][64 + tx * 4];
      float av[8] = {a0.x, a0.y, a0.z, a0.w, a1.x, a1.y, a1.z, a1.w};
      float bv[8] = {b0.x, b0.y, b0.z, b0.w, b1.x, b1.y, b1.z, b1.w};
      #pragma unroll
      for (int i = 0; i < 8; i++)
        #pragma unroll
        for (int j = 0; j < 8; j++)
          acc[i][j] = fmaf(av[i], bv[j], acc[i][j]);
    }
    __syncthreads();
  }
  #pragma unroll
  for (int i = 0; i < 8; i++){
    int r = m0 + ((i < 4) ? (ty * 4 + i) : (64 + ty * 4 + (i - 4)));
    if (r >= N_NODES) continue;
    *(float4*)&C[(size_t)r * 384 + n0 + tx * 4]      = make_float4(acc[i][0], acc[i][1], acc[i][2], acc[i][3]);
    *(float4*)&C[(size_t)r * 384 + n0 + 64 + tx * 4] = make_float4(acc[i][4], acc[i][5], acc[i][6], acc[i][7]);
  }
}

// ======== f32 fused edge logits + softmax (wave per dst; deterministic) ========
__global__ __launch_bounds__(256) void k_softedge32(const float* __restrict__ fcq,
    const int* __restrict__ src, const unsigned* __restrict__ A,
    const unsigned* __restrict__ eidx, float* __restrict__ abuf){
  __shared__ float lds_a[4][DEG_CAP * 4];
  int d = blockIdx.x * 4 + (threadIdx.x >> 6);
  int t = threadIdx.x & 63;
  int wv = threadIdx.x >> 6;
  if (d >= N_NODES) return;
  unsigned k0 = d ? A[d - 1] : 0u, k1 = A[d];
  if (k0 == k1) return;
  float2 c = *(const float2*)&fcq[(size_t)d * 384 + 128 + t * 2];
  float m = -1.0e30f;
  int sn = src[eidx[k0]];
  float2 qn = *(const float2*)&fcq[(size_t)sn * 384 + 256 + t * 2];
  for (unsigned k = k0; k < k1; k++){
    float2 q = qn;
    if (k + 1 < k1){
      int s2 = src[eidx[k + 1]];
      qn = *(const float2*)&fcq[(size_t)s2 * 384 + 256 + t * 2];
    }
    float val = (q.x - c.x) * c.x + (q.y - c.y) * c.y;
    val += __shfl_xor(val, 1);
    val += __shfl_xor(val, 2);
    val += __shfl_xor(val, 4);
    val += __shfl_xor(val, 8);
    float a = (val > 0.f) ? val : expm1f(val);   // ELU
    m = fmaxf(m, a);
    if ((t & 15) == 0) lds_a[wv][(k - k0) * 4 + (t >> 4)] = a;
  }
  float mm = __shfl(m, (t & 3) * 16);
  unsigned nj = (k1 - k0) * 4;
  long long sfx = 0;
  for (unsigned jj = t; jj < nj; jj += 64){
    float ex = __expf(lds_a[wv][jj] - mm);       // jj%4 == t%4
    lds_a[wv][jj] = ex;
    sfx += (long long)llrintf(ex * (float)SC_32);
  }
  #pragma unroll
  for (int msk = 4; msk < 64; msk <<= 1) sfx += __shfl_xor(sfx, msk);
  float sd = (float)((double)sfx * (1.0 / SC_32));
  for (unsigned jj = t; jj < nj; jj += 64)
    abuf[(size_t)k0 * 4 + jj] = lds_a[wv][jj] / sd;
}

// ======== f32 radix select (u32 keys; attn > 0 -> bits ordered) ========
__global__ __launch_bounds__(256) void k_hp32(const float* __restrict__ attn,
    unsigned* __restrict__ sel32, unsigned* __restrict__ krem, unsigned* __restrict__ cnt,
    unsigned* __restrict__ hist, unsigned* __restrict__ done, unsigned maskHi, int shift){
  __shared__ unsigned lh[1024];
  __shared__ unsigned ticket;
  for (int j = threadIdx.x; j < 1024; j += 256) lh[j] = 0;
  __syncthreads();
  int i0 = blockIdx.x * 256 + threadIdx.x;
  int hh = i0 & 3;
  unsigned sel = sel32[hh] & maskHi;
  const int total = N_EDGES * 4;
  for (int i = i0; i < total; i += gridDim.x * 256){
    unsigned u = __float_as_uint(attn[i]);
    if ((u & maskHi) == sel)
      atomicAdd(&lh[hh * 256 + ((u >> shift) & 255u)], 1u);
  }
  __syncthreads();
  for (int j = threadIdx.x; j < 1024; j += 256)
    if (lh[j]) atomicAdd(&hist[j], lh[j]);
  __threadfence();
  if (threadIdx.x == 0) ticket = atomicAdd(done, 1u);
  __syncthreads();
  if (ticket == gridDim.x - 1){
    __threadfence();
    for (int j = threadIdx.x; j < 1024; j += 256){ lh[j] = hist[j]; hist[j] = 0; }
    __syncthreads();
    if (threadIdx.x < 4){
      int t = threadIdx.x;
      unsigned kr = krem[t], cum = 0, b = 0;
      for (; b < 256; b++){
        unsigned c2 = lh[t * 256 + b];
        if (kr < cum + c2) break;
        cum += c2;
      }
      sel32[t] |= b << shift;
      krem[t] = kr - cum;
      cnt[t] += cum;
    }
    if (threadIdx.x == 0) *done = 0;
  }
}

__global__ __launch_bounds__(256) void k_compact32(const float* __restrict__ attn,
    const unsigned* __restrict__ sel32, unsigned* __restrict__ ccnt,
    float* __restrict__ cand){
  __shared__ unsigned lcnt[4];
  __shared__ unsigned lbase[4];
  int t = threadIdx.x;
  if (t < 4) lcnt[t] = 0;
  __syncthreads();
  int i0 = blockIdx.x * 256 + t;
  int hh = i0 & 3;
  unsigned sel = sel32[hh] & 0xFFFF0000u;
  const int total = N_EDGES * 4;
  unsigned mc = 0;
  for (int i = i0; i < total; i += gridDim.x * 256){
    unsigned u = __float_as_uint(attn[i]);
    if ((u & 0xFFFF0000u) == sel) mc++;
  }
  unsigned my_local = mc ? atomicAdd(&lcnt[hh], mc) : 0u;
  __syncthreads();
  if (t < 4) lbase[t] = lcnt[t] ? atomicAdd(&ccnt[t], lcnt[t]) : 0u;
  __syncthreads();
  if (mc == 0) return;
  unsigned pos = lbase[hh] + my_local;
  float* cp = cand + (size_t)hh * N_EDGES;
  for (int i = i0; i < total; i += gridDim.x * 256){
    float v = attn[i];
    unsigned u = __float_as_uint(v);
    if ((u & 0xFFFF0000u) == sel) cp[pos++] = v;
  }
}

__global__ __launch_bounds__(256) void k_fin32(const float* __restrict__ cand,
    const unsigned* __restrict__ ccnt, unsigned* __restrict__ sel32,
    unsigned* __restrict__ krem, unsigned* __restrict__ cnt,
    unsigned* __restrict__ hist, unsigned* __restrict__ done, int shift){
  __shared__ unsigned lh[256];
  __shared__ unsigned ticket;
  int t = threadIdx.x;
  lh[t] = 0;
  __syncthreads();
  int h = blockIdx.x & 3;
  int bidx = blockIdx.x >> 2;
  int bph = gridDim.x >> 2;
  unsigned maskHi = ~((1u << (shift + 8)) - 1u);
  unsigned sel = sel32[h] & maskHi;
  unsigned n = ccnt[h];
  const float* cp = cand + (size_t)h * N_EDGES;
  for (unsigned i = bidx * 256 + t; i < n; i += bph * 256){
    unsigned u = __float_as_uint(cp[i]);
    if ((u & maskHi) == sel) atomicAdd(&lh[(u >> shift) & 255u], 1u);
  }
  __syncthreads();
  if (lh[t]) atomicAdd(&hist[h * 256 + t], lh[t]);
  __threadfence();
  if (t == 0) ticket = atomicAdd(done, 1u);
  __syncthreads();
  if (ticket == gridDim.x - 1){
    __threadfence();
    __shared__ unsigned fh[1024];
    for (int j = t; j < 1024; j += 256){ fh[j] = hist[j]; hist[j] = 0; }
    __syncthreads();
    if (t < 4){
      unsigned kr = krem[t], cum = 0, b = 0;
      for (; b < 256; b++){
        unsigned c2 = fh[t * 256 + b];
        if (kr < cum + c2) break;
        cum += c2;
      }
      sel32[t] |= b << shift;
      krem[t] = kr - cum;
      cnt[t] += cum;
    }
    if (t == 0) *done = 0;
  }
}

// ======== mark boundary candidates (attn32 in [thd*(1-MARG), thd*(1+MARG)]) ====
__global__ __launch_bounds__(256) void k_bmark(const float* __restrict__ attn,
    const unsigned* __restrict__ sel32, unsigned* __restrict__ cbelow,
    unsigned* __restrict__ bcnt, unsigned* __restrict__ blist){
  int t = threadIdx.x;
  int i0 = blockIdx.x * 256 + t;
  int hh = t & 3;
  double thd = (double)__uint_as_float(sel32[hh]);
  double lo = thd * (1.0 - MARG), hi = thd * (1.0 + MARG);
  unsigned below = 0;
  const int total = N_EDGES * 4;
  for (int i = i0; i < total; i += gridDim.x * 256){
    double v = (double)attn[i];
    if (v < lo) below++;
    else if (v <= hi){
      unsigned p = atomicAdd(bcnt, 1u);
      if (p < BCAP) blist[p] = (unsigned)i;
    }
  }
  #pragma unroll
  for (int m = 4; m < 64; m <<= 1) below += __shfl_xor(below, m);
  __shared__ unsigned sb[16];
  int wv = t >> 6;
  if ((t & 63) < 4) sb[wv * 4 + hh] = below;
  __syncthreads();
  if (t < 4){
    unsigned b = sb[t] + sb[4 + t] + sb[8 + t] + sb[12 + t];
    if (b) atomicAdd(&cbelow[t], b);
  }
}

// ======== exact f64 attn for boundary entries (recompute dst softmax from h) ====
// blist entries are ABUF indices: slot = csr_slot*4 + head.
__global__ __launch_bounds__(256) void k_brefine(const float* __restrict__ h,
    const float* __restrict__ fc, const float* __restrict__ fq,
    const int* __restrict__ src, const int* __restrict__ dst,
    const unsigned* __restrict__ A, const unsigned* __restrict__ eidx,
    const unsigned* __restrict__ blist, const unsigned* __restrict__ bcnt,
    double* __restrict__ bval){
  __shared__ double la[4][DEG_CAP];
  int wv = threadIdx.x >> 6;
  int l = threadIdx.x & 63;
  int j = l & 31;
  unsigned nb = *bcnt; if (nb > BCAP) nb = BCAP;
  for (unsigned idx = blockIdx.x * 4 + wv; idx < nb; idx += gridDim.x * 4){
    unsigned slot = blist[idx];
    unsigned kslot = slot >> 2;              // CSR position (NOT edge id)
    int hh = slot & 3;
    int d = dst[eidx[kslot]];                // dst node of that CSR slot
    unsigned k0 = d ? A[d - 1] : 0u, k1 = A[d];
    int col = hh * 32 + j;
    const float* hd = h + (size_t)d * 256;
    double c = 0.0;
    for (int i = 0; i < 256; i += 4){
      float4 hv = *(const float4*)&hd[i];
      c = fma((double)hv.x, (double)fc[(size_t)(i + 0) * 128 + col], c);
      c = fma((double)hv.y, (double)fc[(size_t)(i + 1) * 128 + col], c);
      c = fma((double)hv.z, (double)fc[(size_t)(i + 2) * 128 + col], c);
      c = fma((double)hv.w, (double)fc[(size_t)(i + 3) * 128 + col], c);
    }
    double m = -1.0e300, atgt = 0.0;
    for (unsigned k = k0; k < k1; k++){
      int s = src[eidx[k]];
      const float* hs = h + (size_t)s * 256;
      double q = 0.0;
      for (int i = 0; i < 256; i += 4){
        float4 hv = *(const float4*)&hs[i];
        q = fma((double)hv.x, (double)fq[(size_t)(i + 0) * 128 + col], q);
        q = fma((double)hv.y, (double)fq[(size_t)(i + 1) * 128 + col], q);
        q = fma((double)hv.z, (double)fq[(size_t)(i + 2) * 128 + col], q);
        q = fma((double)hv.w, (double)fq[(size_t)(i + 3) * 128 + col], q);
      }
      double p = (q - c) * c;
      p += __shfl_xor(p, 1);
      p += __shfl_xor(p, 2);
      p += __shfl_xor(p, 4);
      p += __shfl_xor(p, 8);
      p += __shfl_xor(p, 16);
      double a = (p > 0.0) ? p : expm1(p);
      m = fmax(m, a);
      if (l == 0) la[wv][k - k0] = a;
      if (k == kslot) atgt = a;              // this CSR slot is the target edge
    }
    long long sfx = 0;
    for (unsigned kk = l; kk < k1 - k0; kk += 64)
      sfx += llrint(exp(la[wv][kk] - m) * SC_FX);
    #pragma unroll
    for (int msk = 1; msk < 64; msk <<= 1) sfx += __shfl_xor(sfx, msk);
    double sd = (double)sfx * (1.0 / SC_FX);
    if (l == 0) bval[idx] = exp(atgt - m) / sd;
  }
}

// ======== exact f64 select among boundary (1 block per head) ========
__global__ __launch_bounds__(256) void k_bselect(const double* __restrict__ bval,
    const unsigned* __restrict__ blist, const unsigned* __restrict__ bcnt,
    const unsigned* __restrict__ cbelow, double* __restrict__ thd64,
    unsigned* __restrict__ cntless){
  __shared__ unsigned lh[256];
  __shared__ u64 s_sel;
  __shared__ unsigned s_kr, s_cnt;
  int hsel = blockIdx.x;
  int t = threadIdx.x;
  unsigned nb = *bcnt; if (nb > BCAP) nb = BCAP;
  if (t == 0){ s_sel = 0; s_kr = RANK0 - cbelow[hsel]; s_cnt = 0; }
  __syncthreads();
  for (int p = 0; p < 8; p++){
    int shift = 56 - 8 * p;
    u64 maskHi = (p == 0) ? 0ull : (~0ull) << (64 - 8 * p);
    lh[t] = 0;
    __syncthreads();
    u64 sel = s_sel;
    for (unsigned i = t; i < nb; i += 256){
      if ((int)(blist[i] & 3) == hsel){
        u64 u = (u64)__double_as_longlong(bval[i]);
        if ((u & maskHi) == sel) atomicAdd(&lh[(unsigned)((u >> shift) & 255u)], 1u);
      }
    }
    __syncthreads();
    if (t == 0){
      unsigned kr = s_kr, cum = 0, b = 0;
      for (; b < 256; b++){
        unsigned c2 = lh[b];
        if (kr < cum + c2) break;
        cum += c2;
      }
      s_sel |= ((u64)b) << shift;
      s_kr = kr - cum;
      s_cnt += cum;
    }
    __syncthreads();
  }
  if (t == 0){
    thd64[hsel] = __longlong_as_double((long long)s_sel);
    cntless[hsel] = cbelow[hsel] + s_cnt;
  }
}

// ======== sums for certain edges + a3 (boundary deferred to k_bfinal) ========
__global__ __launch_bounds__(256) void k_sums32(const float* __restrict__ attn,
    const unsigned* __restrict__ sel32, u64* __restrict__ gsums, float* __restrict__ a3){
  int t = threadIdx.x;
  int i0 = blockIdx.x * 256 + t;
  int hh = t & 3;
  double thd = (double)__uint_as_float(sel32[hh]);
  double lo = thd * (1.0 - MARG), hi = thd * (1.0 + MARG);
  double al = 0.0, ag = 0.0;
  const int total = N_EDGES * 4;
  for (int i = i0; i < total; i += gridDim.x * 256){
    float vf = attn[i];
    double v = (double)vf;
    if (v < lo){ al += v; a3[i] = 0.f; }
    else if (v > hi){ ag += v; a3[i] = vf; }
    else a3[i] = 0.f;                      // boundary: fixed by k_bfinal
  }
  long long ql = llrint(al * SC_FX);
  long long qg = llrint(ag * SC_FX);
  #pragma unroll
  for (int m = 4; m < 64; m <<= 1){
    ql += __shfl_xor(ql, m);
    qg += __shfl_xor(qg, m);
  }
  __shared__ long long sl[16], sg[16];
  int wv = t >> 6;
  if ((t & 63) < 4){ sl[wv * 4 + hh] = ql; sg[wv * 4 + hh] = qg; }
  __syncthreads();
  if (t < 4){
    long long a = sl[t] + sl[4 + t] + sl[8 + t] + sl[12 + t];
    long long b = sg[t] + sg[4 + t] + sg[8 + t] + sg[12 + t];
    if (a) atomicAdd(&gsums[t],     (u64)a);
    if (b) atomicAdd(&gsums[4 + t], (u64)b);
  }
}

// ======== finalize boundary entries: exact cut + sums + a3 ========
__global__ void k_bfinal(const unsigned* __restrict__ blist, const double* __restrict__ bval,
    const unsigned* __restrict__ bcnt, const double* __restrict__ thd64,
    u64* __restrict__ gsums, float* __restrict__ a3){
  unsigned nb = *bcnt; if (nb > BCAP) nb = BCAP;
  for (unsigned idx = blockIdx.x * 256 + threadIdx.x; idx < nb; idx += gridDim.x * 256){
    unsigned slot = blist[idx];
    int hh = slot & 3;
    double v = bval[idx];
    bool kept = (v >= thd64[hh]);
    a3[slot] = kept ? (float)v : 0.f;
    atomicAdd(&gsums[(kept ? 4 : 0) + hh], (u64)llrint(v * SC_FX));
  }
}

__global__ void k_ratio(const double* __restrict__ thd64, const unsigned* __restrict__ cntless,
                        const u64* __restrict__ gsums, double* __restrict__ trd){
  int t = threadIdx.x;
  if (t < 4){
    double sless = (double)(long long)gsums[t]     * (1.0 / SC_FX);
    double sge   = (double)(long long)gsums[4 + t] * (1.0 / SC_FX);
    double topk  = sless + (double)(LS - (int)cntless[t]) * thd64[t];
    trd[t] = thd64[t];
    trd[4 + t] = (sge + topk) / sge;
  }
}

// ======== CSR gather-scatter (wave per dst; ft at fcq cols 0-127) ========
__global__ __launch_bounds__(256) void k_scatter2(const float* __restrict__ fcq,
    const int* __restrict__ src, const unsigned* __restrict__ A,
    const unsigned* __restrict__ eidx, const float* __restrict__ a3,
    const double* __restrict__ trd, float* __restrict__ out){
  int d = blockIdx.x * 4 + (threadIdx.x >> 6);
  int t = threadIdx.x & 63;
  if (d >= N_NODES) return;
  int hh = t >> 4;
  double ratio = trd[4 + hh];
  unsigned k0 = d ? A[d - 1] : 0u, k1 = A[d];
  long long acc0 = 0, acc1 = 0;
  float wn = (k0 < k1) ? a3[(size_t)k0 * 4 + hh] : 0.f;
  unsigned en = (k0 < k1) ? eidx[k0] : 0u;
  for (unsigned k = k0; k < k1; k++){
    float w = wn;
    unsigned e = en;
    if (k + 1 < k1){ wn = a3[(size_t)(k + 1) * 4 + hh]; en = eidx[k + 1]; }
    if (__ballot(w != 0.f) == 0ull) continue;    // ~71% dropped
    if (w != 0.f){
      int s = src[e];
      float2 f = *(const float2*)&fcq[(size_t)s * 384 + t * 2];
      double a3r = (double)w * ratio;
      acc0 += llrint(a3r * (double)f.x * SC_FX);
      acc1 += llrint(a3r * (double)f.y * SC_FX);
    }
  }
  float* p = &out[(size_t)d * OUTC + t * 2];
  p[0] = (float)((double)acc0 * (1.0 / SC_FX));
  p[1] = (float)((double)acc1 * (1.0 / SC_FX));
}

// ======== head-mean (runs last; ft at fcq cols 0-127) ========
__global__ void k_mean(const float* __restrict__ fcq, float* __restrict__ out){
  int i = blockIdx.x * 256 + threadIdx.x;
  if (i >= N_NODES * DH) return;
  int n = i / DH, dd = i % DH;
  const float* p = fcq + (size_t)n * 384;
  out[(size_t)n * OUTC + 128 + dd] = 0.25f * (p[dd] + p[32 + dd] + p[64 + dd] + p[96 + dd]);
}

extern "C" void kernel_launch(void* const* d_in, const int* in_sizes, int n_in,
                              void* d_out, int out_size, void* d_ws, size_t ws_size,
                              hipStream_t stream){
  const float* h  = (const float*)d_in[0];
  const float* Wl = (const float*)d_in[1];
  const float* fc = (const float*)d_in[2];
  const float* fq = (const float*)d_in[3];
  const int* src  = (const int*)d_in[4];
  const int* dst  = (const int*)d_in[5];
  float* out = (float*)d_out;

  char* ws = (char*)d_ws;
  float*    fcq  = (float*)(ws);                   // 76,800,000
  unsigned* A    = (unsigned*)(ws + 76800000);     // 200,004 (pad to 77,000,064)
  unsigned* eidx = (unsigned*)(ws + 77000064);     // 3,200,000
  float*    a3   = (float*)(ws + 80200064);        // 12,800,000
  unsigned* hist = (unsigned*)(ws + 93000064);     // 4,096
  unsigned* sel32  = (unsigned*)(ws + 93004160);   // 16
  unsigned* krem   = (unsigned*)(ws + 93004176);   // 16
  unsigned* cnt    = (unsigned*)(ws + 93004192);   // 16
  unsigned* done   = (unsigned*)(ws + 93004208);   // 16
  unsigned* ccnt   = (unsigned*)(ws + 93004224);   // 16
  unsigned* cbelow = (unsigned*)(ws + 93004240);   // 16
  unsigned* bcnt   = (unsigned*)(ws + 93004256);   // 16
  unsigned* cntless= (unsigned*)(ws + 93004272);   // 16
  u64*      gsums  = (u64*)(ws + 93004288);        // 64
  double*   thd64  = (double*)(ws + 93004352);     // 32
  double*   trd    = (double*)(ws + 93004416);     // 64
  unsigned* blist  = (unsigned*)(ws + 93008896);   // 262,144 (BCAP*4)
  double*   bval   = (double*)(ws + 93271040);     // 524,288 (BCAP*8)

  // scratch inside d_out (32 MB): both fully dead before scatter2/mean write
  float* abuf = (float*)d_out;                     // 12.8 MB attn32
  float* cand = (float*)((char*)d_out + 12800000); // 12.8 MB select candidates

  hipMemsetAsync(A, 0, 200004, stream);
  hipMemsetAsync(hist, 0, 4096, stream);
  k_init<<<1, 64, 0, stream>>>(sel32, krem, cnt, done, ccnt, cbelow, bcnt, cntless, gsums);

  // CSR
  k_deg<<<(N_EDGES + 255) / 256, 256, 0, stream>>>(dst, A);
  k_scan<<<1, 1024, 0, stream>>>(A);
  k_fill<<<(N_EDGES + 255) / 256, 256, 0, stream>>>(dst, A, eidx);

  // single f32 GEMM -> [ft | c | q]
  dim3 gg((N_NODES + BM - 1) / BM, 3);
  k_gemm384<<<gg, 256, 0, stream>>>(h, Wl, fc, fq, fcq);

  // f32 fused edge logits + softmax
  k_softedge32<<<(N_NODES + 3) / 4, 256, 0, stream>>>(fcq, src, A, eidx, abuf);

  // exact f32 rank select: 2 global passes, compact, 2 finish passes
  k_hp32<<<1024, 256, 0, stream>>>(abuf, sel32, krem, cnt, hist, done, 0u, 24);
  k_hp32<<<1024, 256, 0, stream>>>(abuf, sel32, krem, cnt, hist, done, 0xFF000000u, 16);
  k_compact32<<<1024, 256, 0, stream>>>(abuf, sel32, ccnt, cand);
  k_fin32<<<256, 256, 0, stream>>>(cand, ccnt, sel32, krem, cnt, hist, done, 8);
  k_fin32<<<256, 256, 0, stream>>>(cand, ccnt, sel32, krem, cnt, hist, done, 0);

  // boundary: mark, refine in f64, exact f64 threshold
  k_bmark<<<1024, 256, 0, stream>>>(abuf, sel32, cbelow, bcnt, blist);
  k_brefine<<<512, 256, 0, stream>>>(h, fc, fq, src, dst, A, eidx, blist, bcnt, bval);
  k_bselect<<<4, 256, 0, stream>>>(bval, blist, bcnt, cbelow, thd64, cntless);

  // sums + a3 (+ boundary fixes) + ratio
  k_sums32<<<2048, 256, 0, stream>>>(abuf, sel32, gsums, a3);
  k_bfinal<<<64, 256, 0, stream>>>(blist, bval, bcnt, thd64, gsums, a3);
  k_ratio<<<1, 64, 0, stream>>>(thd64, cntless, gsums, trd);

  // output
  k_scatter2<<<(N_NODES + 3) / 4, 256, 0, stream>>>(fcq, src, A, eidx, a3, trd, out);
  k_mean<<<(N_NODES * DH + 255) / 256, 256, 0, stream>>>(fcq, out);
}

// Round 14
// 1268.564 us; speedup vs baseline: 1.2312x; 1.2312x over previous
//
#include <hip/hip_runtime.h>
#include <hip/hip_bf16.h>
#include <math.h>

#define N_NODES 50000
#define N_EDGES 800000
#define DH 32
#define IN_DIM 256
#define OUTC 160
#define LS 570400     // int(0.713 * 800000) -> exactly 570400
#define RANK0 (LS - 1)
#define DEG_CAP 160   // max in-degree supported (Poisson(16))
#define BCAP 65536    // boundary-candidate cap (expect ~1K)
#define MARG 3.0e-4   // relative margin around thd32 (~30x worst f32 error)

typedef unsigned long long u64;
#define SC_FX 1099511627776.0   // 2^40 fixed-point scale (f64 sums)
#define SC_32 4294967296.0      // 2^32 fixed-point scale (f32 softmax denom)

// ======== CSR build ========
__global__ void k_deg(const int* __restrict__ dst, unsigned* __restrict__ A){
  int e = blockIdx.x * 256 + threadIdx.x;
  if (e < N_EDGES) atomicAdd(&A[dst[e]], 1u);
}

__global__ __launch_bounds__(1024) void k_scan(unsigned* __restrict__ A){
  __shared__ unsigned ps[1024];
  int t = threadIdx.x;
  const int CH = (N_NODES + 1023) / 1024;
  int base = t * CH;
  unsigned s = 0;
  for (int i = 0; i < CH; i++){ int n = base + i; if (n < N_NODES) s += A[n]; }
  ps[t] = s;
  __syncthreads();
  for (int off = 1; off < 1024; off <<= 1){
    unsigned v = (t >= off) ? ps[t - off] : 0;
    __syncthreads();
    ps[t] += v;
    __syncthreads();
  }
  unsigned ex = (t == 0) ? 0 : ps[t - 1];
  for (int i = 0; i < CH; i++){
    int n = base + i;
    if (n < N_NODES){ unsigned dv = A[n]; A[n] = ex; ex += dv; }
  }
}

__global__ void k_fill(const int* __restrict__ dst, unsigned* __restrict__ A,
                       unsigned* __restrict__ eidx){
  int e = blockIdx.x * 256 + threadIdx.x;
  if (e < N_EDGES) eidx[atomicAdd(&A[dst[e]], 1u)] = (unsigned)e;
}
// post-fill: A[d] == offsets[d+1]; node d range = [d? A[d-1]:0, A[d])

__global__ void k_init(unsigned* __restrict__ sel32, unsigned* __restrict__ krem,
                       unsigned* __restrict__ cnt, unsigned* __restrict__ done,
                       unsigned* __restrict__ ccnt, unsigned* __restrict__ cbelow,
                       unsigned* __restrict__ bcnt, unsigned* __restrict__ cntless,
                       u64* __restrict__ gsums){
  int t = threadIdx.x;
  if (t < 4){ sel32[t]=0; krem[t]=RANK0; cnt[t]=0; ccnt[t]=0; cbelow[t]=0; cntless[t]=0; }
  if (t < 8) gsums[t] = 0;
  if (t == 0){ done[0] = 0; bcnt[0] = 0; }
}

// ======== transpose fc/fq to [col][k] for lane-contiguous f64 refine ========
__global__ void k_prept(const float* __restrict__ fc, const float* __restrict__ fq,
                        float* __restrict__ fcT, float* __restrict__ fqT){
  int i = blockIdx.x * 256 + threadIdx.x;
  if (i >= IN_DIM * 128) return;
  int k = i >> 7, c = i & 127;
  fcT[(size_t)c * 256 + k] = fc[i];
  fqT[(size_t)c * 256 + k] = fq[i];
}

// ======== single f32 GEMM: fcq[50000][384] = h @ [Wl^T | fc | fq] ========
#define BM 128
#define BK 16
__global__ __launch_bounds__(256) void k_gemm384(const float* __restrict__ A,
    const float* __restrict__ Wl, const float* __restrict__ fc,
    const float* __restrict__ fq, float* __restrict__ C){
  __shared__ float As[BK][BM + 4];
  __shared__ float Bs[BK][128 + 4];
  int tid = threadIdx.x;
  int m0 = blockIdx.x * BM;
  int n0 = blockIdx.y * 128;               // 0:ft(Wl^T)  128:fc  256:fq
  int ty = tid / 16, tx = tid % 16;
  float acc[8][8];
  #pragma unroll
  for (int i = 0; i < 8; i++)
    #pragma unroll
    for (int j = 0; j < 8; j++) acc[i][j] = 0.f;

  for (int k0 = 0; k0 < IN_DIM; k0 += BK){
    #pragma unroll
    for (int i = 0; i < 2; i++){
      int s = tid * 2 + i;
      int row = s >> 2, c4 = s & 3;
      int r = m0 + row;
      float4 v = make_float4(0.f, 0.f, 0.f, 0.f);
      if (r < N_NODES) v = *(const float4*)&A[(size_t)r * IN_DIM + k0 + c4 * 4];
      As[c4 * 4 + 0][row] = v.x; As[c4 * 4 + 1][row] = v.y;
      As[c4 * 4 + 2][row] = v.z; As[c4 * 4 + 3][row] = v.w;
    }
    if (n0 == 0){
      #pragma unroll
      for (int i = 0; i < 2; i++){
        int s = tid * 2 + i;
        int j = s >> 2, c4 = s & 3;        // Bs[k][j] = Wl[j][k0+k]
        float4 v = *(const float4*)&Wl[(size_t)j * IN_DIM + k0 + c4 * 4];
        Bs[c4 * 4 + 0][j] = v.x; Bs[c4 * 4 + 1][j] = v.y;
        Bs[c4 * 4 + 2][j] = v.z; Bs[c4 * 4 + 3][j] = v.w;
      }
    } else {
      const float* Bsrc = (n0 == 128) ? fc : fq;
      #pragma unroll
      for (int i = 0; i < 2; i++){
        int s = tid * 2 + i;
        int kr = s >> 5, c4 = s & 31;
        *(float4*)&Bs[kr][c4 * 4] = *(const float4*)&Bsrc[(size_t)(k0 + kr) * 128 + c4 * 4];
      }
    }
    __syncthreads();
    #pragma unroll
    for (int kk = 0; kk < BK; kk++){
      float4 a0 = *(const float4*)&As[kk][ty * 4];
      float4 a1 = *(const float4*)&As[kk][64 + ty * 4];
      float4 b0 = *(const float4*)&Bs[kk][tx * 4];
      float4 b1 = *(const float4*)&Bs[kk][64 + tx * 4];
      float av[8] = {a0.x, a0.y, a0.z, a0.w, a1.x, a1.y, a1.z, a1.w};
      float bv[8] = {b0.x, b0.y, b0.z, b0.w, b1.x, b1.y, b1.z, b1.w};
      #pragma unroll
      for (int i = 0; i < 8; i++)
        #pragma unroll
        for (int j = 0; j < 8; j++)
          acc[i][j] = fmaf(av[i], bv[j], acc[i][j]);
    }
    __syncthreads();
  }
  #pragma unroll
  for (int i = 0; i < 8; i++){
    int r = m0 + ((i < 4) ? (ty * 4 + i) : (64 + ty * 4 + (i - 4)));
    if (r >= N_NODES) continue;
    *(float4*)&C[(size_t)r * 384 + n0 + tx * 4]      = make_float4(acc[i][0], acc[i][1], acc[i][2], acc[i][3]);
    *(float4*)&C[(size_t)r * 384 + n0 + 64 + tx * 4] = make_float4(acc[i][4], acc[i][5], acc[i][6], acc[i][7]);
  }
}

// ======== f32 fused edge logits + softmax (wave per dst; deterministic) ========
__global__ __launch_bounds__(256) void k_softedge32(const float* __restrict__ fcq,
    const int* __restrict__ src, const unsigned* __restrict__ A,
    const unsigned* __restrict__ eidx, float* __restrict__ abuf){
  __shared__ float lds_a[4][DEG_CAP * 4];
  int d = blockIdx.x * 4 + (threadIdx.x >> 6);
  int t = threadIdx.x & 63;
  int wv = threadIdx.x >> 6;
  if (d >= N_NODES) return;
  unsigned k0 = d ? A[d - 1] : 0u, k1 = A[d];
  if (k0 == k1) return;
  float2 c = *(const float2*)&fcq[(size_t)d * 384 + 128 + t * 2];
  float m = -1.0e30f;
  int sn = src[eidx[k0]];
  float2 qn = *(const float2*)&fcq[(size_t)sn * 384 + 256 + t * 2];
  for (unsigned k = k0; k < k1; k++){
    float2 q = qn;
    if (k + 1 < k1){
      int s2 = src[eidx[k + 1]];
      qn = *(const float2*)&fcq[(size_t)s2 * 384 + 256 + t * 2];
    }
    float val = (q.x - c.x) * c.x + (q.y - c.y) * c.y;
    val += __shfl_xor(val, 1);
    val += __shfl_xor(val, 2);
    val += __shfl_xor(val, 4);
    val += __shfl_xor(val, 8);
    float a = (val > 0.f) ? val : expm1f(val);   // ELU
    m = fmaxf(m, a);
    if ((t & 15) == 0) lds_a[wv][(k - k0) * 4 + (t >> 4)] = a;
  }
  float mm = __shfl(m, (t & 3) * 16);
  unsigned nj = (k1 - k0) * 4;
  long long sfx = 0;
  for (unsigned jj = t; jj < nj; jj += 64){
    float ex = __expf(lds_a[wv][jj] - mm);       // jj%4 == t%4
    lds_a[wv][jj] = ex;
    sfx += (long long)llrintf(ex * (float)SC_32);
  }
  #pragma unroll
  for (int msk = 4; msk < 64; msk <<= 1) sfx += __shfl_xor(sfx, msk);
  float sd = (float)((double)sfx * (1.0 / SC_32));
  for (unsigned jj = t; jj < nj; jj += 64)
    abuf[(size_t)k0 * 4 + jj] = lds_a[wv][jj] / sd;
}

// ======== f32 radix select (u32 keys; attn > 0 -> bits ordered) ========
__global__ __launch_bounds__(256) void k_hp32(const float* __restrict__ attn,
    unsigned* __restrict__ sel32, unsigned* __restrict__ krem, unsigned* __restrict__ cnt,
    unsigned* __restrict__ hist, unsigned* __restrict__ done, unsigned maskHi, int shift){
  __shared__ unsigned lh[1024];
  __shared__ unsigned ticket;
  for (int j = threadIdx.x; j < 1024; j += 256) lh[j] = 0;
  __syncthreads();
  int i0 = blockIdx.x * 256 + threadIdx.x;
  int hh = i0 & 3;
  unsigned sel = sel32[hh] & maskHi;
  const int total = N_EDGES * 4;
  for (int i = i0; i < total; i += gridDim.x * 256){
    unsigned u = __float_as_uint(attn[i]);
    if ((u & maskHi) == sel)
      atomicAdd(&lh[hh * 256 + ((u >> shift) & 255u)], 1u);
  }
  __syncthreads();
  for (int j = threadIdx.x; j < 1024; j += 256)
    if (lh[j]) atomicAdd(&hist[j], lh[j]);
  __threadfence();
  if (threadIdx.x == 0) ticket = atomicAdd(done, 1u);
  __syncthreads();
  if (ticket == gridDim.x - 1){
    __threadfence();
    for (int j = threadIdx.x; j < 1024; j += 256){ lh[j] = hist[j]; hist[j] = 0; }
    __syncthreads();
    if (threadIdx.x < 4){
      int t = threadIdx.x;
      unsigned kr = krem[t], cum = 0, b = 0;
      for (; b < 256; b++){
        unsigned c2 = lh[t * 256 + b];
        if (kr < cum + c2) break;
        cum += c2;
      }
      sel32[t] |= b << shift;
      krem[t] = kr - cum;
      cnt[t] += cum;
    }
    if (threadIdx.x == 0) *done = 0;
  }
}

__global__ __launch_bounds__(256) void k_compact32(const float* __restrict__ attn,
    const unsigned* __restrict__ sel32, unsigned* __restrict__ ccnt,
    float* __restrict__ cand){
  __shared__ unsigned lcnt[4];
  __shared__ unsigned lbase[4];
  int t = threadIdx.x;
  if (t < 4) lcnt[t] = 0;
  __syncthreads();
  int i0 = blockIdx.x * 256 + t;
  int hh = i0 & 3;
  unsigned sel = sel32[hh] & 0xFFFF0000u;
  const int total = N_EDGES * 4;
  unsigned mc = 0;
  for (int i = i0; i < total; i += gridDim.x * 256){
    unsigned u = __float_as_uint(attn[i]);
    if ((u & 0xFFFF0000u) == sel) mc++;
  }
  unsigned my_local = mc ? atomicAdd(&lcnt[hh], mc) : 0u;
  __syncthreads();
  if (t < 4) lbase[t] = lcnt[t] ? atomicAdd(&ccnt[t], lcnt[t]) : 0u;
  __syncthreads();
  if (mc == 0) return;
  unsigned pos = lbase[hh] + my_local;
  float* cp = cand + (size_t)hh * N_EDGES;
  for (int i = i0; i < total; i += gridDim.x * 256){
    float v = attn[i];
    unsigned u = __float_as_uint(v);
    if ((u & 0xFFFF0000u) == sel) cp[pos++] = v;
  }
}

__global__ __launch_bounds__(256) void k_fin32(const float* __restrict__ cand,
    const unsigned* __restrict__ ccnt, unsigned* __restrict__ sel32,
    unsigned* __restrict__ krem, unsigned* __restrict__ cnt,
    unsigned* __restrict__ hist, unsigned* __restrict__ done, int shift){
  __shared__ unsigned lh[256];
  __shared__ unsigned ticket;
  int t = threadIdx.x;
  lh[t] = 0;
  __syncthreads();
  int h = blockIdx.x & 3;
  int bidx = blockIdx.x >> 2;
  int bph = gridDim.x >> 2;
  unsigned maskHi = ~((1u << (shift + 8)) - 1u);
  unsigned sel = sel32[h] & maskHi;
  unsigned n = ccnt[h];
  const float* cp = cand + (size_t)h * N_EDGES;
  for (unsigned i = bidx * 256 + t; i < n; i += bph * 256){
    unsigned u = __float_as_uint(cp[i]);
    if ((u & maskHi) == sel) atomicAdd(&lh[(u >> shift) & 255u], 1u);
  }
  __syncthreads();
  if (lh[t]) atomicAdd(&hist[h * 256 + t], lh[t]);
  __threadfence();
  if (t == 0) ticket = atomicAdd(done, 1u);
  __syncthreads();
  if (ticket == gridDim.x - 1){
    __threadfence();
    __shared__ unsigned fh[1024];
    for (int j = t; j < 1024; j += 256){ fh[j] = hist[j]; hist[j] = 0; }
    __syncthreads();
    if (t < 4){
      unsigned kr = krem[t], cum = 0, b = 0;
      for (; b < 256; b++){
        unsigned c2 = fh[t * 256 + b];
        if (kr < cum + c2) break;
        cum += c2;
      }
      sel32[t] |= b << shift;
      krem[t] = kr - cum;
      cnt[t] += cum;
    }
    if (t == 0) *done = 0;
  }
}

// ======== mark boundary candidates (attn32 in [thd*(1-MARG), thd*(1+MARG)]) ====
__global__ __launch_bounds__(256) void k_bmark(const float* __restrict__ attn,
    const unsigned* __restrict__ sel32, unsigned* __restrict__ cbelow,
    unsigned* __restrict__ bcnt, unsigned* __restrict__ blist){
  int t = threadIdx.x;
  int i0 = blockIdx.x * 256 + t;
  int hh = t & 3;
  double thd = (double)__uint_as_float(sel32[hh]);
  double lo = thd * (1.0 - MARG), hi = thd * (1.0 + MARG);
  unsigned below = 0;
  const int total = N_EDGES * 4;
  for (int i = i0; i < total; i += gridDim.x * 256){
    double v = (double)attn[i];
    if (v < lo) below++;
    else if (v <= hi){
      unsigned p = atomicAdd(bcnt, 1u);
      if (p < BCAP) blist[p] = (unsigned)i;
    }
  }
  #pragma unroll
  for (int m = 4; m < 64; m <<= 1) below += __shfl_xor(below, m);
  __shared__ unsigned sb[16];
  int wv = t >> 6;
  if ((t & 63) < 4) sb[wv * 4 + hh] = below;
  __syncthreads();
  if (t < 4){
    unsigned b = sb[t] + sb[4 + t] + sb[8 + t] + sb[12 + t];
    if (b) atomicAdd(&cbelow[t], b);
  }
}

// ======== exact f64 attn for boundary entries (ILP dot products, fcT/fqT) ====
// blist entries are ABUF indices: slot = csr_slot*4 + head.
__global__ __launch_bounds__(256) void k_brefine(const float* __restrict__ h,
    const float* __restrict__ fcT, const float* __restrict__ fqT,
    const int* __restrict__ src, const int* __restrict__ dst,
    const unsigned* __restrict__ A, const unsigned* __restrict__ eidx,
    const unsigned* __restrict__ blist, const unsigned* __restrict__ bcnt,
    double* __restrict__ bval){
  __shared__ double la[4][DEG_CAP];
  int wv = threadIdx.x >> 6;
  int l = threadIdx.x & 63;
  int j = l & 31;
  unsigned nb = *bcnt; if (nb > BCAP) nb = BCAP;
  for (unsigned idx = blockIdx.x * 4 + wv; idx < nb; idx += gridDim.x * 4){
    unsigned slot = blist[idx];
    unsigned kslot = slot >> 2;              // CSR position (NOT edge id)
    int hh = slot & 3;
    int d = dst[eidx[kslot]];                // dst node of that CSR slot
    unsigned k0 = d ? A[d - 1] : 0u, k1 = A[d];
    int col = hh * 32 + j;
    const float* wc = fcT + (size_t)col * 256;
    const float* wq = fqT + (size_t)col * 256;
    const float* hd = h + (size_t)d * 256;
    double c0 = 0.0, c1 = 0.0, c2 = 0.0, c3 = 0.0;
    #pragma unroll 4
    for (int i = 0; i < 256; i += 4){
      float4 hv = *(const float4*)&hd[i];
      float4 wv2 = *(const float4*)&wc[i];
      c0 = fma((double)hv.x, (double)wv2.x, c0);
      c1 = fma((double)hv.y, (double)wv2.y, c1);
      c2 = fma((double)hv.z, (double)wv2.z, c2);
      c3 = fma((double)hv.w, (double)wv2.w, c3);
    }
    double c = (c0 + c1) + (c2 + c3);
    double m = -1.0e300, atgt = 0.0;
    for (unsigned k = k0; k < k1; k++){
      int s = src[eidx[k]];
      const float* hs = h + (size_t)s * 256;
      double q0 = 0.0, q1 = 0.0, q2 = 0.0, q3 = 0.0;
      #pragma unroll 4
      for (int i = 0; i < 256; i += 4){
        float4 hv = *(const float4*)&hs[i];
        float4 wv2 = *(const float4*)&wq[i];
        q0 = fma((double)hv.x, (double)wv2.x, q0);
        q1 = fma((double)hv.y, (double)wv2.y, q1);
        q2 = fma((double)hv.z, (double)wv2.z, q2);
        q3 = fma((double)hv.w, (double)wv2.w, q3);
      }
      double q = (q0 + q1) + (q2 + q3);
      double p = (q - c) * c;
      p += __shfl_xor(p, 1);
      p += __shfl_xor(p, 2);
      p += __shfl_xor(p, 4);
      p += __shfl_xor(p, 8);
      p += __shfl_xor(p, 16);
      double a = (p > 0.0) ? p : expm1(p);
      m = fmax(m, a);
      if (l == 0) la[wv][k - k0] = a;
      if (k == kslot) atgt = a;              // this CSR slot is the target edge
    }
    long long sfx = 0;
    for (unsigned kk = l; kk < k1 - k0; kk += 64)
      sfx += llrint(exp(la[wv][kk] - m) * SC_FX);
    #pragma unroll
    for (int msk = 1; msk < 64; msk <<= 1) sfx += __shfl_xor(sfx, msk);
    double sd = (double)sfx * (1.0 / SC_FX);
    if (l == 0) bval[idx] = exp(atgt - m) / sd;
  }
}

// ======== exact f64 select among boundary (1 block per head) ========
__global__ __launch_bounds__(256) void k_bselect(const double* __restrict__ bval,
    const unsigned* __restrict__ blist, const unsigned* __restrict__ bcnt,
    const unsigned* __restrict__ cbelow, double* __restrict__ thd64,
    unsigned* __restrict__ cntless){
  __shared__ unsigned lh[256];
  __shared__ u64 s_sel;
  __shared__ unsigned s_kr, s_cnt;
  int hsel = blockIdx.x;
  int t = threadIdx.x;
  unsigned nb = *bcnt; if (nb > BCAP) nb = BCAP;
  if (t == 0){ s_sel = 0; s_kr = RANK0 - cbelow[hsel]; s_cnt = 0; }
  __syncthreads();
  for (int p = 0; p < 8; p++){
    int shift = 56 - 8 * p;
    u64 maskHi = (p == 0) ? 0ull : (~0ull) << (64 - 8 * p);
    lh[t] = 0;
    __syncthreads();
    u64 sel = s_sel;
    for (unsigned i = t; i < nb; i += 256){
      if ((int)(blist[i] & 3) == hsel){
        u64 u = (u64)__double_as_longlong(bval[i]);
        if ((u & maskHi) == sel) atomicAdd(&lh[(unsigned)((u >> shift) & 255u)], 1u);
      }
    }
    __syncthreads();
    if (t == 0){
      unsigned kr = s_kr, cum = 0, b = 0;
      for (; b < 256; b++){
        unsigned c2 = lh[b];
        if (kr < cum + c2) break;
        cum += c2;
      }
      s_sel |= ((u64)b) << shift;
      s_kr = kr - cum;
      s_cnt += cum;
    }
    __syncthreads();
  }
  if (t == 0){
    thd64[hsel] = __longlong_as_double((long long)s_sel);
    cntless[hsel] = cbelow[hsel] + s_cnt;
  }
}

// ======== sums for certain edges + a3 (boundary deferred to k_bfinal) ========
__global__ __launch_bounds__(256) void k_sums32(const float* __restrict__ attn,
    const unsigned* __restrict__ sel32, u64* __restrict__ gsums, float* __restrict__ a3){
  int t = threadIdx.x;
  int i0 = blockIdx.x * 256 + t;
  int hh = t & 3;
  double thd = (double)__uint_as_float(sel32[hh]);
  double lo = thd * (1.0 - MARG), hi = thd * (1.0 + MARG);
  double al = 0.0, ag = 0.0;
  const int total = N_EDGES * 4;
  for (int i = i0; i < total; i += gridDim.x * 256){
    float vf = attn[i];
    double v = (double)vf;
    if (v < lo){ al += v; a3[i] = 0.f; }
    else if (v > hi){ ag += v; a3[i] = vf; }
    else a3[i] = 0.f;                      // boundary: fixed by k_bfinal
  }
  long long ql = llrint(al * SC_FX);
  long long qg = llrint(ag * SC_FX);
  #pragma unroll
  for (int m = 4; m < 64; m <<= 1){
    ql += __shfl_xor(ql, m);
    qg += __shfl_xor(qg, m);
  }
  __shared__ long long sl[16], sg[16];
  int wv = t >> 6;
  if ((t & 63) < 4){ sl[wv * 4 + hh] = ql; sg[wv * 4 + hh] = qg; }
  __syncthreads();
  if (t < 4){
    long long a = sl[t] + sl[4 + t] + sl[8 + t] + sl[12 + t];
    long long b = sg[t] + sg[4 + t] + sg[8 + t] + sg[12 + t];
    if (a) atomicAdd(&gsums[t],     (u64)a);
    if (b) atomicAdd(&gsums[4 + t], (u64)b);
  }
}

// ======== finalize boundary entries: exact cut + sums + a3 ========
__global__ void k_bfinal(const unsigned* __restrict__ blist, const double* __restrict__ bval,
    const unsigned* __restrict__ bcnt, const double* __restrict__ thd64,
    u64* __restrict__ gsums, float* __restrict__ a3){
  unsigned nb = *bcnt; if (nb > BCAP) nb = BCAP;
  for (unsigned idx = blockIdx.x * 256 + threadIdx.x; idx < nb; idx += gridDim.x * 256){
    unsigned slot = blist[idx];
    int hh = slot & 3;
    double v = bval[idx];
    bool kept = (v >= thd64[hh]);
    a3[slot] = kept ? (float)v : 0.f;
    atomicAdd(&gsums[(kept ? 4 : 0) + hh], (u64)llrint(v * SC_FX));
  }
}

__global__ void k_ratio(const double* __restrict__ thd64, const unsigned* __restrict__ cntless,
                        const u64* __restrict__ gsums, double* __restrict__ trd){
  int t = threadIdx.x;
  if (t < 4){
    double sless = (double)(long long)gsums[t]     * (1.0 / SC_FX);
    double sge   = (double)(long long)gsums[4 + t] * (1.0 / SC_FX);
    double topk  = sless + (double)(LS - (int)cntless[t]) * thd64[t];
    trd[t] = thd64[t];
    trd[4 + t] = (sge + topk) / sge;
  }
}

// ======== CSR gather-scatter (wave per dst; ft at fcq cols 0-127) ========
__global__ __launch_bounds__(256) void k_scatter2(const float* __restrict__ fcq,
    const int* __restrict__ src, const unsigned* __restrict__ A,
    const unsigned* __restrict__ eidx, const float* __restrict__ a3,
    const double* __restrict__ trd, float* __restrict__ out){
  int d = blockIdx.x * 4 + (threadIdx.x >> 6);
  int t = threadIdx.x & 63;
  if (d >= N_NODES) return;
  int hh = t >> 4;
  double ratio = trd[4 + hh];
  unsigned k0 = d ? A[d - 1] : 0u, k1 = A[d];
  long long acc0 = 0, acc1 = 0;
  float wn = (k0 < k1) ? a3[(size_t)k0 * 4 + hh] : 0.f;
  unsigned en = (k0 < k1) ? eidx[k0] : 0u;
  for (unsigned k = k0; k < k1; k++){
    float w = wn;
    unsigned e = en;
    if (k + 1 < k1){ wn = a3[(size_t)(k + 1) * 4 + hh]; en = eidx[k + 1]; }
    if (__ballot(w != 0.f) == 0ull) continue;    // ~71% dropped
    if (w != 0.f){
      int s = src[e];
      float2 f = *(const float2*)&fcq[(size_t)s * 384 + t * 2];
      double a3r = (double)w * ratio;
      acc0 += llrint(a3r * (double)f.x * SC_FX);
      acc1 += llrint(a3r * (double)f.y * SC_FX);
    }
  }
  float* p = &out[(size_t)d * OUTC + t * 2];
  p[0] = (float)((double)acc0 * (1.0 / SC_FX));
  p[1] = (float)((double)acc1 * (1.0 / SC_FX));
}

// ======== head-mean (runs last; ft at fcq cols 0-127) ========
__global__ void k_mean(const float* __restrict__ fcq, float* __restrict__ out){
  int i = blockIdx.x * 256 + threadIdx.x;
  if (i >= N_NODES * DH) return;
  int n = i / DH, dd = i % DH;
  const float* p = fcq + (size_t)n * 384;
  out[(size_t)n * OUTC + 128 + dd] = 0.25f * (p[dd] + p[32 + dd] + p[64 + dd] + p[96 + dd]);
}

extern "C" void kernel_launch(void* const* d_in, const int* in_sizes, int n_in,
                              void* d_out, int out_size, void* d_ws, size_t ws_size,
                              hipStream_t stream){
  const float* h  = (const float*)d_in[0];
  const float* Wl = (const float*)d_in[1];
  const float* fc = (const float*)d_in[2];
  const float* fq = (const float*)d_in[3];
  const int* src  = (const int*)d_in[4];
  const int* dst  = (const int*)d_in[5];
  float* out = (float*)d_out;

  char* ws = (char*)d_ws;
  float*    fcq  = (float*)(ws);                   // 76,800,000
  unsigned* A    = (unsigned*)(ws + 76800000);     // 200,004 (pad to 77,000,064)
  unsigned* eidx = (unsigned*)(ws + 77000064);     // 3,200,000
  float*    a3   = (float*)(ws + 80200064);        // 12,800,000
  unsigned* hist = (unsigned*)(ws + 93000064);     // 4,096
  unsigned* sel32  = (unsigned*)(ws + 93004160);   // 16
  unsigned* krem   = (unsigned*)(ws + 93004176);   // 16
  unsigned* cnt    = (unsigned*)(ws + 93004192);   // 16
  unsigned* done   = (unsigned*)(ws + 93004208);   // 16
  unsigned* ccnt   = (unsigned*)(ws + 93004224);   // 16
  unsigned* cbelow = (unsigned*)(ws + 93004240);   // 16
  unsigned* bcnt   = (unsigned*)(ws + 93004256);   // 16
  unsigned* cntless= (unsigned*)(ws + 93004272);   // 16
  u64*      gsums  = (u64*)(ws + 93004288);        // 64
  double*   thd64  = (double*)(ws + 93004352);     // 32
  double*   trd    = (double*)(ws + 93004416);     // 64
  unsigned* blist  = (unsigned*)(ws + 93008896);   // 262,144 (BCAP*4)
  double*   bval   = (double*)(ws + 93271040);     // 524,288 (BCAP*8)
  float*    fcT    = (float*)(ws + 93795328);      // 131,072
  float*    fqT    = (float*)(ws + 93926400);      // 131,072

  // scratch inside d_out (32 MB): both fully dead before scatter2/mean write
  float* abuf = (float*)d_out;                     // 12.8 MB attn32
  float* cand = (float*)((char*)d_out + 12800000); // 12.8 MB select candidates

  hipMemsetAsync(A, 0, 200004, stream);
  hipMemsetAsync(hist, 0, 4096, stream);
  k_init<<<1, 64, 0, stream>>>(sel32, krem, cnt, done, ccnt, cbelow, bcnt, cntless, gsums);
  k_prept<<<(IN_DIM * 128 + 255) / 256, 256, 0, stream>>>(fc, fq, fcT, fqT);

  // CSR
  k_deg<<<(N_EDGES + 255) / 256, 256, 0, stream>>>(dst, A);
  k_scan<<<1, 1024, 0, stream>>>(A);
  k_fill<<<(N_EDGES + 255) / 256, 256, 0, stream>>>(dst, A, eidx);

  // single f32 GEMM -> [ft | c | q]
  dim3 gg((N_NODES + BM - 1) / BM, 3);
  k_gemm384<<<gg, 256, 0, stream>>>(h, Wl, fc, fq, fcq);

  // f32 fused edge logits + softmax
  k_softedge32<<<(N_NODES + 3) / 4, 256, 0, stream>>>(fcq, src, A, eidx, abuf);

  // exact f32 rank select: 2 global passes, compact, 2 finish passes
  k_hp32<<<1024, 256, 0, stream>>>(abuf, sel32, krem, cnt, hist, done, 0u, 24);
  k_hp32<<<1024, 256, 0, stream>>>(abuf, sel32, krem, cnt, hist, done, 0xFF000000u, 16);
  k_compact32<<<1024, 256, 0, stream>>>(abuf, sel32, ccnt, cand);
  k_fin32<<<256, 256, 0, stream>>>(cand, ccnt, sel32, krem, cnt, hist, done, 8);
  k_fin32<<<256, 256, 0, stream>>>(cand, ccnt, sel32, krem, cnt, hist, done, 0);

  // boundary: mark, refine in f64, exact f64 threshold
  k_bmark<<<1024, 256, 0, stream>>>(abuf, sel32, cbelow, bcnt, blist);
  k_brefine<<<512, 256, 0, stream>>>(h, fcT, fqT, src, dst, A, eidx, blist, bcnt, bval);
  k_bselect<<<4, 256, 0, stream>>>(bval, blist, bcnt, cbelow, thd64, cntless);

  // sums + a3 (+ boundary fixes) + ratio
  k_sums32<<<2048, 256, 0, stream>>>(abuf, sel32, gsums, a3);
  k_bfinal<<<64, 256, 0, stream>>>(blist, bval, bcnt, thd64, gsums, a3);
  k_ratio<<<1, 64, 0, stream>>>(thd64, cntless, gsums, trd);

  // output
  k_scatter2<<<(N_NODES + 3) / 4, 256, 0, stream>>>(fcq, src, A, eidx, a3, trd, out);
  k_mean<<<(N_NODES * DH + 255) / 256, 256, 0, stream>>>(fcq, out);
}

// Round 15
// 1245.247 us; speedup vs baseline: 1.2543x; 1.0187x over previous
//
#include <hip/hip_runtime.h>
#include <hip/hip_bf16.h>
#include <math.h>

#define N_NODES 50000
#define N_EDGES 800000
#define DH 32
#define IN_DIM 256
#define OUTC 160
#define LS 570400     // int(0.713 * 800000) -> exactly 570400
#define RANK0 (LS - 1)
#define DEG_CAP 160   // max in-degree supported (Poisson(16))
#define BCAP 65536    // boundary-candidate cap (expect ~1K)
#define MARG 3.0e-4   // relative margin around thd32 (~30x worst f32 error)

typedef unsigned long long u64;
#define SC_FX 1099511627776.0   // 2^40 fixed-point scale (f64 sums)
#define SC_32 4294967296.0      // 2^32 fixed-point scale (f32 softmax denom)

// ======== CSR build ========
__global__ void k_deg(const int* __restrict__ dst, unsigned* __restrict__ A){
  int e = blockIdx.x * 256 + threadIdx.x;
  if (e < N_EDGES) atomicAdd(&A[dst[e]], 1u);
}

__global__ __launch_bounds__(1024) void k_scan(unsigned* __restrict__ A){
  __shared__ unsigned ps[1024];
  int t = threadIdx.x;
  const int CH = (N_NODES + 1023) / 1024;
  int base = t * CH;
  unsigned s = 0;
  for (int i = 0; i < CH; i++){ int n = base + i; if (n < N_NODES) s += A[n]; }
  ps[t] = s;
  __syncthreads();
  for (int off = 1; off < 1024; off <<= 1){
    unsigned v = (t >= off) ? ps[t - off] : 0;
    __syncthreads();
    ps[t] += v;
    __syncthreads();
  }
  unsigned ex = (t == 0) ? 0 : ps[t - 1];
  for (int i = 0; i < CH; i++){
    int n = base + i;
    if (n < N_NODES){ unsigned dv = A[n]; A[n] = ex; ex += dv; }
  }
}

__global__ void k_fill(const int* __restrict__ dst, unsigned* __restrict__ A,
                       unsigned* __restrict__ eidx){
  int e = blockIdx.x * 256 + threadIdx.x;
  if (e < N_EDGES) eidx[atomicAdd(&A[dst[e]], 1u)] = (unsigned)e;
}
// post-fill: A[d] == offsets[d+1]; node d range = [d? A[d-1]:0, A[d])

__global__ void k_init(unsigned* __restrict__ sel32, unsigned* __restrict__ krem,
                       unsigned* __restrict__ cnt, unsigned* __restrict__ done,
                       unsigned* __restrict__ ccnt, unsigned* __restrict__ cbelow,
                       unsigned* __restrict__ bcnt, unsigned* __restrict__ cntless,
                       u64* __restrict__ gsums){
  int t = threadIdx.x;
  if (t < 4){ sel32[t]=0; krem[t]=RANK0; cnt[t]=0; ccnt[t]=0; cbelow[t]=0; cntless[t]=0; }
  if (t < 8) gsums[t] = 0;
  if (t == 0){ done[0] = 0; bcnt[0] = 0; }
}

// ======== transpose fc/fq to [col][k] for lane-contiguous f64 refine ========
__global__ void k_prept(const float* __restrict__ fc, const float* __restrict__ fq,
                        float* __restrict__ fcT, float* __restrict__ fqT){
  int i = blockIdx.x * 256 + threadIdx.x;
  if (i >= IN_DIM * 128) return;
  int k = i >> 7, c = i & 127;
  fcT[(size_t)c * 256 + k] = fc[i];
  fqT[(size_t)c * 256 + k] = fq[i];
}

// ======== single f32 GEMM: fcq[50000][384] = h @ [Wl^T | fc | fq] ========
#define BM 128
#define BK 16
__global__ __launch_bounds__(256) void k_gemm384(const float* __restrict__ A,
    const float* __restrict__ Wl, const float* __restrict__ fc,
    const float* __restrict__ fq, float* __restrict__ C){
  __shared__ float As[BK][BM + 4];
  __shared__ float Bs[BK][128 + 4];
  int tid = threadIdx.x;
  int m0 = blockIdx.x * BM;
  int n0 = blockIdx.y * 128;               // 0:ft(Wl^T)  128:fc  256:fq
  int ty = tid / 16, tx = tid % 16;
  float acc[8][8];
  #pragma unroll
  for (int i = 0; i < 8; i++)
    #pragma unroll
    for (int j = 0; j < 8; j++) acc[i][j] = 0.f;

  for (int k0 = 0; k0 < IN_DIM; k0 += BK){
    #pragma unroll
    for (int i = 0; i < 2; i++){
      int s = tid * 2 + i;
      int row = s >> 2, c4 = s & 3;
      int r = m0 + row;
      float4 v = make_float4(0.f, 0.f, 0.f, 0.f);
      if (r < N_NODES) v = *(const float4*)&A[(size_t)r * IN_DIM + k0 + c4 * 4];
      As[c4 * 4 + 0][row] = v.x; As[c4 * 4 + 1][row] = v.y;
      As[c4 * 4 + 2][row] = v.z; As[c4 * 4 + 3][row] = v.w;
    }
    if (n0 == 0){
      #pragma unroll
      for (int i = 0; i < 2; i++){
        int s = tid * 2 + i;
        int j = s >> 2, c4 = s & 3;        // Bs[k][j] = Wl[j][k0+k]
        float4 v = *(const float4*)&Wl[(size_t)j * IN_DIM + k0 + c4 * 4];
        Bs[c4 * 4 + 0][j] = v.x; Bs[c4 * 4 + 1][j] = v.y;
        Bs[c4 * 4 + 2][j] = v.z; Bs[c4 * 4 + 3][j] = v.w;
      }
    } else {
      const float* Bsrc = (n0 == 128) ? fc : fq;
      #pragma unroll
      for (int i = 0; i < 2; i++){
        int s = tid * 2 + i;
        int kr = s >> 5, c4 = s & 31;
        *(float4*)&Bs[kr][c4 * 4] = *(const float4*)&Bsrc[(size_t)(k0 + kr) * 128 + c4 * 4];
      }
    }
    __syncthreads();
    #pragma unroll
    for (int kk = 0; kk < BK; kk++){
      float4 a0 = *(const float4*)&As[kk][ty * 4];
      float4 a1 = *(const float4*)&As[kk][64 + ty * 4];
      float4 b0 = *(const float4*)&Bs[kk][tx * 4];
      float4 b1 = *(const float4*)&Bs[kk][64 + tx * 4];
      float av[8] = {a0.x, a0.y, a0.z, a0.w, a1.x, a1.y, a1.z, a1.w};
      float bv[8] = {b0.x, b0.y, b0.z, b0.w, b1.x, b1.y, b1.z, b1.w};
      #pragma unroll
      for (int i = 0; i < 8; i++)
        #pragma unroll
        for (int j = 0; j < 8; j++)
          acc[i][j] = fmaf(av[i], bv[j], acc[i][j]);
    }
    __syncthreads();
  }
  #pragma unroll
  for (int i = 0; i < 8; i++){
    int r = m0 + ((i < 4) ? (ty * 4 + i) : (64 + ty * 4 + (i - 4)));
    if (r >= N_NODES) continue;
    *(float4*)&C[(size_t)r * 384 + n0 + tx * 4]      = make_float4(acc[i][0], acc[i][1], acc[i][2], acc[i][3]);
    *(float4*)&C[(size_t)r * 384 + n0 + 64 + tx * 4] = make_float4(acc[i][4], acc[i][5], acc[i][6], acc[i][7]);
  }
}

// ======== f32 fused edge logits + softmax (wave per dst; deterministic) ========
__global__ __launch_bounds__(256) void k_softedge32(const float* __restrict__ fcq,
    const int* __restrict__ src, const unsigned* __restrict__ A,
    const unsigned* __restrict__ eidx, float* __restrict__ abuf){
  __shared__ float lds_a[4][DEG_CAP * 4];
  int d = blockIdx.x * 4 + (threadIdx.x >> 6);
  int t = threadIdx.x & 63;
  int wv = threadIdx.x >> 6;
  if (d >= N_NODES) return;
  unsigned k0 = d ? A[d - 1] : 0u, k1 = A[d];
  if (k0 == k1) return;
  float2 c = *(const float2*)&fcq[(size_t)d * 384 + 128 + t * 2];
  float m = -1.0e30f;
  int sn = src[eidx[k0]];
  float2 qn = *(const float2*)&fcq[(size_t)sn * 384 + 256 + t * 2];
  for (unsigned k = k0; k < k1; k++){
    float2 q = qn;
    if (k + 1 < k1){
      int s2 = src[eidx[k + 1]];
      qn = *(const float2*)&fcq[(size_t)s2 * 384 + 256 + t * 2];
    }
    float val = (q.x - c.x) * c.x + (q.y - c.y) * c.y;
    val += __shfl_xor(val, 1);
    val += __shfl_xor(val, 2);
    val += __shfl_xor(val, 4);
    val += __shfl_xor(val, 8);
    float a = (val > 0.f) ? val : expm1f(val);   // ELU
    m = fmaxf(m, a);
    if ((t & 15) == 0) lds_a[wv][(k - k0) * 4 + (t >> 4)] = a;
  }
  float mm = __shfl(m, (t & 3) * 16);
  unsigned nj = (k1 - k0) * 4;
  long long sfx = 0;
  for (unsigned jj = t; jj < nj; jj += 64){
    float ex = __expf(lds_a[wv][jj] - mm);       // jj%4 == t%4
    lds_a[wv][jj] = ex;
    sfx += (long long)llrintf(ex * (float)SC_32);
  }
  #pragma unroll
  for (int msk = 4; msk < 64; msk <<= 1) sfx += __shfl_xor(sfx, msk);
  float sd = (float)((double)sfx * (1.0 / SC_32));
  for (unsigned jj = t; jj < nj; jj += 64)
    abuf[(size_t)k0 * 4 + jj] = lds_a[wv][jj] / sd;
}

// ======== f32 radix select (u32 keys; attn > 0 -> bits ordered) ========
__global__ __launch_bounds__(256) void k_hp32(const float* __restrict__ attn,
    unsigned* __restrict__ sel32, unsigned* __restrict__ krem, unsigned* __restrict__ cnt,
    unsigned* __restrict__ hist, unsigned* __restrict__ done, unsigned maskHi, int shift){
  __shared__ unsigned lh[1024];
  __shared__ unsigned ticket;
  for (int j = threadIdx.x; j < 1024; j += 256) lh[j] = 0;
  __syncthreads();
  int i0 = blockIdx.x * 256 + threadIdx.x;
  int hh = i0 & 3;
  unsigned sel = sel32[hh] & maskHi;
  const int total = N_EDGES * 4;
  for (int i = i0; i < total; i += gridDim.x * 256){
    unsigned u = __float_as_uint(attn[i]);
    if ((u & maskHi) == sel)
      atomicAdd(&lh[hh * 256 + ((u >> shift) & 255u)], 1u);
  }
  __syncthreads();
  for (int j = threadIdx.x; j < 1024; j += 256)
    if (lh[j]) atomicAdd(&hist[j], lh[j]);
  __threadfence();
  if (threadIdx.x == 0) ticket = atomicAdd(done, 1u);
  __syncthreads();
  if (ticket == gridDim.x - 1){
    __threadfence();
    for (int j = threadIdx.x; j < 1024; j += 256){ lh[j] = hist[j]; hist[j] = 0; }
    __syncthreads();
    if (threadIdx.x < 4){
      int t = threadIdx.x;
      unsigned kr = krem[t], cum = 0, b = 0;
      for (; b < 256; b++){
        unsigned c2 = lh[t * 256 + b];
        if (kr < cum + c2) break;
        cum += c2;
      }
      sel32[t] |= b << shift;
      krem[t] = kr - cum;
      cnt[t] += cum;
    }
    if (threadIdx.x == 0) *done = 0;
  }
}

__global__ __launch_bounds__(256) void k_compact32(const float* __restrict__ attn,
    const unsigned* __restrict__ sel32, unsigned* __restrict__ ccnt,
    float* __restrict__ cand){
  __shared__ unsigned lcnt[4];
  __shared__ unsigned lbase[4];
  int t = threadIdx.x;
  if (t < 4) lcnt[t] = 0;
  __syncthreads();
  int i0 = blockIdx.x * 256 + t;
  int hh = i0 & 3;
  unsigned sel = sel32[hh] & 0xFFFF0000u;
  const int total = N_EDGES * 4;
  unsigned mc = 0;
  for (int i = i0; i < total; i += gridDim.x * 256){
    unsigned u = __float_as_uint(attn[i]);
    if ((u & 0xFFFF0000u) == sel) mc++;
  }
  unsigned my_local = mc ? atomicAdd(&lcnt[hh], mc) : 0u;
  __syncthreads();
  if (t < 4) lbase[t] = lcnt[t] ? atomicAdd(&ccnt[t], lcnt[t]) : 0u;
  __syncthreads();
  if (mc == 0) return;
  unsigned pos = lbase[hh] + my_local;
  float* cp = cand + (size_t)hh * N_EDGES;
  for (int i = i0; i < total; i += gridDim.x * 256){
    float v = attn[i];
    unsigned u = __float_as_uint(v);
    if ((u & 0xFFFF0000u) == sel) cp[pos++] = v;
  }
}

__global__ __launch_bounds__(256) void k_fin32(const float* __restrict__ cand,
    const unsigned* __restrict__ ccnt, unsigned* __restrict__ sel32,
    unsigned* __restrict__ krem, unsigned* __restrict__ cnt,
    unsigned* __restrict__ hist, unsigned* __restrict__ done, int shift){
  __shared__ unsigned lh[256];
  __shared__ unsigned ticket;
  int t = threadIdx.x;
  lh[t] = 0;
  __syncthreads();
  int h = blockIdx.x & 3;
  int bidx = blockIdx.x >> 2;
  int bph = gridDim.x >> 2;
  unsigned maskHi = ~((1u << (shift + 8)) - 1u);
  unsigned sel = sel32[h] & maskHi;
  unsigned n = ccnt[h];
  const float* cp = cand + (size_t)h * N_EDGES;
  for (unsigned i = bidx * 256 + t; i < n; i += bph * 256){
    unsigned u = __float_as_uint(cp[i]);
    if ((u & maskHi) == sel) atomicAdd(&lh[(u >> shift) & 255u], 1u);
  }
  __syncthreads();
  if (lh[t]) atomicAdd(&hist[h * 256 + t], lh[t]);
  __threadfence();
  if (t == 0) ticket = atomicAdd(done, 1u);
  __syncthreads();
  if (ticket == gridDim.x - 1){
    __threadfence();
    __shared__ unsigned fh[1024];
    for (int j = t; j < 1024; j += 256){ fh[j] = hist[j]; hist[j] = 0; }
    __syncthreads();
    if (t < 4){
      unsigned kr = krem[t], cum = 0, b = 0;
      for (; b < 256; b++){
        unsigned c2 = fh[t * 256 + b];
        if (kr < cum + c2) break;
        cum += c2;
      }
      sel32[t] |= b << shift;
      krem[t] = kr - cum;
      cnt[t] += cum;
    }
    if (t == 0) *done = 0;
  }
}

// ======== mark boundary candidates (attn32 in [thd*(1-MARG), thd*(1+MARG)]) ====
__global__ __launch_bounds__(256) void k_bmark(const float* __restrict__ attn,
    const unsigned* __restrict__ sel32, unsigned* __restrict__ cbelow,
    unsigned* __restrict__ bcnt, unsigned* __restrict__ blist){
  int t = threadIdx.x;
  int i0 = blockIdx.x * 256 + t;
  int hh = t & 3;
  double thd = (double)__uint_as_float(sel32[hh]);
  double lo = thd * (1.0 - MARG), hi = thd * (1.0 + MARG);
  unsigned below = 0;
  const int total = N_EDGES * 4;
  for (int i = i0; i < total; i += gridDim.x * 256){
    double v = (double)attn[i];
    if (v < lo) below++;
    else if (v <= hi){
      unsigned p = atomicAdd(bcnt, 1u);
      if (p < BCAP) blist[p] = (unsigned)i;
    }
  }
  #pragma unroll
  for (int m = 4; m < 64; m <<= 1) below += __shfl_xor(below, m);
  __shared__ unsigned sb[16];
  int wv = t >> 6;
  if ((t & 63) < 4) sb[wv * 4 + hh] = below;
  __syncthreads();
  if (t < 4){
    unsigned b = sb[t] + sb[4 + t] + sb[8 + t] + sb[12 + t];
    if (b) atomicAdd(&cbelow[t], b);
  }
}

// ======== exact f64 attn for boundary entries: BLOCK per entry, 4-way edges ====
// blist entries are ABUF indices: slot = csr_slot*4 + head.
__global__ __launch_bounds__(256) void k_brefine(const float* __restrict__ h,
    const float* __restrict__ fcT, const float* __restrict__ fqT,
    const int* __restrict__ src, const int* __restrict__ dst,
    const unsigned* __restrict__ A, const unsigned* __restrict__ eidx,
    const unsigned* __restrict__ blist, const unsigned* __restrict__ bcnt,
    double* __restrict__ bval){
  __shared__ double la[DEG_CAP];
  int wv = threadIdx.x >> 6;
  int l = threadIdx.x & 63;
  int j = l & 31;
  unsigned nb = *bcnt; if (nb > BCAP) nb = BCAP;
  for (unsigned idx = blockIdx.x; idx < nb; idx += gridDim.x){
    unsigned slot = blist[idx];
    unsigned kslot = slot >> 2;              // CSR position
    int hh = slot & 3;
    int d = dst[eidx[kslot]];
    unsigned k0 = d ? A[d - 1] : 0u, k1 = A[d];
    unsigned deg = k1 - k0;
    int col = hh * 32 + j;
    const float* wc = fcT + (size_t)col * 256;
    const float* wq = fqT + (size_t)col * 256;
    // c-dot, redundantly per wave (identical sequence -> deterministic)
    const float* hd = h + (size_t)d * 256;
    double c0 = 0.0, c1 = 0.0, c2 = 0.0, c3 = 0.0;
    #pragma unroll 8
    for (int i = 0; i < 256; i += 4){
      float4 hv = *(const float4*)&hd[i];
      float4 w2 = *(const float4*)&wc[i];
      c0 = fma((double)hv.x, (double)w2.x, c0);
      c1 = fma((double)hv.y, (double)w2.y, c1);
      c2 = fma((double)hv.z, (double)w2.z, c2);
      c3 = fma((double)hv.w, (double)w2.w, c3);
    }
    double cj = (c0 + c1) + (c2 + c3);
    // q-dots: wave wv handles edges k0+wv, k0+wv+4, ...
    for (unsigned k = k0 + wv; k < k1; k += 4){
      int s = src[eidx[k]];
      const float* hs = h + (size_t)s * 256;
      double q0 = 0.0, q1 = 0.0, q2 = 0.0, q3 = 0.0;
      #pragma unroll 8
      for (int i = 0; i < 256; i += 4){
        float4 hv = *(const float4*)&hs[i];
        float4 w2 = *(const float4*)&wq[i];
        q0 = fma((double)hv.x, (double)w2.x, q0);
        q1 = fma((double)hv.y, (double)w2.y, q1);
        q2 = fma((double)hv.z, (double)w2.z, q2);
        q3 = fma((double)hv.w, (double)w2.w, q3);
      }
      double p = (((q0 + q1) + (q2 + q3)) - cj) * cj;
      p += __shfl_xor(p, 1);
      p += __shfl_xor(p, 2);
      p += __shfl_xor(p, 4);
      p += __shfl_xor(p, 8);
      p += __shfl_xor(p, 16);
      double a = (p > 0.0) ? p : expm1(p);
      if (l == 0) la[k - k0] = a;
    }
    __syncthreads();
    if (wv == 0){
      double m = -1.0e300;
      for (unsigned kk = l; kk < deg; kk += 64) m = fmax(m, la[kk]);
      #pragma unroll
      for (int msk = 1; msk < 64; msk <<= 1) m = fmax(m, __shfl_xor(m, msk));
      long long sfx = 0;
      for (unsigned kk = l; kk < deg; kk += 64)
        sfx += llrint(exp(la[kk] - m) * SC_FX);
      #pragma unroll
      for (int msk = 1; msk < 64; msk <<= 1) sfx += __shfl_xor(sfx, msk);
      if (l == 0){
        double sd = (double)sfx * (1.0 / SC_FX);
        bval[idx] = exp(la[kslot - k0] - m) / sd;
      }
    }
    __syncthreads();   // protect la before next grid-stride iteration
  }
}

// ======== exact f64 select among boundary (1 block per head) ========
__global__ __launch_bounds__(256) void k_bselect(const double* __restrict__ bval,
    const unsigned* __restrict__ blist, const unsigned* __restrict__ bcnt,
    const unsigned* __restrict__ cbelow, double* __restrict__ thd64,
    unsigned* __restrict__ cntless){
  __shared__ unsigned lh[256];
  __shared__ u64 s_sel;
  __shared__ unsigned s_kr, s_cnt;
  int hsel = blockIdx.x;
  int t = threadIdx.x;
  unsigned nb = *bcnt; if (nb > BCAP) nb = BCAP;
  if (t == 0){ s_sel = 0; s_kr = RANK0 - cbelow[hsel]; s_cnt = 0; }
  __syncthreads();
  for (int p = 0; p < 8; p++){
    int shift = 56 - 8 * p;
    u64 maskHi = (p == 0) ? 0ull : (~0ull) << (64 - 8 * p);
    lh[t] = 0;
    __syncthreads();
    u64 sel = s_sel;
    for (unsigned i = t; i < nb; i += 256){
      if ((int)(blist[i] & 3) == hsel){
        u64 u = (u64)__double_as_longlong(bval[i]);
        if ((u & maskHi) == sel) atomicAdd(&lh[(unsigned)((u >> shift) & 255u)], 1u);
      }
    }
    __syncthreads();
    if (t == 0){
      unsigned kr = s_kr, cum = 0, b = 0;
      for (; b < 256; b++){
        unsigned c2 = lh[b];
        if (kr < cum + c2) break;
        cum += c2;
      }
      s_sel |= ((u64)b) << shift;
      s_kr = kr - cum;
      s_cnt += cum;
    }
    __syncthreads();
  }
  if (t == 0){
    thd64[hsel] = __longlong_as_double((long long)s_sel);
    cntless[hsel] = cbelow[hsel] + s_cnt;
  }
}

// ======== sums for certain edges + a3 (boundary deferred to k_bfinal) ========
__global__ __launch_bounds__(256) void k_sums32(const float* __restrict__ attn,
    const unsigned* __restrict__ sel32, u64* __restrict__ gsums, float* __restrict__ a3){
  int t = threadIdx.x;
  int i0 = blockIdx.x * 256 + t;
  int hh = t & 3;
  double thd = (double)__uint_as_float(sel32[hh]);
  double lo = thd * (1.0 - MARG), hi = thd * (1.0 + MARG);
  double al = 0.0, ag = 0.0;
  const int total = N_EDGES * 4;
  for (int i = i0; i < total; i += gridDim.x * 256){
    float vf = attn[i];
    double v = (double)vf;
    if (v < lo){ al += v; a3[i] = 0.f; }
    else if (v > hi){ ag += v; a3[i] = vf; }
    else a3[i] = 0.f;                      // boundary: fixed by k_bfinal
  }
  long long ql = llrint(al * SC_FX);
  long long qg = llrint(ag * SC_FX);
  #pragma unroll
  for (int m = 4; m < 64; m <<= 1){
    ql += __shfl_xor(ql, m);
    qg += __shfl_xor(qg, m);
  }
  __shared__ long long sl[16], sg[16];
  int wv = t >> 6;
  if ((t & 63) < 4){ sl[wv * 4 + hh] = ql; sg[wv * 4 + hh] = qg; }
  __syncthreads();
  if (t < 4){
    long long a = sl[t] + sl[4 + t] + sl[8 + t] + sl[12 + t];
    long long b = sg[t] + sg[4 + t] + sg[8 + t] + sg[12 + t];
    if (a) atomicAdd(&gsums[t],     (u64)a);
    if (b) atomicAdd(&gsums[4 + t], (u64)b);
  }
}

// ======== finalize boundary entries: exact cut + sums + a3 ========
__global__ void k_bfinal(const unsigned* __restrict__ blist, const double* __restrict__ bval,
    const unsigned* __restrict__ bcnt, const double* __restrict__ thd64,
    u64* __restrict__ gsums, float* __restrict__ a3){
  unsigned nb = *bcnt; if (nb > BCAP) nb = BCAP;
  for (unsigned idx = blockIdx.x * 256 + threadIdx.x; idx < nb; idx += gridDim.x * 256){
    unsigned slot = blist[idx];
    int hh = slot & 3;
    double v = bval[idx];
    bool kept = (v >= thd64[hh]);
    a3[slot] = kept ? (float)v : 0.f;
    atomicAdd(&gsums[(kept ? 4 : 0) + hh], (u64)llrint(v * SC_FX));
  }
}

__global__ void k_ratio(const double* __restrict__ thd64, const unsigned* __restrict__ cntless,
                        const u64* __restrict__ gsums, double* __restrict__ trd){
  int t = threadIdx.x;
  if (t < 4){
    double sless = (double)(long long)gsums[t]     * (1.0 / SC_FX);
    double sge   = (double)(long long)gsums[4 + t] * (1.0 / SC_FX);
    double topk  = sless + (double)(LS - (int)cntless[t]) * thd64[t];
    trd[t] = thd64[t];
    trd[4 + t] = (sge + topk) / sge;
  }
}

// ======== CSR gather-scatter (wave per dst; ft at fcq cols 0-127) ========
__global__ __launch_bounds__(256) void k_scatter2(const float* __restrict__ fcq,
    const int* __restrict__ src, const unsigned* __restrict__ A,
    const unsigned* __restrict__ eidx, const float* __restrict__ a3,
    const double* __restrict__ trd, float* __restrict__ out){
  int d = blockIdx.x * 4 + (threadIdx.x >> 6);
  int t = threadIdx.x & 63;
  if (d >= N_NODES) return;
  int hh = t >> 4;
  double ratio = trd[4 + hh];
  unsigned k0 = d ? A[d - 1] : 0u, k1 = A[d];
  long long acc0 = 0, acc1 = 0;
  float wn = (k0 < k1) ? a3[(size_t)k0 * 4 + hh] : 0.f;
  unsigned en = (k0 < k1) ? eidx[k0] : 0u;
  for (unsigned k = k0; k < k1; k++){
    float w = wn;
    unsigned e = en;
    if (k + 1 < k1){ wn = a3[(size_t)(k + 1) * 4 + hh]; en = eidx[k + 1]; }
    if (__ballot(w != 0.f) == 0ull) continue;    // ~71% dropped
    if (w != 0.f){
      int s = src[e];
      float2 f = *(const float2*)&fcq[(size_t)s * 384 + t * 2];
      double a3r = (double)w * ratio;
      acc0 += llrint(a3r * (double)f.x * SC_FX);
      acc1 += llrint(a3r * (double)f.y * SC_FX);
    }
  }
  float* p = &out[(size_t)d * OUTC + t * 2];
  p[0] = (float)((double)acc0 * (1.0 / SC_FX));
  p[1] = (float)((double)acc1 * (1.0 / SC_FX));
}

// ======== head-mean (runs last; ft at fcq cols 0-127) ========
__global__ void k_mean(const float* __restrict__ fcq, float* __restrict__ out){
  int i = blockIdx.x * 256 + threadIdx.x;
  if (i >= N_NODES * DH) return;
  int n = i / DH, dd = i % DH;
  const float* p = fcq + (size_t)n * 384;
  out[(size_t)n * OUTC + 128 + dd] = 0.25f * (p[dd] + p[32 + dd] + p[64 + dd] + p[96 + dd]);
}

extern "C" void kernel_launch(void* const* d_in, const int* in_sizes, int n_in,
                              void* d_out, int out_size, void* d_ws, size_t ws_size,
                              hipStream_t stream){
  const float* h  = (const float*)d_in[0];
  const float* Wl = (const float*)d_in[1];
  const float* fc = (const float*)d_in[2];
  const float* fq = (const float*)d_in[3];
  const int* src  = (const int*)d_in[4];
  const int* dst  = (const int*)d_in[5];
  float* out = (float*)d_out;

  char* ws = (char*)d_ws;
  float*    fcq  = (float*)(ws);                   // 76,800,000
  unsigned* A    = (unsigned*)(ws + 76800000);     // 200,004 (pad to 77,000,064)
  unsigned* eidx = (unsigned*)(ws + 77000064);     // 3,200,000
  float*    a3   = (float*)(ws + 80200064);        // 12,800,000
  unsigned* hist = (unsigned*)(ws + 93000064);     // 4,096
  unsigned* sel32  = (unsigned*)(ws + 93004160);   // 16
  unsigned* krem   = (unsigned*)(ws + 93004176);   // 16
  unsigned* cnt    = (unsigned*)(ws + 93004192);   // 16
  unsigned* done   = (unsigned*)(ws + 93004208);   // 16
  unsigned* ccnt   = (unsigned*)(ws + 93004224);   // 16
  unsigned* cbelow = (unsigned*)(ws + 93004240);   // 16
  unsigned* bcnt   = (unsigned*)(ws + 93004256);   // 16
  unsigned* cntless= (unsigned*)(ws + 93004272);   // 16
  u64*      gsums  = (u64*)(ws + 93004288);        // 64
  double*   thd64  = (double*)(ws + 93004352);     // 32
  double*   trd    = (double*)(ws + 93004416);     // 64
  unsigned* blist  = (unsigned*)(ws + 93008896);   // 262,144 (BCAP*4)
  double*   bval   = (double*)(ws + 93271040);     // 524,288 (BCAP*8)
  float*    fcT    = (float*)(ws + 93795328);      // 131,072
  float*    fqT    = (float*)(ws + 93926400);      // 131,072

  // scratch inside d_out (32 MB): both fully dead before scatter2/mean write
  float* abuf = (float*)d_out;                     // 12.8 MB attn32
  float* cand = (float*)((char*)d_out + 12800000); // 12.8 MB select candidates

  hipMemsetAsync(A, 0, 200004, stream);
  hipMemsetAsync(hist, 0, 4096, stream);
  k_init<<<1, 64, 0, stream>>>(sel32, krem, cnt, done, ccnt, cbelow, bcnt, cntless, gsums);
  k_prept<<<(IN_DIM * 128 + 255) / 256, 256, 0, stream>>>(fc, fq, fcT, fqT);

  // CSR
  k_deg<<<(N_EDGES + 255) / 256, 256, 0, stream>>>(dst, A);
  k_scan<<<1, 1024, 0, stream>>>(A);
  k_fill<<<(N_EDGES + 255) / 256, 256, 0, stream>>>(dst, A, eidx);

  // single f32 GEMM -> [ft | c | q]
  dim3 gg((N_NODES + BM - 1) / BM, 3);
  k_gemm384<<<gg, 256, 0, stream>>>(h, Wl, fc, fq, fcq);

  // f32 fused edge logits + softmax
  k_softedge32<<<(N_NODES + 3) / 4, 256, 0, stream>>>(fcq, src, A, eidx, abuf);

  // exact f32 rank select: 2 global passes, compact, 2 finish passes
  k_hp32<<<1024, 256, 0, stream>>>(abuf, sel32, krem, cnt, hist, done, 0u, 24);
  k_hp32<<<1024, 256, 0, stream>>>(abuf, sel32, krem, cnt, hist, done, 0xFF000000u, 16);
  k_compact32<<<1024, 256, 0, stream>>>(abuf, sel32, ccnt, cand);
  k_fin32<<<256, 256, 0, stream>>>(cand, ccnt, sel32, krem, cnt, hist, done, 8);
  k_fin32<<<256, 256, 0, stream>>>(cand, ccnt, sel32, krem, cnt, hist, done, 0);

  // boundary: mark, refine in f64 (block per entry), exact f64 threshold
  k_bmark<<<1024, 256, 0, stream>>>(abuf, sel32, cbelow, bcnt, blist);
  k_brefine<<<2048, 256, 0, stream>>>(h, fcT, fqT, src, dst, A, eidx, blist, bcnt, bval);
  k_bselect<<<4, 256, 0, stream>>>(bval, blist, bcnt, cbelow, thd64, cntless);

  // sums + a3 (+ boundary fixes) + ratio
  k_sums32<<<2048, 256, 0, stream>>>(abuf, sel32, gsums, a3);
  k_bfinal<<<64, 256, 0, stream>>>(blist, bval, bcnt, thd64, gsums, a3);
  k_ratio<<<1, 64, 0, stream>>>(thd64, cntless, gsums, trd);

  // output
  k_scatter2<<<(N_NODES + 3) / 4, 256, 0, stream>>>(fcq, src, A, eidx, a3, trd, out);
  k_mean<<<(N_NODES * DH + 255) / 256, 256, 0, stream>>>(fcq, out);
}

// Round 16
// 1031.542 us; speedup vs baseline: 1.5141x; 1.2072x over previous
//
#include <hip/hip_runtime.h>
#include <hip/hip_bf16.h>
#include <math.h>

#define N_NODES 50000
#define N_EDGES 800000
#define DH 32
#define IN_DIM 256
#define OUTC 160
#define LS 570400     // int(0.713 * 800000) -> exactly 570400
#define RANK0 (LS - 1)
#define DEG_CAP 160   // max in-degree supported (Poisson(16))
#define BCAP 65536    // boundary-candidate cap (expect ~1K)
#define MARG 3.0e-4   // relative margin around thd32 (~30x worst f32 error)

typedef unsigned long long u64;
#define SC_FX 1099511627776.0   // 2^40 fixed-point scale (f64 sums)
#define SC_32 4294967296.0      // 2^32 fixed-point scale (f32 softmax denom)

// ======== CSR build ========
__global__ void k_deg(const int* __restrict__ dst, unsigned* __restrict__ A){
  int e = blockIdx.x * 256 + threadIdx.x;
  if (e < N_EDGES) atomicAdd(&A[dst[e]], 1u);
}

__global__ __launch_bounds__(1024) void k_scan(unsigned* __restrict__ A){
  __shared__ unsigned ps[1024];
  int t = threadIdx.x;
  const int CH = (N_NODES + 1023) / 1024;
  int base = t * CH;
  unsigned s = 0;
  for (int i = 0; i < CH; i++){ int n = base + i; if (n < N_NODES) s += A[n]; }
  ps[t] = s;
  __syncthreads();
  for (int off = 1; off < 1024; off <<= 1){
    unsigned v = (t >= off) ? ps[t - off] : 0;
    __syncthreads();
    ps[t] += v;
    __syncthreads();
  }
  unsigned ex = (t == 0) ? 0 : ps[t - 1];
  for (int i = 0; i < CH; i++){
    int n = base + i;
    if (n < N_NODES){ unsigned dv = A[n]; A[n] = ex; ex += dv; }
  }
}

__global__ void k_fill(const int* __restrict__ dst, unsigned* __restrict__ A,
                       unsigned* __restrict__ eidx){
  int e = blockIdx.x * 256 + threadIdx.x;
  if (e < N_EDGES) eidx[atomicAdd(&A[dst[e]], 1u)] = (unsigned)e;
}
// post-fill: A[d] == offsets[d+1]; node d range = [d? A[d-1]:0, A[d])

__global__ void k_init(unsigned* __restrict__ sel32, unsigned* __restrict__ krem,
                       unsigned* __restrict__ cnt, unsigned* __restrict__ done,
                       unsigned* __restrict__ ccnt, unsigned* __restrict__ cbelow,
                       unsigned* __restrict__ bcnt, unsigned* __restrict__ cntless,
                       u64* __restrict__ gsums){
  int t = threadIdx.x;
  if (t < 4){ sel32[t]=0; krem[t]=RANK0; cnt[t]=0; ccnt[t]=0; cbelow[t]=0; cntless[t]=0; }
  if (t < 8) gsums[t] = 0;
  if (t == 0){ done[0] = 0; bcnt[0] = 0; }
}

// ======== transpose fc/fq to [col][k] for refine ========
__global__ void k_prept(const float* __restrict__ fc, const float* __restrict__ fq,
                        float* __restrict__ fcT, float* __restrict__ fqT){
  int i = blockIdx.x * 256 + threadIdx.x;
  if (i >= IN_DIM * 128) return;
  int k = i >> 7, c = i & 127;
  fcT[(size_t)c * 256 + k] = fc[i];
  fqT[(size_t)c * 256 + k] = fq[i];
}

// ======== single f32 GEMM: fcq[50000][384] = h @ [Wl^T | fc | fq] ========
#define BM 128
#define BK 16
__global__ __launch_bounds__(256) void k_gemm384(const float* __restrict__ A,
    const float* __restrict__ Wl, const float* __restrict__ fc,
    const float* __restrict__ fq, float* __restrict__ C){
  __shared__ float As[BK][BM + 4];
  __shared__ float Bs[BK][128 + 4];
  int tid = threadIdx.x;
  int m0 = blockIdx.x * BM;
  int n0 = blockIdx.y * 128;               // 0:ft(Wl^T)  128:fc  256:fq
  int ty = tid / 16, tx = tid % 16;
  float acc[8][8];
  #pragma unroll
  for (int i = 0; i < 8; i++)
    #pragma unroll
    for (int j = 0; j < 8; j++) acc[i][j] = 0.f;

  for (int k0 = 0; k0 < IN_DIM; k0 += BK){
    #pragma unroll
    for (int i = 0; i < 2; i++){
      int s = tid * 2 + i;
      int row = s >> 2, c4 = s & 3;
      int r = m0 + row;
      float4 v = make_float4(0.f, 0.f, 0.f, 0.f);
      if (r < N_NODES) v = *(const float4*)&A[(size_t)r * IN_DIM + k0 + c4 * 4];
      As[c4 * 4 + 0][row] = v.x; As[c4 * 4 + 1][row] = v.y;
      As[c4 * 4 + 2][row] = v.z; As[c4 * 4 + 3][row] = v.w;
    }
    if (n0 == 0){
      #pragma unroll
      for (int i = 0; i < 2; i++){
        int s = tid * 2 + i;
        int j = s >> 2, c4 = s & 3;        // Bs[k][j] = Wl[j][k0+k]
        float4 v = *(const float4*)&Wl[(size_t)j * IN_DIM + k0 + c4 * 4];
        Bs[c4 * 4 + 0][j] = v.x; Bs[c4 * 4 + 1][j] = v.y;
        Bs[c4 * 4 + 2][j] = v.z; Bs[c4 * 4 + 3][j] = v.w;
      }
    } else {
      const float* Bsrc = (n0 == 128) ? fc : fq;
      #pragma unroll
      for (int i = 0; i < 2; i++){
        int s = tid * 2 + i;
        int kr = s >> 5, c4 = s & 31;
        *(float4*)&Bs[kr][c4 * 4] = *(const float4*)&Bsrc[(size_t)(k0 + kr) * 128 + c4 * 4];
      }
    }
    __syncthreads();
    #pragma unroll
    for (int kk = 0; kk < BK; kk++){
      float4 a0 = *(const float4*)&As[kk][ty * 4];
      float4 a1 = *(const float4*)&As[kk][64 + ty * 4];
      float4 b0 = *(const float4*)&Bs[kk][tx * 4];
      float4 b1 = *(const float4*)&Bs[kk][64 + tx * 4];
      float av[8] = {a0.x, a0.y, a0.z, a0.w, a1.x, a1.y, a1.z, a1.w};
      float bv[8] = {b0.x, b0.y, b0.z, b0.w, b1.x, b1.y, b1.z, b1.w};
      #pragma unroll
      for (int i = 0; i < 8; i++)
        #pragma unroll
        for (int j = 0; j < 8; j++)
          acc[i][j] = fmaf(av[i], bv[j], acc[i][j]);
    }
    __syncthreads();
  }
  #pragma unroll
  for (int i = 0; i < 8; i++){
    int r = m0 + ((i < 4) ? (ty * 4 + i) : (64 + ty * 4 + (i - 4)));
    if (r >= N_NODES) continue;
    *(float4*)&C[(size_t)r * 384 + n0 + tx * 4]      = make_float4(acc[i][0], acc[i][1], acc[i][2], acc[i][3]);
    *(float4*)&C[(size_t)r * 384 + n0 + 64 + tx * 4] = make_float4(acc[i][4], acc[i][5], acc[i][6], acc[i][7]);
  }
}

// ======== f32 fused edge logits + softmax (wave per dst; deterministic) ========
__global__ __launch_bounds__(256) void k_softedge32(const float* __restrict__ fcq,
    const int* __restrict__ src, const unsigned* __restrict__ A,
    const unsigned* __restrict__ eidx, float* __restrict__ abuf){
  __shared__ float lds_a[4][DEG_CAP * 4];
  int d = blockIdx.x * 4 + (threadIdx.x >> 6);
  int t = threadIdx.x & 63;
  int wv = threadIdx.x >> 6;
  if (d >= N_NODES) return;
  unsigned k0 = d ? A[d - 1] : 0u, k1 = A[d];
  if (k0 == k1) return;
  float2 c = *(const float2*)&fcq[(size_t)d * 384 + 128 + t * 2];
  float m = -1.0e30f;
  int sn = src[eidx[k0]];
  float2 qn = *(const float2*)&fcq[(size_t)sn * 384 + 256 + t * 2];
  for (unsigned k = k0; k < k1; k++){
    float2 q = qn;
    if (k + 1 < k1){
      int s2 = src[eidx[k + 1]];
      qn = *(const float2*)&fcq[(size_t)s2 * 384 + 256 + t * 2];
    }
    float val = (q.x - c.x) * c.x + (q.y - c.y) * c.y;
    val += __shfl_xor(val, 1);
    val += __shfl_xor(val, 2);
    val += __shfl_xor(val, 4);
    val += __shfl_xor(val, 8);
    float a = (val > 0.f) ? val : expm1f(val);   // ELU
    m = fmaxf(m, a);
    if ((t & 15) == 0) lds_a[wv][(k - k0) * 4 + (t >> 4)] = a;
  }
  float mm = __shfl(m, (t & 3) * 16);
  unsigned nj = (k1 - k0) * 4;
  long long sfx = 0;
  for (unsigned jj = t; jj < nj; jj += 64){
    float ex = __expf(lds_a[wv][jj] - mm);       // jj%4 == t%4
    lds_a[wv][jj] = ex;
    sfx += (long long)llrintf(ex * (float)SC_32);
  }
  #pragma unroll
  for (int msk = 4; msk < 64; msk <<= 1) sfx += __shfl_xor(sfx, msk);
  float sd = (float)((double)sfx * (1.0 / SC_32));
  for (unsigned jj = t; jj < nj; jj += 64)
    abuf[(size_t)k0 * 4 + jj] = lds_a[wv][jj] / sd;
}

// ======== f32 radix select (u32 keys; attn > 0 -> bits ordered) ========
__global__ __launch_bounds__(256) void k_hp32(const float* __restrict__ attn,
    unsigned* __restrict__ sel32, unsigned* __restrict__ krem, unsigned* __restrict__ cnt,
    unsigned* __restrict__ hist, unsigned* __restrict__ done, unsigned maskHi, int shift){
  __shared__ unsigned lh[1024];
  __shared__ unsigned ticket;
  for (int j = threadIdx.x; j < 1024; j += 256) lh[j] = 0;
  __syncthreads();
  int i0 = blockIdx.x * 256 + threadIdx.x;
  int hh = i0 & 3;
  unsigned sel = sel32[hh] & maskHi;
  const int total = N_EDGES * 4;
  for (int i = i0; i < total; i += gridDim.x * 256){
    unsigned u = __float_as_uint(attn[i]);
    if ((u & maskHi) == sel)
      atomicAdd(&lh[hh * 256 + ((u >> shift) & 255u)], 1u);
  }
  __syncthreads();
  for (int j = threadIdx.x; j < 1024; j += 256)
    if (lh[j]) atomicAdd(&hist[j], lh[j]);
  __threadfence();
  if (threadIdx.x == 0) ticket = atomicAdd(done, 1u);
  __syncthreads();
  if (ticket == gridDim.x - 1){
    __threadfence();
    for (int j = threadIdx.x; j < 1024; j += 256){ lh[j] = hist[j]; hist[j] = 0; }
    __syncthreads();
    if (threadIdx.x < 4){
      int t = threadIdx.x;
      unsigned kr = krem[t], cum = 0, b = 0;
      for (; b < 256; b++){
        unsigned c2 = lh[t * 256 + b];
        if (kr < cum + c2) break;
        cum += c2;
      }
      sel32[t] |= b << shift;
      krem[t] = kr - cum;
      cnt[t] += cum;
    }
    if (threadIdx.x == 0) *done = 0;
  }
}

__global__ __launch_bounds__(256) void k_compact32(const float* __restrict__ attn,
    const unsigned* __restrict__ sel32, unsigned* __restrict__ ccnt,
    float* __restrict__ cand){
  __shared__ unsigned lcnt[4];
  __shared__ unsigned lbase[4];
  int t = threadIdx.x;
  if (t < 4) lcnt[t] = 0;
  __syncthreads();
  int i0 = blockIdx.x * 256 + t;
  int hh = i0 & 3;
  unsigned sel = sel32[hh] & 0xFFFF0000u;
  const int total = N_EDGES * 4;
  unsigned mc = 0;
  for (int i = i0; i < total; i += gridDim.x * 256){
    unsigned u = __float_as_uint(attn[i]);
    if ((u & 0xFFFF0000u) == sel) mc++;
  }
  unsigned my_local = mc ? atomicAdd(&lcnt[hh], mc) : 0u;
  __syncthreads();
  if (t < 4) lbase[t] = lcnt[t] ? atomicAdd(&ccnt[t], lcnt[t]) : 0u;
  __syncthreads();
  if (mc == 0) return;
  unsigned pos = lbase[hh] + my_local;
  float* cp = cand + (size_t)hh * N_EDGES;
  for (int i = i0; i < total; i += gridDim.x * 256){
    float v = attn[i];
    unsigned u = __float_as_uint(v);
    if ((u & 0xFFFF0000u) == sel) cp[pos++] = v;
  }
}

__global__ __launch_bounds__(256) void k_fin32(const float* __restrict__ cand,
    const unsigned* __restrict__ ccnt, unsigned* __restrict__ sel32,
    unsigned* __restrict__ krem, unsigned* __restrict__ cnt,
    unsigned* __restrict__ hist, unsigned* __restrict__ done, int shift){
  __shared__ unsigned lh[256];
  __shared__ unsigned ticket;
  int t = threadIdx.x;
  lh[t] = 0;
  __syncthreads();
  int h = blockIdx.x & 3;
  int bidx = blockIdx.x >> 2;
  int bph = gridDim.x >> 2;
  unsigned maskHi = ~((1u << (shift + 8)) - 1u);
  unsigned sel = sel32[h] & maskHi;
  unsigned n = ccnt[h];
  const float* cp = cand + (size_t)h * N_EDGES;
  for (unsigned i = bidx * 256 + t; i < n; i += bph * 256){
    unsigned u = __float_as_uint(cp[i]);
    if ((u & maskHi) == sel) atomicAdd(&lh[(u >> shift) & 255u], 1u);
  }
  __syncthreads();
  if (lh[t]) atomicAdd(&hist[h * 256 + t], lh[t]);
  __threadfence();
  if (t == 0) ticket = atomicAdd(done, 1u);
  __syncthreads();
  if (ticket == gridDim.x - 1){
    __threadfence();
    __shared__ unsigned fh[1024];
    for (int j = t; j < 1024; j += 256){ fh[j] = hist[j]; hist[j] = 0; }
    __syncthreads();
    if (t < 4){
      unsigned kr = krem[t], cum = 0, b = 0;
      for (; b < 256; b++){
        unsigned c2 = fh[t * 256 + b];
        if (kr < cum + c2) break;
        cum += c2;
      }
      sel32[t] |= b << shift;
      krem[t] = kr - cum;
      cnt[t] += cum;
    }
    if (t == 0) *done = 0;
  }
}

// ======== mark boundary candidates (attn32 in [thd*(1-MARG), thd*(1+MARG)]) ====
__global__ __launch_bounds__(256) void k_bmark(const float* __restrict__ attn,
    const unsigned* __restrict__ sel32, unsigned* __restrict__ cbelow,
    unsigned* __restrict__ bcnt, unsigned* __restrict__ blist){
  int t = threadIdx.x;
  int i0 = blockIdx.x * 256 + t;
  int hh = t & 3;
  double thd = (double)__uint_as_float(sel32[hh]);
  double lo = thd * (1.0 - MARG), hi = thd * (1.0 + MARG);
  unsigned below = 0;
  const int total = N_EDGES * 4;
  for (int i = i0; i < total; i += gridDim.x * 256){
    double v = (double)attn[i];
    if (v < lo) below++;
    else if (v <= hi){
      unsigned p = atomicAdd(bcnt, 1u);
      if (p < BCAP) blist[p] = (unsigned)i;
    }
  }
  #pragma unroll
  for (int m = 4; m < 64; m <<= 1) below += __shfl_xor(below, m);
  __shared__ unsigned sb[16];
  int wv = t >> 6;
  if ((t & 63) < 4) sb[wv * 4 + hh] = below;
  __syncthreads();
  if (t < 4){
    unsigned b = sb[t] + sb[4 + t] + sb[8 + t] + sb[12 + t];
    if (b) atomicAdd(&cbelow[t], b);
  }
}

// ======== exact f64 boundary refine: block/entry, LDS-staged weights ========
// blist entries are ABUF indices: slot = csr_slot*4 + head.
// wqs[col][k] stride 257 -> bank (col+k)%32, conflict-free scalar reads.
__global__ __launch_bounds__(256) void k_brefine(const float* __restrict__ h,
    const float* __restrict__ fcT, const float* __restrict__ fqT,
    const int* __restrict__ src, const int* __restrict__ dst,
    const unsigned* __restrict__ A, const unsigned* __restrict__ eidx,
    const unsigned* __restrict__ blist, const unsigned* __restrict__ bcnt,
    double* __restrict__ bval){
  __shared__ float wqs[32][257];
  __shared__ double cs[32];
  __shared__ double la[DEG_CAP];
  int tid = threadIdx.x;
  int wv = tid >> 6;
  int l = tid & 63;
  int j = l & 31;               // column within head
  int khalf = l >> 5;           // k-range half (0:[0,128) 1:[128,256))
  unsigned nb = *bcnt; if (nb > BCAP) nb = BCAP;
  for (unsigned idx = blockIdx.x; idx < nb; idx += gridDim.x){
    unsigned slot = blist[idx];
    unsigned kslot = slot >> 2;              // CSR position
    int hh = slot & 3;
    int d = dst[eidx[kslot]];
    unsigned k0 = d ? A[d - 1] : 0u, k1 = A[d];
    unsigned deg = k1 - k0;
    // ---- stage fq head slice (32KB) into LDS, conflict-free layout ----
    {
      int col = tid >> 3, seg = tid & 7;     // 32 floats per (col,seg)
      const float* gsrc = fqT + (size_t)(hh * 32 + col) * 256 + seg * 32;
      #pragma unroll
      for (int r = 0; r < 8; r++){
        float4 v = *(const float4*)&gsrc[r * 4];
        float* wdst = &wqs[col][seg * 32 + r * 4];
        wdst[0] = v.x; wdst[1] = v.y; wdst[2] = v.z; wdst[3] = v.w;
      }
    }
    __syncthreads();
    // ---- c-dot by wave 0 only (k-split halves), broadcast via cs[] ----
    if (wv == 0){
      const float* hd = h + (size_t)d * 256 + khalf * 128;
      const float* wc = fcT + (size_t)(hh * 32 + j) * 256 + khalf * 128;
      double c0 = 0.0, c1 = 0.0, c2 = 0.0, c3 = 0.0;
      #pragma unroll 8
      for (int i = 0; i < 128; i += 4){
        float4 hv = *(const float4*)&hd[i];
        float4 w2 = *(const float4*)&wc[i];
        c0 = fma((double)hv.x, (double)w2.x, c0);
        c1 = fma((double)hv.y, (double)w2.y, c1);
        c2 = fma((double)hv.z, (double)w2.z, c2);
        c3 = fma((double)hv.w, (double)w2.w, c3);
      }
      double c = (c0 + c1) + (c2 + c3);
      c += __shfl_xor(c, 32);                // combine k-halves
      if (l < 32) cs[l] = c;
    }
    __syncthreads();
    double cj = cs[j];
    // ---- q-dots: wave wv handles edges k0+wv, +4, ... ----
    for (unsigned k = k0 + wv; k < k1; k += 4){
      int s = src[eidx[k]];
      const float* hs = h + (size_t)s * 256 + khalf * 128;
      const float* wr = &wqs[j][khalf * 128];
      float4 hv = *(const float4*)&hs[0];
      double q0 = 0.0, q1 = 0.0, q2 = 0.0, q3 = 0.0;
      #pragma unroll 4
      for (int i = 0; i < 128; i += 4){
        float4 cur = hv;
        if (i + 4 < 128) hv = *(const float4*)&hs[i + 4];
        q0 = fma((double)cur.x, (double)wr[i + 0], q0);
        q1 = fma((double)cur.y, (double)wr[i + 1], q1);
        q2 = fma((double)cur.z, (double)wr[i + 2], q2);
        q3 = fma((double)cur.w, (double)wr[i + 3], q3);
      }
      double q = (q0 + q1) + (q2 + q3);
      q += __shfl_xor(q, 32);                // full-range dot for col j
      double p = (q - cj) * cj;
      p += __shfl_xor(p, 1);
      p += __shfl_xor(p, 2);
      p += __shfl_xor(p, 4);
      p += __shfl_xor(p, 8);
      p += __shfl_xor(p, 16);
      double a = (p > 0.0) ? p : expm1(p);
      if (l == 0) la[k - k0] = a;
    }
    __syncthreads();
    // ---- wave 0: max + fixed-point denominator + target ----
    if (wv == 0){
      double m = -1.0e300;
      for (unsigned kk = l; kk < deg; kk += 64) m = fmax(m, la[kk]);
      #pragma unroll
      for (int msk = 1; msk < 64; msk <<= 1) m = fmax(m, __shfl_xor(m, msk));
      long long sfx = 0;
      for (unsigned kk = l; kk < deg; kk += 64)
        sfx += llrint(exp(la[kk] - m) * SC_FX);
      #pragma unroll
      for (int msk = 1; msk < 64; msk <<= 1) sfx += __shfl_xor(sfx, msk);
      if (l == 0){
        double sd = (double)sfx * (1.0 / SC_FX);
        bval[idx] = exp(la[kslot - k0] - m) / sd;
      }
    }
    __syncthreads();   // protect wqs/la before next grid-stride iteration
  }
}

// ======== exact f64 select among boundary (1 block per head) ========
__global__ __launch_bounds__(256) void k_bselect(const double* __restrict__ bval,
    const unsigned* __restrict__ blist, const unsigned* __restrict__ bcnt,
    const unsigned* __restrict__ cbelow, double* __restrict__ thd64,
    unsigned* __restrict__ cntless){
  __shared__ unsigned lh[256];
  __shared__ u64 s_sel;
  __shared__ unsigned s_kr, s_cnt;
  int hsel = blockIdx.x;
  int t = threadIdx.x;
  unsigned nb = *bcnt; if (nb > BCAP) nb = BCAP;
  if (t == 0){ s_sel = 0; s_kr = RANK0 - cbelow[hsel]; s_cnt = 0; }
  __syncthreads();
  for (int p = 0; p < 8; p++){
    int shift = 56 - 8 * p;
    u64 maskHi = (p == 0) ? 0ull : (~0ull) << (64 - 8 * p);
    lh[t] = 0;
    __syncthreads();
    u64 sel = s_sel;
    for (unsigned i = t; i < nb; i += 256){
      if ((int)(blist[i] & 3) == hsel){
        u64 u = (u64)__double_as_longlong(bval[i]);
        if ((u & maskHi) == sel) atomicAdd(&lh[(unsigned)((u >> shift) & 255u)], 1u);
      }
    }
    __syncthreads();
    if (t == 0){
      unsigned kr = s_kr, cum = 0, b = 0;
      for (; b < 256; b++){
        unsigned c2 = lh[b];
        if (kr < cum + c2) break;
        cum += c2;
      }
      s_sel |= ((u64)b) << shift;
      s_kr = kr - cum;
      s_cnt += cum;
    }
    __syncthreads();
  }
  if (t == 0){
    thd64[hsel] = __longlong_as_double((long long)s_sel);
    cntless[hsel] = cbelow[hsel] + s_cnt;
  }
}

// ======== sums for certain edges + a3 (boundary deferred to k_bfinal) ========
__global__ __launch_bounds__(256) void k_sums32(const float* __restrict__ attn,
    const unsigned* __restrict__ sel32, u64* __restrict__ gsums, float* __restrict__ a3){
  int t = threadIdx.x;
  int i0 = blockIdx.x * 256 + t;
  int hh = t & 3;
  double thd = (double)__uint_as_float(sel32[hh]);
  double lo = thd * (1.0 - MARG), hi = thd * (1.0 + MARG);
  double al = 0.0, ag = 0.0;
  const int total = N_EDGES * 4;
  for (int i = i0; i < total; i += gridDim.x * 256){
    float vf = attn[i];
    double v = (double)vf;
    if (v < lo){ al += v; a3[i] = 0.f; }
    else if (v > hi){ ag += v; a3[i] = vf; }
    else a3[i] = 0.f;                      // boundary: fixed by k_bfinal
  }
  long long ql = llrint(al * SC_FX);
  long long qg = llrint(ag * SC_FX);
  #pragma unroll
  for (int m = 4; m < 64; m <<= 1){
    ql += __shfl_xor(ql, m);
    qg += __shfl_xor(qg, m);
  }
  __shared__ long long sl[16], sg[16];
  int wv = t >> 6;
  if ((t & 63) < 4){ sl[wv * 4 + hh] = ql; sg[wv * 4 + hh] = qg; }
  __syncthreads();
  if (t < 4){
    long long a = sl[t] + sl[4 + t] + sl[8 + t] + sl[12 + t];
    long long b = sg[t] + sg[4 + t] + sg[8 + t] + sg[12 + t];
    if (a) atomicAdd(&gsums[t],     (u64)a);
    if (b) atomicAdd(&gsums[4 + t], (u64)b);
  }
}

// ======== finalize boundary entries: exact cut + sums + a3 ========
__global__ void k_bfinal(const unsigned* __restrict__ blist, const double* __restrict__ bval,
    const unsigned* __restrict__ bcnt, const double* __restrict__ thd64,
    u64* __restrict__ gsums, float* __restrict__ a3){
  unsigned nb = *bcnt; if (nb > BCAP) nb = BCAP;
  for (unsigned idx = blockIdx.x * 256 + threadIdx.x; idx < nb; idx += gridDim.x * 256){
    unsigned slot = blist[idx];
    int hh = slot & 3;
    double v = bval[idx];
    bool kept = (v >= thd64[hh]);
    a3[slot] = kept ? (float)v : 0.f;
    atomicAdd(&gsums[(kept ? 4 : 0) + hh], (u64)llrint(v * SC_FX));
  }
}

__global__ void k_ratio(const double* __restrict__ thd64, const unsigned* __restrict__ cntless,
                        const u64* __restrict__ gsums, double* __restrict__ trd){
  int t = threadIdx.x;
  if (t < 4){
    double sless = (double)(long long)gsums[t]     * (1.0 / SC_FX);
    double sge   = (double)(long long)gsums[4 + t] * (1.0 / SC_FX);
    double topk  = sless + (double)(LS - (int)cntless[t]) * thd64[t];
    trd[t] = thd64[t];
    trd[4 + t] = (sge + topk) / sge;
  }
}

// ======== CSR gather-scatter (wave per dst; ft at fcq cols 0-127) ========
__global__ __launch_bounds__(256) void k_scatter2(const float* __restrict__ fcq,
    const int* __restrict__ src, const unsigned* __restrict__ A,
    const unsigned* __restrict__ eidx, const float* __restrict__ a3,
    const double* __restrict__ trd, float* __restrict__ out){
  int d = blockIdx.x * 4 + (threadIdx.x >> 6);
  int t = threadIdx.x & 63;
  if (d >= N_NODES) return;
  int hh = t >> 4;
  double ratio = trd[4 + hh];
  unsigned k0 = d ? A[d - 1] : 0u, k1 = A[d];
  long long acc0 = 0, acc1 = 0;
  float wn = (k0 < k1) ? a3[(size_t)k0 * 4 + hh] : 0.f;
  unsigned en = (k0 < k1) ? eidx[k0] : 0u;
  for (unsigned k = k0; k < k1; k++){
    float w = wn;
    unsigned e = en;
    if (k + 1 < k1){ wn = a3[(size_t)(k + 1) * 4 + hh]; en = eidx[k + 1]; }
    if (__ballot(w != 0.f) == 0ull) continue;    // ~71% dropped
    if (w != 0.f){
      int s = src[e];
      float2 f = *(const float2*)&fcq[(size_t)s * 384 + t * 2];
      double a3r = (double)w * ratio;
      acc0 += llrint(a3r * (double)f.x * SC_FX);
      acc1 += llrint(a3r * (double)f.y * SC_FX);
    }
  }
  float* p = &out[(size_t)d * OUTC + t * 2];
  p[0] = (float)((double)acc0 * (1.0 / SC_FX));
  p[1] = (float)((double)acc1 * (1.0 / SC_FX));
}

// ======== head-mean (runs last; ft at fcq cols 0-127) ========
__global__ void k_mean(const float* __restrict__ fcq, float* __restrict__ out){
  int i = blockIdx.x * 256 + threadIdx.x;
  if (i >= N_NODES * DH) return;
  int n = i / DH, dd = i % DH;
  const float* p = fcq + (size_t)n * 384;
  out[(size_t)n * OUTC + 128 + dd] = 0.25f * (p[dd] + p[32 + dd] + p[64 + dd] + p[96 + dd]);
}

extern "C" void kernel_launch(void* const* d_in, const int* in_sizes, int n_in,
                              void* d_out, int out_size, void* d_ws, size_t ws_size,
                              hipStream_t stream){
  const float* h  = (const float*)d_in[0];
  const float* Wl = (const float*)d_in[1];
  const float* fc = (const float*)d_in[2];
  const float* fq = (const float*)d_in[3];
  const int* src  = (const int*)d_in[4];
  const int* dst  = (const int*)d_in[5];
  float* out = (float*)d_out;

  char* ws = (char*)d_ws;
  float*    fcq  = (float*)(ws);                   // 76,800,000
  unsigned* A    = (unsigned*)(ws + 76800000);     // 200,004 (pad to 77,000,064)
  unsigned* eidx = (unsigned*)(ws + 77000064);     // 3,200,000
  float*    a3   = (float*)(ws + 80200064);        // 12,800,000
  unsigned* hist = (unsigned*)(ws + 93000064);     // 4,096
  unsigned* sel32  = (unsigned*)(ws + 93004160);   // 16
  unsigned* krem   = (unsigned*)(ws + 93004176);   // 16
  unsigned* cnt    = (unsigned*)(ws + 93004192);   // 16
  unsigned* done   = (unsigned*)(ws + 93004208);   // 16
  unsigned* ccnt   = (unsigned*)(ws + 93004224);   // 16
  unsigned* cbelow = (unsigned*)(ws + 93004240);   // 16
  unsigned* bcnt   = (unsigned*)(ws + 93004256);   // 16
  unsigned* cntless= (unsigned*)(ws + 93004272);   // 16
  u64*      gsums  = (u64*)(ws + 93004288);        // 64
  double*   thd64  = (double*)(ws + 93004352);     // 32
  double*   trd    = (double*)(ws + 93004416);     // 64
  unsigned* blist  = (unsigned*)(ws + 93008896);   // 262,144 (BCAP*4)
  double*   bval   = (double*)(ws + 93271040);     // 524,288 (BCAP*8)
  float*    fcT    = (float*)(ws + 93795328);      // 131,072
  float*    fqT    = (float*)(ws + 93926400);      // 131,072

  // scratch inside d_out (32 MB): both fully dead before scatter2/mean write
  float* abuf = (float*)d_out;                     // 12.8 MB attn32
  float* cand = (float*)((char*)d_out + 12800000); // 12.8 MB select candidates

  hipMemsetAsync(A, 0, 200004, stream);
  hipMemsetAsync(hist, 0, 4096, stream);
  k_init<<<1, 64, 0, stream>>>(sel32, krem, cnt, done, ccnt, cbelow, bcnt, cntless, gsums);
  k_prept<<<(IN_DIM * 128 + 255) / 256, 256, 0, stream>>>(fc, fq, fcT, fqT);

  // CSR
  k_deg<<<(N_EDGES + 255) / 256, 256, 0, stream>>>(dst, A);
  k_scan<<<1, 1024, 0, stream>>>(A);
  k_fill<<<(N_EDGES + 255) / 256, 256, 0, stream>>>(dst, A, eidx);

  // single f32 GEMM -> [ft | c | q]
  dim3 gg((N_NODES + BM - 1) / BM, 3);
  k_gemm384<<<gg, 256, 0, stream>>>(h, Wl, fc, fq, fcq);

  // f32 fused edge logits + softmax
  k_softedge32<<<(N_NODES + 3) / 4, 256, 0, stream>>>(fcq, src, A, eidx, abuf);

  // exact f32 rank select: 2 global passes, compact, 2 finish passes
  k_hp32<<<1024, 256, 0, stream>>>(abuf, sel32, krem, cnt, hist, done, 0u, 24);
  k_hp32<<<1024, 256, 0, stream>>>(abuf, sel32, krem, cnt, hist, done, 0xFF000000u, 16);
  k_compact32<<<1024, 256, 0, stream>>>(abuf, sel32, ccnt, cand);
  k_fin32<<<256, 256, 0, stream>>>(cand, ccnt, sel32, krem, cnt, hist, done, 8);
  k_fin32<<<256, 256, 0, stream>>>(cand, ccnt, sel32, krem, cnt, hist, done, 0);

  // boundary: mark, refine in f64 (block per entry, LDS weights), exact select
  k_bmark<<<1024, 256, 0, stream>>>(abuf, sel32, cbelow, bcnt, blist);
  k_brefine<<<2048, 256, 0, stream>>>(h, fcT, fqT, src, dst, A, eidx, blist, bcnt, bval);
  k_bselect<<<4, 256, 0, stream>>>(bval, blist, bcnt, cbelow, thd64, cntless);

  // sums + a3 (+ boundary fixes) + ratio
  k_sums32<<<2048, 256, 0, stream>>>(abuf, sel32, gsums, a3);
  k_bfinal<<<64, 256, 0, stream>>>(blist, bval, bcnt, thd64, gsums, a3);
  k_ratio<<<1, 64, 0, stream>>>(thd64, cntless, gsums, trd);

  // output
  k_scatter2<<<(N_NODES + 3) / 4, 256, 0, stream>>>(fcq, src, A, eidx, a3, trd, out);
  k_mean<<<(N_NODES * DH + 255) / 256, 256, 0, stream>>>(fcq, out);
}

// Round 17
// 978.810 us; speedup vs baseline: 1.5957x; 1.0539x over previous
//
#include <hip/hip_runtime.h>
#include <hip/hip_bf16.h>
#include <math.h>

#define N_NODES 50000
#define N_EDGES 800000
#define DH 32
#define IN_DIM 256
#define OUTC 160
#define LS 570400     // int(0.713 * 800000) -> exactly 570400
#define RANK0 (LS - 1)
#define DEG_CAP 160   // max in-degree supported (Poisson(16))
#define BCAP 65536    // boundary-candidate cap (expect ~1K)
#define MARG 3.0e-4   // relative margin around thd32 (~30x worst f32 error)

typedef unsigned long long u64;
#define SC_FX 1099511627776.0   // 2^40 fixed-point scale (f64 sums)
#define SC_32 4294967296.0      // 2^32 fixed-point scale (f32 softmax denom)

// ======== CSR build ========
__global__ void k_deg(const int* __restrict__ dst, unsigned* __restrict__ A){
  int e = blockIdx.x * 256 + threadIdx.x;
  if (e < N_EDGES) atomicAdd(&A[dst[e]], 1u);
}

__global__ __launch_bounds__(1024) void k_scan(unsigned* __restrict__ A){
  __shared__ unsigned ps[1024];
  int t = threadIdx.x;
  const int CH = (N_NODES + 1023) / 1024;
  int base = t * CH;
  unsigned s = 0;
  for (int i = 0; i < CH; i++){ int n = base + i; if (n < N_NODES) s += A[n]; }
  ps[t] = s;
  __syncthreads();
  for (int off = 1; off < 1024; off <<= 1){
    unsigned v = (t >= off) ? ps[t - off] : 0;
    __syncthreads();
    ps[t] += v;
    __syncthreads();
  }
  unsigned ex = (t == 0) ? 0 : ps[t - 1];
  for (int i = 0; i < CH; i++){
    int n = base + i;
    if (n < N_NODES){ unsigned dv = A[n]; A[n] = ex; ex += dv; }
  }
}

__global__ void k_fill(const int* __restrict__ dst, unsigned* __restrict__ A,
                       unsigned* __restrict__ eidx){
  int e = blockIdx.x * 256 + threadIdx.x;
  if (e < N_EDGES) eidx[atomicAdd(&A[dst[e]], 1u)] = (unsigned)e;
}
// post-fill: A[d] == offsets[d+1]; node d range = [d? A[d-1]:0, A[d])

__global__ void k_init(unsigned* __restrict__ sel32, unsigned* __restrict__ krem,
                       unsigned* __restrict__ cnt, unsigned* __restrict__ done,
                       unsigned* __restrict__ ccnt, unsigned* __restrict__ cbelow,
                       unsigned* __restrict__ bcnt, unsigned* __restrict__ cntless,
                       u64* __restrict__ gsums){
  int t = threadIdx.x;
  if (t < 4){ sel32[t]=0; krem[t]=RANK0; cnt[t]=0; ccnt[t]=0; cbelow[t]=0; cntless[t]=0; }
  if (t < 8) gsums[t] = 0;
  if (t == 0){ done[0] = 0; bcnt[0] = 0; }
}

// ======== transpose fc/fq to [col][k] for refine ========
__global__ void k_prept(const float* __restrict__ fc, const float* __restrict__ fq,
                        float* __restrict__ fcT, float* __restrict__ fqT){
  int i = blockIdx.x * 256 + threadIdx.x;
  if (i >= IN_DIM * 128) return;
  int k = i >> 7, c = i & 127;
  fcT[(size_t)c * 256 + k] = fc[i];
  fqT[(size_t)c * 256 + k] = fq[i];
}

// ======== single f32 GEMM: fcq[50000][384] = h @ [Wl^T | fc | fq] ========
#define BM 128
#define BK 16
__global__ __launch_bounds__(256) void k_gemm384(const float* __restrict__ A,
    const float* __restrict__ Wl, const float* __restrict__ fc,
    const float* __restrict__ fq, float* __restrict__ C){
  __shared__ float As[BK][BM + 4];
  __shared__ float Bs[BK][128 + 4];
  int tid = threadIdx.x;
  int m0 = blockIdx.x * BM;
  int n0 = blockIdx.y * 128;               // 0:ft(Wl^T)  128:fc  256:fq
  int ty = tid / 16, tx = tid % 16;
  float acc[8][8];
  #pragma unroll
  for (int i = 0; i < 8; i++)
    #pragma unroll
    for (int j = 0; j < 8; j++) acc[i][j] = 0.f;

  for (int k0 = 0; k0 < IN_DIM; k0 += BK){
    #pragma unroll
    for (int i = 0; i < 2; i++){
      int s = tid * 2 + i;
      int row = s >> 2, c4 = s & 3;
      int r = m0 + row;
      float4 v = make_float4(0.f, 0.f, 0.f, 0.f);
      if (r < N_NODES) v = *(const float4*)&A[(size_t)r * IN_DIM + k0 + c4 * 4];
      As[c4 * 4 + 0][row] = v.x; As[c4 * 4 + 1][row] = v.y;
      As[c4 * 4 + 2][row] = v.z; As[c4 * 4 + 3][row] = v.w;
    }
    if (n0 == 0){
      #pragma unroll
      for (int i = 0; i < 2; i++){
        int s = tid * 2 + i;
        int j = s >> 2, c4 = s & 3;        // Bs[k][j] = Wl[j][k0+k]
        float4 v = *(const float4*)&Wl[(size_t)j * IN_DIM + k0 + c4 * 4];
        Bs[c4 * 4 + 0][j] = v.x; Bs[c4 * 4 + 1][j] = v.y;
        Bs[c4 * 4 + 2][j] = v.z; Bs[c4 * 4 + 3][j] = v.w;
      }
    } else {
      const float* Bsrc = (n0 == 128) ? fc : fq;
      #pragma unroll
      for (int i = 0; i < 2; i++){
        int s = tid * 2 + i;
        int kr = s >> 5, c4 = s & 31;
        *(float4*)&Bs[kr][c4 * 4] = *(const float4*)&Bsrc[(size_t)(k0 + kr) * 128 + c4 * 4];
      }
    }
    __syncthreads();
    #pragma unroll
    for (int kk = 0; kk < BK; kk++){
      float4 a0 = *(const float4*)&As[kk][ty * 4];
      float4 a1 = *(const float4*)&As[kk][64 + ty * 4];
      float4 b0 = *(const float4*)&Bs[kk][tx * 4];
      float4 b1 = *(const float4*)&Bs[kk][64 + tx * 4];
      float av[8] = {a0.x, a0.y, a0.z, a0.w, a1.x, a1.y, a1.z, a1.w};
      float bv[8] = {b0.x, b0.y, b0.z, b0.w, b1.x, b1.y, b1.z, b1.w};
      #pragma unroll
      for (int i = 0; i < 8; i++)
        #pragma unroll
        for (int j = 0; j < 8; j++)
          acc[i][j] = fmaf(av[i], bv[j], acc[i][j]);
    }
    __syncthreads();
  }
  #pragma unroll
  for (int i = 0; i < 8; i++){
    int r = m0 + ((i < 4) ? (ty * 4 + i) : (64 + ty * 4 + (i - 4)));
    if (r >= N_NODES) continue;
    *(float4*)&C[(size_t)r * 384 + n0 + tx * 4]      = make_float4(acc[i][0], acc[i][1], acc[i][2], acc[i][3]);
    *(float4*)&C[(size_t)r * 384 + n0 + 64 + tx * 4] = make_float4(acc[i][4], acc[i][5], acc[i][6], acc[i][7]);
  }
}

// ======== f32 fused edge logits + softmax: 2 dst per wave, float4 lanes ========
// half-wave (32 lanes) serves one dst; lane ll covers dims [ll*4, ll*4+4);
// head of lane = ll>>3; per-head reduce = shfl_xor 1,2,4 (8 lanes).
__global__ __launch_bounds__(256) void k_softedge32(const float* __restrict__ fcq,
    const int* __restrict__ src, const unsigned* __restrict__ A,
    const unsigned* __restrict__ eidx, float* __restrict__ abuf){
  __shared__ float lds_a[8][DEG_CAP * 4];
  int tid = threadIdx.x;
  int wv = tid >> 6;
  int l = tid & 63;
  int half = l >> 5;
  int ll = l & 31;
  int ds = wv * 2 + half;                 // dst slot in block (0..7)
  int d = blockIdx.x * 8 + ds;
  bool ok = (d < N_NODES);
  unsigned k0 = 0, k1 = 0;
  if (ok){ k0 = d ? A[d - 1] : 0u; k1 = A[d]; }
  unsigned deg = k1 - k0;                 // uniform within half-wave
  float4 c4 = make_float4(0.f, 0.f, 0.f, 0.f);
  float4 q4n = make_float4(0.f, 0.f, 0.f, 0.f);
  if (deg){
    c4 = *(const float4*)&fcq[(size_t)d * 384 + 128 + ll * 4];
    int sn = src[eidx[k0]];
    q4n = *(const float4*)&fcq[(size_t)sn * 384 + 256 + ll * 4];
  }
  float m = -1.0e30f;
  for (unsigned kk = 0; kk < deg; kk++){
    float4 q4 = q4n;
    if (kk + 1 < deg){
      int s2 = src[eidx[k0 + kk + 1]];
      q4n = *(const float4*)&fcq[(size_t)s2 * 384 + 256 + ll * 4];
    }
    float v = (q4.x - c4.x) * c4.x;
    v = fmaf(q4.y - c4.y, c4.y, v);
    v = fmaf(q4.z - c4.z, c4.z, v);
    v = fmaf(q4.w - c4.w, c4.w, v);
    v += __shfl_xor(v, 1);
    v += __shfl_xor(v, 2);
    v += __shfl_xor(v, 4);
    float a = (v > 0.f) ? v : expm1f(v);   // ELU; identical across 8-lane group
    m = fmaxf(m, a);                       // running max of head (ll>>3)
    if ((ll & 7) == 0) lds_a[ds][kk * 4 + (ll >> 3)] = a;
  }
  // denominator phase: lane ll handles slots jj ≡ ll (mod 32); head = ll&3
  float mm = __shfl(m, half * 32 + (ll & 3) * 8);   // max of head (ll&3)
  unsigned nj = deg * 4;
  long long sfx = 0;
  for (unsigned jj = ll; jj < nj; jj += 32){
    float ex = __expf(lds_a[ds][jj] - mm);
    lds_a[ds][jj] = ex;
    sfx += (long long)llrintf(ex * (float)SC_32);
  }
  sfx += __shfl_xor(sfx, 4);
  sfx += __shfl_xor(sfx, 8);
  sfx += __shfl_xor(sfx, 16);
  if (deg){
    float sd = (float)((double)sfx * (1.0 / SC_32));
    for (unsigned jj = ll; jj < nj; jj += 32)
      abuf[(size_t)k0 * 4 + jj] = lds_a[ds][jj] / sd;
  }
}

// ======== f32 radix select (u32 keys; attn > 0 -> bits ordered) ========
__global__ __launch_bounds__(256) void k_hp32(const float* __restrict__ attn,
    unsigned* __restrict__ sel32, unsigned* __restrict__ krem, unsigned* __restrict__ cnt,
    unsigned* __restrict__ hist, unsigned* __restrict__ done, unsigned maskHi, int shift){
  __shared__ unsigned lh[1024];
  __shared__ unsigned ticket;
  for (int j = threadIdx.x; j < 1024; j += 256) lh[j] = 0;
  __syncthreads();
  int i0 = blockIdx.x * 256 + threadIdx.x;
  int hh = i0 & 3;
  unsigned sel = sel32[hh] & maskHi;
  const int total = N_EDGES * 4;
  for (int i = i0; i < total; i += gridDim.x * 256){
    unsigned u = __float_as_uint(attn[i]);
    if ((u & maskHi) == sel)
      atomicAdd(&lh[hh * 256 + ((u >> shift) & 255u)], 1u);
  }
  __syncthreads();
  for (int j = threadIdx.x; j < 1024; j += 256)
    if (lh[j]) atomicAdd(&hist[j], lh[j]);
  __threadfence();
  if (threadIdx.x == 0) ticket = atomicAdd(done, 1u);
  __syncthreads();
  if (ticket == gridDim.x - 1){
    __threadfence();
    for (int j = threadIdx.x; j < 1024; j += 256){ lh[j] = hist[j]; hist[j] = 0; }
    __syncthreads();
    if (threadIdx.x < 4){
      int t = threadIdx.x;
      unsigned kr = krem[t], cum = 0, b = 0;
      for (; b < 256; b++){
        unsigned c2 = lh[t * 256 + b];
        if (kr < cum + c2) break;
        cum += c2;
      }
      sel32[t] |= b << shift;
      krem[t] = kr - cum;
      cnt[t] += cum;
    }
    if (threadIdx.x == 0) *done = 0;
  }
}

__global__ __launch_bounds__(256) void k_compact32(const float* __restrict__ attn,
    const unsigned* __restrict__ sel32, unsigned* __restrict__ ccnt,
    float* __restrict__ cand){
  __shared__ unsigned lcnt[4];
  __shared__ unsigned lbase[4];
  int t = threadIdx.x;
  if (t < 4) lcnt[t] = 0;
  __syncthreads();
  int i0 = blockIdx.x * 256 + t;
  int hh = i0 & 3;
  unsigned sel = sel32[hh] & 0xFFFF0000u;
  const int total = N_EDGES * 4;
  unsigned mc = 0;
  for (int i = i0; i < total; i += gridDim.x * 256){
    unsigned u = __float_as_uint(attn[i]);
    if ((u & 0xFFFF0000u) == sel) mc++;
  }
  unsigned my_local = mc ? atomicAdd(&lcnt[hh], mc) : 0u;
  __syncthreads();
  if (t < 4) lbase[t] = lcnt[t] ? atomicAdd(&ccnt[t], lcnt[t]) : 0u;
  __syncthreads();
  if (mc == 0) return;
  unsigned pos = lbase[hh] + my_local;
  float* cp = cand + (size_t)hh * N_EDGES;
  for (int i = i0; i < total; i += gridDim.x * 256){
    float v = attn[i];
    unsigned u = __float_as_uint(v);
    if ((u & 0xFFFF0000u) == sel) cp[pos++] = v;
  }
}

__global__ __launch_bounds__(256) void k_fin32(const float* __restrict__ cand,
    const unsigned* __restrict__ ccnt, unsigned* __restrict__ sel32,
    unsigned* __restrict__ krem, unsigned* __restrict__ cnt,
    unsigned* __restrict__ hist, unsigned* __restrict__ done, int shift){
  __shared__ unsigned lh[256];
  __shared__ unsigned ticket;
  int t = threadIdx.x;
  lh[t] = 0;
  __syncthreads();
  int h = blockIdx.x & 3;
  int bidx = blockIdx.x >> 2;
  int bph = gridDim.x >> 2;
  unsigned maskHi = ~((1u << (shift + 8)) - 1u);
  unsigned sel = sel32[h] & maskHi;
  unsigned n = ccnt[h];
  const float* cp = cand + (size_t)h * N_EDGES;
  for (unsigned i = bidx * 256 + t; i < n; i += bph * 256){
    unsigned u = __float_as_uint(cp[i]);
    if ((u & maskHi) == sel) atomicAdd(&lh[(u >> shift) & 255u], 1u);
  }
  __syncthreads();
  if (lh[t]) atomicAdd(&hist[h * 256 + t], lh[t]);
  __threadfence();
  if (t == 0) ticket = atomicAdd(done, 1u);
  __syncthreads();
  if (ticket == gridDim.x - 1){
    __threadfence();
    __shared__ unsigned fh[1024];
    for (int j = t; j < 1024; j += 256){ fh[j] = hist[j]; hist[j] = 0; }
    __syncthreads();
    if (t < 4){
      unsigned kr = krem[t], cum = 0, b = 0;
      for (; b < 256; b++){
        unsigned c2 = fh[t * 256 + b];
        if (kr < cum + c2) break;
        cum += c2;
      }
      sel32[t] |= b << shift;
      krem[t] = kr - cum;
      cnt[t] += cum;
    }
    if (t == 0) *done = 0;
  }
}

// ======== mark boundary candidates (attn32 in [thd*(1-MARG), thd*(1+MARG)]) ====
__global__ __launch_bounds__(256) void k_bmark(const float* __restrict__ attn,
    const unsigned* __restrict__ sel32, unsigned* __restrict__ cbelow,
    unsigned* __restrict__ bcnt, unsigned* __restrict__ blist){
  int t = threadIdx.x;
  int i0 = blockIdx.x * 256 + t;
  int hh = t & 3;
  double thd = (double)__uint_as_float(sel32[hh]);
  double lo = thd * (1.0 - MARG), hi = thd * (1.0 + MARG);
  unsigned below = 0;
  const int total = N_EDGES * 4;
  for (int i = i0; i < total; i += gridDim.x * 256){
    double v = (double)attn[i];
    if (v < lo) below++;
    else if (v <= hi){
      unsigned p = atomicAdd(bcnt, 1u);
      if (p < BCAP) blist[p] = (unsigned)i;
    }
  }
  #pragma unroll
  for (int m = 4; m < 64; m <<= 1) below += __shfl_xor(below, m);
  __shared__ unsigned sb[16];
  int wv = t >> 6;
  if ((t & 63) < 4) sb[wv * 4 + hh] = below;
  __syncthreads();
  if (t < 4){
    unsigned b = sb[t] + sb[4 + t] + sb[8 + t] + sb[12 + t];
    if (b) atomicAdd(&cbelow[t], b);
  }
}

// ======== exact f64 boundary refine: block/entry, LDS-staged weights ========
__global__ __launch_bounds__(256) void k_brefine(const float* __restrict__ h,
    const float* __restrict__ fcT, const float* __restrict__ fqT,
    const int* __restrict__ src, const int* __restrict__ dst,
    const unsigned* __restrict__ A, const unsigned* __restrict__ eidx,
    const unsigned* __restrict__ blist, const unsigned* __restrict__ bcnt,
    double* __restrict__ bval){
  __shared__ float wqs[32][257];
  __shared__ double cs[32];
  __shared__ double la[DEG_CAP];
  int tid = threadIdx.x;
  int wv = tid >> 6;
  int l = tid & 63;
  int j = l & 31;
  int khalf = l >> 5;
  unsigned nb = *bcnt; if (nb > BCAP) nb = BCAP;
  for (unsigned idx = blockIdx.x; idx < nb; idx += gridDim.x){
    unsigned slot = blist[idx];
    unsigned kslot = slot >> 2;
    int hh = slot & 3;
    int d = dst[eidx[kslot]];
    unsigned k0 = d ? A[d - 1] : 0u, k1 = A[d];
    unsigned deg = k1 - k0;
    {
      int col = tid >> 3, seg = tid & 7;
      const float* gsrc = fqT + (size_t)(hh * 32 + col) * 256 + seg * 32;
      #pragma unroll
      for (int r = 0; r < 8; r++){
        float4 v = *(const float4*)&gsrc[r * 4];
        float* wdst = &wqs[col][seg * 32 + r * 4];
        wdst[0] = v.x; wdst[1] = v.y; wdst[2] = v.z; wdst[3] = v.w;
      }
    }
    __syncthreads();
    if (wv == 0){
      const float* hd = h + (size_t)d * 256 + khalf * 128;
      const float* wc = fcT + (size_t)(hh * 32 + j) * 256 + khalf * 128;
      double c0 = 0.0, c1 = 0.0, c2 = 0.0, c3 = 0.0;
      #pragma unroll 8
      for (int i = 0; i < 128; i += 4){
        float4 hv = *(const float4*)&hd[i];
        float4 w2 = *(const float4*)&wc[i];
        c0 = fma((double)hv.x, (double)w2.x, c0);
        c1 = fma((double)hv.y, (double)w2.y, c1);
        c2 = fma((double)hv.z, (double)w2.z, c2);
        c3 = fma((double)hv.w, (double)w2.w, c3);
      }
      double c = (c0 + c1) + (c2 + c3);
      c += __shfl_xor(c, 32);
      if (l < 32) cs[l] = c;
    }
    __syncthreads();
    double cj = cs[j];
    for (unsigned k = k0 + wv; k < k1; k += 4){
      int s = src[eidx[k]];
      const float* hs = h + (size_t)s * 256 + khalf * 128;
      const float* wr = &wqs[j][khalf * 128];
      float4 hv = *(const float4*)&hs[0];
      double q0 = 0.0, q1 = 0.0, q2 = 0.0, q3 = 0.0;
      #pragma unroll 4
      for (int i = 0; i < 128; i += 4){
        float4 cur = hv;
        if (i + 4 < 128) hv = *(const float4*)&hs[i + 4];
        q0 = fma((double)cur.x, (double)wr[i + 0], q0);
        q1 = fma((double)cur.y, (double)wr[i + 1], q1);
        q2 = fma((double)cur.z, (double)wr[i + 2], q2);
        q3 = fma((double)cur.w, (double)wr[i + 3], q3);
      }
      double q = (q0 + q1) + (q2 + q3);
      q += __shfl_xor(q, 32);
      double p = (q - cj) * cj;
      p += __shfl_xor(p, 1);
      p += __shfl_xor(p, 2);
      p += __shfl_xor(p, 4);
      p += __shfl_xor(p, 8);
      p += __shfl_xor(p, 16);
      double a = (p > 0.0) ? p : expm1(p);
      if (l == 0) la[k - k0] = a;
    }
    __syncthreads();
    if (wv == 0){
      double m = -1.0e300;
      for (unsigned kk = l; kk < deg; kk += 64) m = fmax(m, la[kk]);
      #pragma unroll
      for (int msk = 1; msk < 64; msk <<= 1) m = fmax(m, __shfl_xor(m, msk));
      long long sfx = 0;
      for (unsigned kk = l; kk < deg; kk += 64)
        sfx += llrint(exp(la[kk] - m) * SC_FX);
      #pragma unroll
      for (int msk = 1; msk < 64; msk <<= 1) sfx += __shfl_xor(sfx, msk);
      if (l == 0){
        double sd = (double)sfx * (1.0 / SC_FX);
        bval[idx] = exp(la[kslot - k0] - m) / sd;
      }
    }
    __syncthreads();
  }
}

// ======== exact f64 select among boundary (1 block per head) ========
__global__ __launch_bounds__(256) void k_bselect(const double* __restrict__ bval,
    const unsigned* __restrict__ blist, const unsigned* __restrict__ bcnt,
    const unsigned* __restrict__ cbelow, double* __restrict__ thd64,
    unsigned* __restrict__ cntless){
  __shared__ unsigned lh[256];
  __shared__ u64 s_sel;
  __shared__ unsigned s_kr, s_cnt;
  int hsel = blockIdx.x;
  int t = threadIdx.x;
  unsigned nb = *bcnt; if (nb > BCAP) nb = BCAP;
  if (t == 0){ s_sel = 0; s_kr = RANK0 - cbelow[hsel]; s_cnt = 0; }
  __syncthreads();
  for (int p = 0; p < 8; p++){
    int shift = 56 - 8 * p;
    u64 maskHi = (p == 0) ? 0ull : (~0ull) << (64 - 8 * p);
    lh[t] = 0;
    __syncthreads();
    u64 sel = s_sel;
    for (unsigned i = t; i < nb; i += 256){
      if ((int)(blist[i] & 3) == hsel){
        u64 u = (u64)__double_as_longlong(bval[i]);
        if ((u & maskHi) == sel) atomicAdd(&lh[(unsigned)((u >> shift) & 255u)], 1u);
      }
    }
    __syncthreads();
    if (t == 0){
      unsigned kr = s_kr, cum = 0, b = 0;
      for (; b < 256; b++){
        unsigned c2 = lh[b];
        if (kr < cum + c2) break;
        cum += c2;
      }
      s_sel |= ((u64)b) << shift;
      s_kr = kr - cum;
      s_cnt += cum;
    }
    __syncthreads();
  }
  if (t == 0){
    thd64[hsel] = __longlong_as_double((long long)s_sel);
    cntless[hsel] = cbelow[hsel] + s_cnt;
  }
}

// ======== sums for certain edges + a3 (boundary deferred to k_bfinal) ========
__global__ __launch_bounds__(256) void k_sums32(const float* __restrict__ attn,
    const unsigned* __restrict__ sel32, u64* __restrict__ gsums, float* __restrict__ a3){
  int t = threadIdx.x;
  int i0 = blockIdx.x * 256 + t;
  int hh = t & 3;
  double thd = (double)__uint_as_float(sel32[hh]);
  double lo = thd * (1.0 - MARG), hi = thd * (1.0 + MARG);
  double al = 0.0, ag = 0.0;
  const int total = N_EDGES * 4;
  for (int i = i0; i < total; i += gridDim.x * 256){
    float vf = attn[i];
    double v = (double)vf;
    if (v < lo){ al += v; a3[i] = 0.f; }
    else if (v > hi){ ag += v; a3[i] = vf; }
    else a3[i] = 0.f;                      // boundary: fixed by k_bfinal
  }
  long long ql = llrint(al * SC_FX);
  long long qg = llrint(ag * SC_FX);
  #pragma unroll
  for (int m = 4; m < 64; m <<= 1){
    ql += __shfl_xor(ql, m);
    qg += __shfl_xor(qg, m);
  }
  __shared__ long long sl[16], sg[16];
  int wv = t >> 6;
  if ((t & 63) < 4){ sl[wv * 4 + hh] = ql; sg[wv * 4 + hh] = qg; }
  __syncthreads();
  if (t < 4){
    long long a = sl[t] + sl[4 + t] + sl[8 + t] + sl[12 + t];
    long long b = sg[t] + sg[4 + t] + sg[8 + t] + sg[12 + t];
    if (a) atomicAdd(&gsums[t],     (u64)a);
    if (b) atomicAdd(&gsums[4 + t], (u64)b);
  }
}

// ======== finalize boundary entries: exact cut + sums + a3 ========
__global__ void k_bfinal(const unsigned* __restrict__ blist, const double* __restrict__ bval,
    const unsigned* __restrict__ bcnt, const double* __restrict__ thd64,
    u64* __restrict__ gsums, float* __restrict__ a3){
  unsigned nb = *bcnt; if (nb > BCAP) nb = BCAP;
  for (unsigned idx = blockIdx.x * 256 + threadIdx.x; idx < nb; idx += gridDim.x * 256){
    unsigned slot = blist[idx];
    int hh = slot & 3;
    double v = bval[idx];
    bool kept = (v >= thd64[hh]);
    a3[slot] = kept ? (float)v : 0.f;
    atomicAdd(&gsums[(kept ? 4 : 0) + hh], (u64)llrint(v * SC_FX));
  }
}

__global__ void k_ratio(const double* __restrict__ thd64, const unsigned* __restrict__ cntless,
                        const u64* __restrict__ gsums, double* __restrict__ trd){
  int t = threadIdx.x;
  if (t < 4){
    double sless = (double)(long long)gsums[t]     * (1.0 / SC_FX);
    double sge   = (double)(long long)gsums[4 + t] * (1.0 / SC_FX);
    double topk  = sless + (double)(LS - (int)cntless[t]) * thd64[t];
    trd[t] = thd64[t];
    trd[4 + t] = (sge + topk) / sge;
  }
}

// ======== CSR gather-scatter (wave per dst; ft at fcq cols 0-127) ========
__global__ __launch_bounds__(256) void k_scatter2(const float* __restrict__ fcq,
    const int* __restrict__ src, const unsigned* __restrict__ A,
    const unsigned* __restrict__ eidx, const float* __restrict__ a3,
    const double* __restrict__ trd, float* __restrict__ out){
  int d = blockIdx.x * 4 + (threadIdx.x >> 6);
  int t = threadIdx.x & 63;
  if (d >= N_NODES) return;
  int hh = t >> 4;
  double ratio = trd[4 + hh];
  unsigned k0 = d ? A[d - 1] : 0u, k1 = A[d];
  long long acc0 = 0, acc1 = 0;
  float wn = (k0 < k1) ? a3[(size_t)k0 * 4 + hh] : 0.f;
  unsigned en = (k0 < k1) ? eidx[k0] : 0u;
  for (unsigned k = k0; k < k1; k++){
    float w = wn;
    unsigned e = en;
    if (k + 1 < k1){ wn = a3[(size_t)(k + 1) * 4 + hh]; en = eidx[k + 1]; }
    if (__ballot(w != 0.f) == 0ull) continue;    // ~71% dropped
    if (w != 0.f){
      int s = src[e];
      float2 f = *(const float2*)&fcq[(size_t)s * 384 + t * 2];
      double a3r = (double)w * ratio;
      acc0 += llrint(a3r * (double)f.x * SC_FX);
      acc1 += llrint(a3r * (double)f.y * SC_FX);
    }
  }
  float* p = &out[(size_t)d * OUTC + t * 2];
  p[0] = (float)((double)acc0 * (1.0 / SC_FX));
  p[1] = (float)((double)acc1 * (1.0 / SC_FX));
}

// ======== head-mean (runs last; ft at fcq cols 0-127) ========
__global__ void k_mean(const float* __restrict__ fcq, float* __restrict__ out){
  int i = blockIdx.x * 256 + threadIdx.x;
  if (i >= N_NODES * DH) return;
  int n = i / DH, dd = i % DH;
  const float* p = fcq + (size_t)n * 384;
  out[(size_t)n * OUTC + 128 + dd] = 0.25f * (p[dd] + p[32 + dd] + p[64 + dd] + p[96 + dd]);
}

extern "C" void kernel_launch(void* const* d_in, const int* in_sizes, int n_in,
                              void* d_out, int out_size, void* d_ws, size_t ws_size,
                              hipStream_t stream){
  const float* h  = (const float*)d_in[0];
  const float* Wl = (const float*)d_in[1];
  const float* fc = (const float*)d_in[2];
  const float* fq = (const float*)d_in[3];
  const int* src  = (const int*)d_in[4];
  const int* dst  = (const int*)d_in[5];
  float* out = (float*)d_out;

  char* ws = (char*)d_ws;
  float*    fcq  = (float*)(ws);                   // 76,800,000
  unsigned* A    = (unsigned*)(ws + 76800000);     // 200,004 (pad to 77,000,064)
  unsigned* eidx = (unsigned*)(ws + 77000064);     // 3,200,000
  float*    a3   = (float*)(ws + 80200064);        // 12,800,000
  unsigned* hist = (unsigned*)(ws + 93000064);     // 4,096
  unsigned* sel32  = (unsigned*)(ws + 93004160);   // 16
  unsigned* krem   = (unsigned*)(ws + 93004176);   // 16
  unsigned* cnt    = (unsigned*)(ws + 93004192);   // 16
  unsigned* done   = (unsigned*)(ws + 93004208);   // 16
  unsigned* ccnt   = (unsigned*)(ws + 93004224);   // 16
  unsigned* cbelow = (unsigned*)(ws + 93004240);   // 16
  unsigned* bcnt   = (unsigned*)(ws + 93004256);   // 16
  unsigned* cntless= (unsigned*)(ws + 93004272);   // 16
  u64*      gsums  = (u64*)(ws + 93004288);        // 64
  double*   thd64  = (double*)(ws + 93004352);     // 32
  double*   trd    = (double*)(ws + 93004416);     // 64
  unsigned* blist  = (unsigned*)(ws + 93008896);   // 262,144 (BCAP*4)
  double*   bval   = (double*)(ws + 93271040);     // 524,288 (BCAP*8)
  float*    fcT    = (float*)(ws + 93795328);      // 131,072
  float*    fqT    = (float*)(ws + 93926400);      // 131,072

  // scratch inside d_out (32 MB): both fully dead before scatter2/mean write
  float* abuf = (float*)d_out;                     // 12.8 MB attn32
  float* cand = (float*)((char*)d_out + 12800000); // 12.8 MB select candidates

  hipMemsetAsync(A, 0, 200004, stream);
  hipMemsetAsync(hist, 0, 4096, stream);
  k_init<<<1, 64, 0, stream>>>(sel32, krem, cnt, done, ccnt, cbelow, bcnt, cntless, gsums);
  k_prept<<<(IN_DIM * 128 + 255) / 256, 256, 0, stream>>>(fc, fq, fcT, fqT);

  // CSR
  k_deg<<<(N_EDGES + 255) / 256, 256, 0, stream>>>(dst, A);
  k_scan<<<1, 1024, 0, stream>>>(A);
  k_fill<<<(N_EDGES + 255) / 256, 256, 0, stream>>>(dst, A, eidx);

  // single f32 GEMM -> [ft | c | q]
  dim3 gg((N_NODES + BM - 1) / BM, 3);
  k_gemm384<<<gg, 256, 0, stream>>>(h, Wl, fc, fq, fcq);

  // f32 fused edge logits + softmax (2 dst per wave)
  k_softedge32<<<(N_NODES + 7) / 8, 256, 0, stream>>>(fcq, src, A, eidx, abuf);

  // exact f32 rank select: 2 global passes, compact, 2 finish passes
  k_hp32<<<1024, 256, 0, stream>>>(abuf, sel32, krem, cnt, hist, done, 0u, 24);
  k_hp32<<<1024, 256, 0, stream>>>(abuf, sel32, krem, cnt, hist, done, 0xFF000000u, 16);
  k_compact32<<<1024, 256, 0, stream>>>(abuf, sel32, ccnt, cand);
  k_fin32<<<256, 256, 0, stream>>>(cand, ccnt, sel32, krem, cnt, hist, done, 8);
  k_fin32<<<256, 256, 0, stream>>>(cand, ccnt, sel32, krem, cnt, hist, done, 0);

  // boundary: mark, refine in f64 (block per entry, LDS weights), exact select
  k_bmark<<<1024, 256, 0, stream>>>(abuf, sel32, cbelow, bcnt, blist);
  k_brefine<<<2048, 256, 0, stream>>>(h, fcT, fqT, src, dst, A, eidx, blist, bcnt, bval);
  k_bselect<<<4, 256, 0, stream>>>(bval, blist, bcnt, cbelow, thd64, cntless);

  // sums + a3 (+ boundary fixes) + ratio
  k_sums32<<<2048, 256, 0, stream>>>(abuf, sel32, gsums, a3);
  k_bfinal<<<64, 256, 0, stream>>>(blist, bval, bcnt, thd64, gsums, a3);
  k_ratio<<<1, 64, 0, stream>>>(thd64, cntless, gsums, trd);

  // output
  k_scatter2<<<(N_NODES + 3) / 4, 256, 0, stream>>>(fcq, src, A, eidx, a3, trd, out);
  k_mean<<<(N_NODES * DH + 255) / 256, 256, 0, stream>>>(fcq, out);
}

// Round 18
// 965.671 us; speedup vs baseline: 1.6174x; 1.0136x over previous
//
#include <hip/hip_runtime.h>
#include <hip/hip_bf16.h>
#include <math.h>

#define N_NODES 50000
#define N_EDGES 800000
#define DH 32
#define IN_DIM 256
#define OUTC 160
#define LS 570400     // int(0.713 * 800000) -> exactly 570400
#define RANK0 (LS - 1)
#define DEG_CAP 160   // max in-degree supported (Poisson(16))
#define BCAP 65536    // boundary-candidate cap (expect ~1K)
#define MARG 3.0e-4   // relative margin around thd32 (~30x worst f32 error)

typedef unsigned long long u64;
#define SC_FX 1099511627776.0   // 2^40 fixed-point scale (f64 sums)
#define SC_32 4294967296.0      // 2^32 fixed-point scale (f32 softmax denom)

// ======== CSR build ========
__global__ void k_deg(const int* __restrict__ dst, unsigned* __restrict__ A){
  int e = blockIdx.x * 256 + threadIdx.x;
  if (e < N_EDGES) atomicAdd(&A[dst[e]], 1u);
}

__global__ __launch_bounds__(1024) void k_scan(unsigned* __restrict__ A){
  __shared__ unsigned ps[1024];
  int t = threadIdx.x;
  const int CH = (N_NODES + 1023) / 1024;
  int base = t * CH;
  unsigned s = 0;
  for (int i = 0; i < CH; i++){ int n = base + i; if (n < N_NODES) s += A[n]; }
  ps[t] = s;
  __syncthreads();
  for (int off = 1; off < 1024; off <<= 1){
    unsigned v = (t >= off) ? ps[t - off] : 0;
    __syncthreads();
    ps[t] += v;
    __syncthreads();
  }
  unsigned ex = (t == 0) ? 0 : ps[t - 1];
  for (int i = 0; i < CH; i++){
    int n = base + i;
    if (n < N_NODES){ unsigned dv = A[n]; A[n] = ex; ex += dv; }
  }
}

__global__ void k_fill(const int* __restrict__ dst, unsigned* __restrict__ A,
                       unsigned* __restrict__ eidx){
  int e = blockIdx.x * 256 + threadIdx.x;
  if (e < N_EDGES) eidx[atomicAdd(&A[dst[e]], 1u)] = (unsigned)e;
}
// post-fill: A[d] == offsets[d+1]; node d range = [d? A[d-1]:0, A[d])

__global__ void k_init(unsigned* __restrict__ sel32, unsigned* __restrict__ krem,
                       unsigned* __restrict__ cnt, unsigned* __restrict__ done,
                       unsigned* __restrict__ ccnt, unsigned* __restrict__ cbelow,
                       unsigned* __restrict__ bcnt, unsigned* __restrict__ cntless,
                       u64* __restrict__ gsums){
  int t = threadIdx.x;
  if (t < 4){ sel32[t]=0; krem[t]=RANK0; cnt[t]=0; ccnt[t]=0; cbelow[t]=0; cntless[t]=0; }
  if (t < 8) gsums[t] = 0;
  if (t == 0){ done[0] = 0; bcnt[0] = 0; }
}

// ======== transpose fc/fq to [col][k] for refine ========
__global__ void k_prept(const float* __restrict__ fc, const float* __restrict__ fq,
                        float* __restrict__ fcT, float* __restrict__ fqT){
  int i = blockIdx.x * 256 + threadIdx.x;
  if (i >= IN_DIM * 128) return;
  int k = i >> 7, c = i & 127;
  fcT[(size_t)c * 256 + k] = fc[i];
  fqT[(size_t)c * 256 + k] = fq[i];
}

// ======== single f32 GEMM with register-prefetch pipeline ========
#define BM 128
#define BK 16
__global__ __launch_bounds__(256) void k_gemm384(const float* __restrict__ A,
    const float* __restrict__ Wl, const float* __restrict__ fc,
    const float* __restrict__ fq, float* __restrict__ C){
  __shared__ float As[BK][BM + 4];
  __shared__ float Bs[BK][128 + 4];
  int tid = threadIdx.x;
  int m0 = blockIdx.x * BM;
  int n0 = blockIdx.y * 128;               // 0:ft(Wl^T)  128:fc  256:fq
  int ty = tid / 16, tx = tid % 16;
  const float* Bsrc = (n0 == 128) ? fc : fq;

  // per-thread staging coordinates
  int sA0r = (tid * 2) >> 2,     sA0c = (tid * 2) & 3;
  int sA1r = (tid * 2 + 1) >> 2, sA1c = (tid * 2 + 1) & 3;
  int sW0j = sA0r, sW0c = sA0c;            // n0==0: Wl[j][k0+c4*4]
  int sW1j = sA1r, sW1c = sA1c;
  int sB0k = (tid * 2) >> 5,     sB0c = (tid * 2) & 31;
  int sB1k = (tid * 2 + 1) >> 5, sB1c = (tid * 2 + 1) & 31;

  float acc[8][8];
  #pragma unroll
  for (int i = 0; i < 8; i++)
    #pragma unroll
    for (int j = 0; j < 8; j++) acc[i][j] = 0.f;

  float4 rA0, rA1, rB0, rB1;
  // prologue: load k0 = 0
  {
    int r0 = m0 + sA0r, r1 = m0 + sA1r;
    rA0 = (r0 < N_NODES) ? *(const float4*)&A[(size_t)r0 * IN_DIM + sA0c * 4] : make_float4(0,0,0,0);
    rA1 = (r1 < N_NODES) ? *(const float4*)&A[(size_t)r1 * IN_DIM + sA1c * 4] : make_float4(0,0,0,0);
    if (n0 == 0){
      rB0 = *(const float4*)&Wl[(size_t)sW0j * IN_DIM + sW0c * 4];
      rB1 = *(const float4*)&Wl[(size_t)sW1j * IN_DIM + sW1c * 4];
    } else {
      rB0 = *(const float4*)&Bsrc[(size_t)sB0k * 128 + sB0c * 4];
      rB1 = *(const float4*)&Bsrc[(size_t)sB1k * 128 + sB1c * 4];
    }
  }

  for (int k0 = 0; k0 < IN_DIM; k0 += BK){
    // publish current tile to LDS
    As[sA0c * 4 + 0][sA0r] = rA0.x; As[sA0c * 4 + 1][sA0r] = rA0.y;
    As[sA0c * 4 + 2][sA0r] = rA0.z; As[sA0c * 4 + 3][sA0r] = rA0.w;
    As[sA1c * 4 + 0][sA1r] = rA1.x; As[sA1c * 4 + 1][sA1r] = rA1.y;
    As[sA1c * 4 + 2][sA1r] = rA1.z; As[sA1c * 4 + 3][sA1r] = rA1.w;
    if (n0 == 0){
      Bs[sW0c * 4 + 0][sW0j] = rB0.x; Bs[sW0c * 4 + 1][sW0j] = rB0.y;
      Bs[sW0c * 4 + 2][sW0j] = rB0.z; Bs[sW0c * 4 + 3][sW0j] = rB0.w;
      Bs[sW1c * 4 + 0][sW1j] = rB1.x; Bs[sW1c * 4 + 1][sW1j] = rB1.y;
      Bs[sW1c * 4 + 2][sW1j] = rB1.z; Bs[sW1c * 4 + 3][sW1j] = rB1.w;
    } else {
      *(float4*)&Bs[sB0k][sB0c * 4] = rB0;
      *(float4*)&Bs[sB1k][sB1c * 4] = rB1;
    }
    __syncthreads();
    // prefetch next tile into registers (latency hidden under FMA phase)
    if (k0 + BK < IN_DIM){
      int kn = k0 + BK;
      int r0 = m0 + sA0r, r1 = m0 + sA1r;
      rA0 = (r0 < N_NODES) ? *(const float4*)&A[(size_t)r0 * IN_DIM + kn + sA0c * 4] : make_float4(0,0,0,0);
      rA1 = (r1 < N_NODES) ? *(const float4*)&A[(size_t)r1 * IN_DIM + kn + sA1c * 4] : make_float4(0,0,0,0);
      if (n0 == 0){
        rB0 = *(const float4*)&Wl[(size_t)sW0j * IN_DIM + kn + sW0c * 4];
        rB1 = *(const float4*)&Wl[(size_t)sW1j * IN_DIM + kn + sW1c * 4];
      } else {
        rB0 = *(const float4*)&Bsrc[(size_t)(kn + sB0k) * 128 + sB0c * 4];
        rB1 = *(const float4*)&Bsrc[(size_t)(kn + sB1k) * 128 + sB1c * 4];
      }
    }
    #pragma unroll
    for (int kk = 0; kk < BK; kk++){
      float4 a0 = *(const float4*)&As[kk][ty * 4];
      float4 a1 = *(const float4*)&As[kk][64 + ty * 4];
      float4 b0 = *(const float4*)&Bs[kk][tx * 4];
      float4 b1 = *(const float4*)&Bs[kk][64 + tx * 4];
      float av[8] = {a0.x, a0.y, a0.z, a0.w, a1.x, a1.y, a1.z, a1.w};
      float bv[8] = {b0.x, b0.y, b0.z, b0.w, b1.x, b1.y, b1.z, b1.w};
      #pragma unroll
      for (int i = 0; i < 8; i++)
        #pragma unroll
        for (int j = 0; j < 8; j++)
          acc[i][j] = fmaf(av[i], bv[j], acc[i][j]);
    }
    __syncthreads();
  }
  #pragma unroll
  for (int i = 0; i < 8; i++){
    int r = m0 + ((i < 4) ? (ty * 4 + i) : (64 + ty * 4 + (i - 4)));
    if (r >= N_NODES) continue;
    *(float4*)&C[(size_t)r * 384 + n0 + tx * 4]      = make_float4(acc[i][0], acc[i][1], acc[i][2], acc[i][3]);
    *(float4*)&C[(size_t)r * 384 + n0 + 64 + tx * 4] = make_float4(acc[i][4], acc[i][5], acc[i][6], acc[i][7]);
  }
}

// ======== f32 fused edge logits + softmax: 2 dst per wave, float4 lanes ========
__global__ __launch_bounds__(256) void k_softedge32(const float* __restrict__ fcq,
    const int* __restrict__ src, const unsigned* __restrict__ A,
    const unsigned* __restrict__ eidx, float* __restrict__ abuf){
  __shared__ float lds_a[8][DEG_CAP * 4];
  int tid = threadIdx.x;
  int wv = tid >> 6;
  int l = tid & 63;
  int half = l >> 5;
  int ll = l & 31;
  int ds = wv * 2 + half;                 // dst slot in block (0..7)
  int d = blockIdx.x * 8 + ds;
  bool ok = (d < N_NODES);
  unsigned k0 = 0, k1 = 0;
  if (ok){ k0 = d ? A[d - 1] : 0u; k1 = A[d]; }
  unsigned deg = k1 - k0;                 // uniform within half-wave
  float4 c4 = make_float4(0.f, 0.f, 0.f, 0.f);
  float4 q4n = make_float4(0.f, 0.f, 0.f, 0.f);
  if (deg){
    c4 = *(const float4*)&fcq[(size_t)d * 384 + 128 + ll * 4];
    int sn = src[eidx[k0]];
    q4n = *(const float4*)&fcq[(size_t)sn * 384 + 256 + ll * 4];
  }
  float m = -1.0e30f;
  for (unsigned kk = 0; kk < deg; kk++){
    float4 q4 = q4n;
    if (kk + 1 < deg){
      int s2 = src[eidx[k0 + kk + 1]];
      q4n = *(const float4*)&fcq[(size_t)s2 * 384 + 256 + ll * 4];
    }
    float v = (q4.x - c4.x) * c4.x;
    v = fmaf(q4.y - c4.y, c4.y, v);
    v = fmaf(q4.z - c4.z, c4.z, v);
    v = fmaf(q4.w - c4.w, c4.w, v);
    v += __shfl_xor(v, 1);
    v += __shfl_xor(v, 2);
    v += __shfl_xor(v, 4);
    float a = (v > 0.f) ? v : expm1f(v);   // ELU; identical across 8-lane group
    m = fmaxf(m, a);
    if ((ll & 7) == 0) lds_a[ds][kk * 4 + (ll >> 3)] = a;
  }
  float mm = __shfl(m, half * 32 + (ll & 3) * 8);   // max of head (ll&3)
  unsigned nj = deg * 4;
  long long sfx = 0;
  for (unsigned jj = ll; jj < nj; jj += 32){
    float ex = __expf(lds_a[ds][jj] - mm);
    lds_a[ds][jj] = ex;
    sfx += (long long)llrintf(ex * (float)SC_32);
  }
  sfx += __shfl_xor(sfx, 4);
  sfx += __shfl_xor(sfx, 8);
  sfx += __shfl_xor(sfx, 16);
  if (deg){
    float sd = (float)((double)sfx * (1.0 / SC_32));
    for (unsigned jj = ll; jj < nj; jj += 32)
      abuf[(size_t)k0 * 4 + jj] = lds_a[ds][jj] / sd;
  }
}

// ======== f32 radix select (u32 keys; attn > 0 -> bits ordered) ========
__global__ __launch_bounds__(256) void k_hp32(const float* __restrict__ attn,
    unsigned* __restrict__ sel32, unsigned* __restrict__ krem, unsigned* __restrict__ cnt,
    unsigned* __restrict__ hist, unsigned* __restrict__ done, unsigned maskHi, int shift){
  __shared__ unsigned lh[1024];
  __shared__ unsigned ticket;
  for (int j = threadIdx.x; j < 1024; j += 256) lh[j] = 0;
  __syncthreads();
  int i0 = blockIdx.x * 256 + threadIdx.x;
  int hh = i0 & 3;
  unsigned sel = sel32[hh] & maskHi;
  const int total = N_EDGES * 4;
  for (int i = i0; i < total; i += gridDim.x * 256){
    unsigned u = __float_as_uint(attn[i]);
    if ((u & maskHi) == sel)
      atomicAdd(&lh[hh * 256 + ((u >> shift) & 255u)], 1u);
  }
  __syncthreads();
  for (int j = threadIdx.x; j < 1024; j += 256)
    if (lh[j]) atomicAdd(&hist[j], lh[j]);
  __threadfence();
  if (threadIdx.x == 0) ticket = atomicAdd(done, 1u);
  __syncthreads();
  if (ticket == gridDim.x - 1){
    __threadfence();
    for (int j = threadIdx.x; j < 1024; j += 256){ lh[j] = hist[j]; hist[j] = 0; }
    __syncthreads();
    if (threadIdx.x < 4){
      int t = threadIdx.x;
      unsigned kr = krem[t], cum = 0, b = 0;
      for (; b < 256; b++){
        unsigned c2 = lh[t * 256 + b];
        if (kr < cum + c2) break;
        cum += c2;
      }
      sel32[t] |= b << shift;
      krem[t] = kr - cum;
      cnt[t] += cum;
    }
    if (threadIdx.x == 0) *done = 0;
  }
}

__global__ __launch_bounds__(256) void k_compact32(const float* __restrict__ attn,
    const unsigned* __restrict__ sel32, unsigned* __restrict__ ccnt,
    float* __restrict__ cand){
  __shared__ unsigned lcnt[4];
  __shared__ unsigned lbase[4];
  int t = threadIdx.x;
  if (t < 4) lcnt[t] = 0;
  __syncthreads();
  int i0 = blockIdx.x * 256 + t;
  int hh = i0 & 3;
  unsigned sel = sel32[hh] & 0xFFFF0000u;
  const int total = N_EDGES * 4;
  unsigned mc = 0;
  for (int i = i0; i < total; i += gridDim.x * 256){
    unsigned u = __float_as_uint(attn[i]);
    if ((u & 0xFFFF0000u) == sel) mc++;
  }
  unsigned my_local = mc ? atomicAdd(&lcnt[hh], mc) : 0u;
  __syncthreads();
  if (t < 4) lbase[t] = lcnt[t] ? atomicAdd(&ccnt[t], lcnt[t]) : 0u;
  __syncthreads();
  if (mc == 0) return;
  unsigned pos = lbase[hh] + my_local;
  float* cp = cand + (size_t)hh * N_EDGES;
  for (int i = i0; i < total; i += gridDim.x * 256){
    float v = attn[i];
    unsigned u = __float_as_uint(v);
    if ((u & 0xFFFF0000u) == sel) cp[pos++] = v;
  }
}

__global__ __launch_bounds__(256) void k_fin32(const float* __restrict__ cand,
    const unsigned* __restrict__ ccnt, unsigned* __restrict__ sel32,
    unsigned* __restrict__ krem, unsigned* __restrict__ cnt,
    unsigned* __restrict__ hist, unsigned* __restrict__ done, int shift){
  __shared__ unsigned lh[256];
  __shared__ unsigned ticket;
  int t = threadIdx.x;
  lh[t] = 0;
  __syncthreads();
  int h = blockIdx.x & 3;
  int bidx = blockIdx.x >> 2;
  int bph = gridDim.x >> 2;
  unsigned maskHi = ~((1u << (shift + 8)) - 1u);
  unsigned sel = sel32[h] & maskHi;
  unsigned n = ccnt[h];
  const float* cp = cand + (size_t)h * N_EDGES;
  for (unsigned i = bidx * 256 + t; i < n; i += bph * 256){
    unsigned u = __float_as_uint(cp[i]);
    if ((u & maskHi) == sel) atomicAdd(&lh[(u >> shift) & 255u], 1u);
  }
  __syncthreads();
  if (lh[t]) atomicAdd(&hist[h * 256 + t], lh[t]);
  __threadfence();
  if (t == 0) ticket = atomicAdd(done, 1u);
  __syncthreads();
  if (ticket == gridDim.x - 1){
    __threadfence();
    __shared__ unsigned fh[1024];
    for (int j = t; j < 1024; j += 256){ fh[j] = hist[j]; hist[j] = 0; }
    __syncthreads();
    if (t < 4){
      unsigned kr = krem[t], cum = 0, b = 0;
      for (; b < 256; b++){
        unsigned c2 = fh[t * 256 + b];
        if (kr < cum + c2) break;
        cum += c2;
      }
      sel32[t] |= b << shift;
      krem[t] = kr - cum;
      cnt[t] += cum;
    }
    if (t == 0) *done = 0;
  }
}

// ======== mark boundary candidates (attn32 in [thd*(1-MARG), thd*(1+MARG)]) ====
__global__ __launch_bounds__(256) void k_bmark(const float* __restrict__ attn,
    const unsigned* __restrict__ sel32, unsigned* __restrict__ cbelow,
    unsigned* __restrict__ bcnt, unsigned* __restrict__ blist){
  int t = threadIdx.x;
  int i0 = blockIdx.x * 256 + t;
  int hh = t & 3;
  double thd = (double)__uint_as_float(sel32[hh]);
  double lo = thd * (1.0 - MARG), hi = thd * (1.0 + MARG);
  unsigned below = 0;
  const int total = N_EDGES * 4;
  for (int i = i0; i < total; i += gridDim.x * 256){
    double v = (double)attn[i];
    if (v < lo) below++;
    else if (v <= hi){
      unsigned p = atomicAdd(bcnt, 1u);
      if (p < BCAP) blist[p] = (unsigned)i;
    }
  }
  #pragma unroll
  for (int m = 4; m < 64; m <<= 1) below += __shfl_xor(below, m);
  __shared__ unsigned sb[16];
  int wv = t >> 6;
  if ((t & 63) < 4) sb[wv * 4 + hh] = below;
  __syncthreads();
  if (t < 4){
    unsigned b = sb[t] + sb[4 + t] + sb[8 + t] + sb[12 + t];
    if (b) atomicAdd(&cbelow[t], b);
  }
}

// ======== exact f64 boundary refine: block/entry, LDS-staged weights ========
__global__ __launch_bounds__(256) void k_brefine(const float* __restrict__ h,
    const float* __restrict__ fcT, const float* __restrict__ fqT,
    const int* __restrict__ src, const int* __restrict__ dst,
    const unsigned* __restrict__ A, const unsigned* __restrict__ eidx,
    const unsigned* __restrict__ blist, const unsigned* __restrict__ bcnt,
    double* __restrict__ bval){
  __shared__ float wqs[32][257];
  __shared__ double cs[32];
  __shared__ double la[DEG_CAP];
  int tid = threadIdx.x;
  int wv = tid >> 6;
  int l = tid & 63;
  int j = l & 31;
  int khalf = l >> 5;
  unsigned nb = *bcnt; if (nb > BCAP) nb = BCAP;
  for (unsigned idx = blockIdx.x; idx < nb; idx += gridDim.x){
    unsigned slot = blist[idx];
    unsigned kslot = slot >> 2;
    int hh = slot & 3;
    int d = dst[eidx[kslot]];
    unsigned k0 = d ? A[d - 1] : 0u, k1 = A[d];
    unsigned deg = k1 - k0;
    {
      int col = tid >> 3, seg = tid & 7;
      const float* gsrc = fqT + (size_t)(hh * 32 + col) * 256 + seg * 32;
      #pragma unroll
      for (int r = 0; r < 8; r++){
        float4 v = *(const float4*)&gsrc[r * 4];
        float* wdst = &wqs[col][seg * 32 + r * 4];
        wdst[0] = v.x; wdst[1] = v.y; wdst[2] = v.z; wdst[3] = v.w;
      }
    }
    __syncthreads();
    if (wv == 0){
      const float* hd = h + (size_t)d * 256 + khalf * 128;
      const float* wc = fcT + (size_t)(hh * 32 + j) * 256 + khalf * 128;
      double c0 = 0.0, c1 = 0.0, c2 = 0.0, c3 = 0.0;
      #pragma unroll 8
      for (int i = 0; i < 128; i += 4){
        float4 hv = *(const float4*)&hd[i];
        float4 w2 = *(const float4*)&wc[i];
        c0 = fma((double)hv.x, (double)w2.x, c0);
        c1 = fma((double)hv.y, (double)w2.y, c1);
        c2 = fma((double)hv.z, (double)w2.z, c2);
        c3 = fma((double)hv.w, (double)w2.w, c3);
      }
      double c = (c0 + c1) + (c2 + c3);
      c += __shfl_xor(c, 32);
      if (l < 32) cs[l] = c;
    }
    __syncthreads();
    double cj = cs[j];
    for (unsigned k = k0 + wv; k < k1; k += 4){
      int s = src[eidx[k]];
      const float* hs = h + (size_t)s * 256 + khalf * 128;
      const float* wr = &wqs[j][khalf * 128];
      float4 hv = *(const float4*)&hs[0];
      double q0 = 0.0, q1 = 0.0, q2 = 0.0, q3 = 0.0;
      #pragma unroll 4
      for (int i = 0; i < 128; i += 4){
        float4 cur = hv;
        if (i + 4 < 128) hv = *(const float4*)&hs[i + 4];
        q0 = fma((double)cur.x, (double)wr[i + 0], q0);
        q1 = fma((double)cur.y, (double)wr[i + 1], q1);
        q2 = fma((double)cur.z, (double)wr[i + 2], q2);
        q3 = fma((double)cur.w, (double)wr[i + 3], q3);
      }
      double q = (q0 + q1) + (q2 + q3);
      q += __shfl_xor(q, 32);
      double p = (q - cj) * cj;
      p += __shfl_xor(p, 1);
      p += __shfl_xor(p, 2);
      p += __shfl_xor(p, 4);
      p += __shfl_xor(p, 8);
      p += __shfl_xor(p, 16);
      double a = (p > 0.0) ? p : expm1(p);
      if (l == 0) la[k - k0] = a;
    }
    __syncthreads();
    if (wv == 0){
      double m = -1.0e300;
      for (unsigned kk = l; kk < deg; kk += 64) m = fmax(m, la[kk]);
      #pragma unroll
      for (int msk = 1; msk < 64; msk <<= 1) m = fmax(m, __shfl_xor(m, msk));
      long long sfx = 0;
      for (unsigned kk = l; kk < deg; kk += 64)
        sfx += llrint(exp(la[kk] - m) * SC_FX);
      #pragma unroll
      for (int msk = 1; msk < 64; msk <<= 1) sfx += __shfl_xor(sfx, msk);
      if (l == 0){
        double sd = (double)sfx * (1.0 / SC_FX);
        bval[idx] = exp(la[kslot - k0] - m) / sd;
      }
    }
    __syncthreads();
  }
}

// ======== exact f64 select among boundary (1 block per head) ========
__global__ __launch_bounds__(256) void k_bselect(const double* __restrict__ bval,
    const unsigned* __restrict__ blist, const unsigned* __restrict__ bcnt,
    const unsigned* __restrict__ cbelow, double* __restrict__ thd64,
    unsigned* __restrict__ cntless){
  __shared__ unsigned lh[256];
  __shared__ u64 s_sel;
  __shared__ unsigned s_kr, s_cnt;
  int hsel = blockIdx.x;
  int t = threadIdx.x;
  unsigned nb = *bcnt; if (nb > BCAP) nb = BCAP;
  if (t == 0){ s_sel = 0; s_kr = RANK0 - cbelow[hsel]; s_cnt = 0; }
  __syncthreads();
  for (int p = 0; p < 8; p++){
    int shift = 56 - 8 * p;
    u64 maskHi = (p == 0) ? 0ull : (~0ull) << (64 - 8 * p);
    lh[t] = 0;
    __syncthreads();
    u64 sel = s_sel;
    for (unsigned i = t; i < nb; i += 256){
      if ((int)(blist[i] & 3) == hsel){
        u64 u = (u64)__double_as_longlong(bval[i]);
        if ((u & maskHi) == sel) atomicAdd(&lh[(unsigned)((u >> shift) & 255u)], 1u);
      }
    }
    __syncthreads();
    if (t == 0){
      unsigned kr = s_kr, cum = 0, b = 0;
      for (; b < 256; b++){
        unsigned c2 = lh[b];
        if (kr < cum + c2) break;
        cum += c2;
      }
      s_sel |= ((u64)b) << shift;
      s_kr = kr - cum;
      s_cnt += cum;
    }
    __syncthreads();
  }
  if (t == 0){
    thd64[hsel] = __longlong_as_double((long long)s_sel);
    cntless[hsel] = cbelow[hsel] + s_cnt;
  }
}

// ======== sums for certain edges + a3 (boundary deferred to k_bfinal) ========
__global__ __launch_bounds__(256) void k_sums32(const float* __restrict__ attn,
    const unsigned* __restrict__ sel32, u64* __restrict__ gsums, float* __restrict__ a3){
  int t = threadIdx.x;
  int i0 = blockIdx.x * 256 + t;
  int hh = t & 3;
  double thd = (double)__uint_as_float(sel32[hh]);
  double lo = thd * (1.0 - MARG), hi = thd * (1.0 + MARG);
  double al = 0.0, ag = 0.0;
  const int total = N_EDGES * 4;
  for (int i = i0; i < total; i += gridDim.x * 256){
    float vf = attn[i];
    double v = (double)vf;
    if (v < lo){ al += v; a3[i] = 0.f; }
    else if (v > hi){ ag += v; a3[i] = vf; }
    else a3[i] = 0.f;                      // boundary: fixed by k_bfinal
  }
  long long ql = llrint(al * SC_FX);
  long long qg = llrint(ag * SC_FX);
  #pragma unroll
  for (int m = 4; m < 64; m <<= 1){
    ql += __shfl_xor(ql, m);
    qg += __shfl_xor(qg, m);
  }
  __shared__ long long sl[16], sg[16];
  int wv = t >> 6;
  if ((t & 63) < 4){ sl[wv * 4 + hh] = ql; sg[wv * 4 + hh] = qg; }
  __syncthreads();
  if (t < 4){
    long long a = sl[t] + sl[4 + t] + sl[8 + t] + sl[12 + t];
    long long b = sg[t] + sg[4 + t] + sg[8 + t] + sg[12 + t];
    if (a) atomicAdd(&gsums[t],     (u64)a);
    if (b) atomicAdd(&gsums[4 + t], (u64)b);
  }
}

// ======== finalize boundary entries: exact cut + sums + a3 ========
__global__ void k_bfinal(const unsigned* __restrict__ blist, const double* __restrict__ bval,
    const unsigned* __restrict__ bcnt, const double* __restrict__ thd64,
    u64* __restrict__ gsums, float* __restrict__ a3){
  unsigned nb = *bcnt; if (nb > BCAP) nb = BCAP;
  for (unsigned idx = blockIdx.x * 256 + threadIdx.x; idx < nb; idx += gridDim.x * 256){
    unsigned slot = blist[idx];
    int hh = slot & 3;
    double v = bval[idx];
    bool kept = (v >= thd64[hh]);
    a3[slot] = kept ? (float)v : 0.f;
    atomicAdd(&gsums[(kept ? 4 : 0) + hh], (u64)llrint(v * SC_FX));
  }
}

__global__ void k_ratio(const double* __restrict__ thd64, const unsigned* __restrict__ cntless,
                        const u64* __restrict__ gsums, double* __restrict__ trd){
  int t = threadIdx.x;
  if (t < 4){
    double sless = (double)(long long)gsums[t]     * (1.0 / SC_FX);
    double sge   = (double)(long long)gsums[4 + t] * (1.0 / SC_FX);
    double topk  = sless + (double)(LS - (int)cntless[t]) * thd64[t];
    trd[t] = thd64[t];
    trd[4 + t] = (sge + topk) / sge;
  }
}

// ======== CSR gather-scatter (wave per dst; ft at fcq cols 0-127) ========
__global__ __launch_bounds__(256) void k_scatter2(const float* __restrict__ fcq,
    const int* __restrict__ src, const unsigned* __restrict__ A,
    const unsigned* __restrict__ eidx, const float* __restrict__ a3,
    const double* __restrict__ trd, float* __restrict__ out){
  int d = blockIdx.x * 4 + (threadIdx.x >> 6);
  int t = threadIdx.x & 63;
  if (d >= N_NODES) return;
  int hh = t >> 4;
  double ratio = trd[4 + hh];
  unsigned k0 = d ? A[d - 1] : 0u, k1 = A[d];
  long long acc0 = 0, acc1 = 0;
  float wn = (k0 < k1) ? a3[(size_t)k0 * 4 + hh] : 0.f;
  unsigned en = (k0 < k1) ? eidx[k0] : 0u;
  for (unsigned k = k0; k < k1; k++){
    float w = wn;
    unsigned e = en;
    if (k + 1 < k1){ wn = a3[(size_t)(k + 1) * 4 + hh]; en = eidx[k + 1]; }
    if (__ballot(w != 0.f) == 0ull) continue;    // ~71% dropped
    if (w != 0.f){
      int s = src[e];
      float2 f = *(const float2*)&fcq[(size_t)s * 384 + t * 2];
      double a3r = (double)w * ratio;
      acc0 += llrint(a3r * (double)f.x * SC_FX);
      acc1 += llrint(a3r * (double)f.y * SC_FX);
    }
  }
  float* p = &out[(size_t)d * OUTC + t * 2];
  p[0] = (float)((double)acc0 * (1.0 / SC_FX));
  p[1] = (float)((double)acc1 * (1.0 / SC_FX));
}

// ======== head-mean (runs last; ft at fcq cols 0-127) ========
__global__ void k_mean(const float* __restrict__ fcq, float* __restrict__ out){
  int i = blockIdx.x * 256 + threadIdx.x;
  if (i >= N_NODES * DH) return;
  int n = i / DH, dd = i % DH;
  const float* p = fcq + (size_t)n * 384;
  out[(size_t)n * OUTC + 128 + dd] = 0.25f * (p[dd] + p[32 + dd] + p[64 + dd] + p[96 + dd]);
}

extern "C" void kernel_launch(void* const* d_in, const int* in_sizes, int n_in,
                              void* d_out, int out_size, void* d_ws, size_t ws_size,
                              hipStream_t stream){
  const float* h  = (const float*)d_in[0];
  const float* Wl = (const float*)d_in[1];
  const float* fc = (const float*)d_in[2];
  const float* fq = (const float*)d_in[3];
  const int* src  = (const int*)d_in[4];
  const int* dst  = (const int*)d_in[5];
  float* out = (float*)d_out;

  char* ws = (char*)d_ws;
  float*    fcq  = (float*)(ws);                   // 76,800,000
  unsigned* A    = (unsigned*)(ws + 76800000);     // 200,004 (pad to 77,000,064)
  unsigned* eidx = (unsigned*)(ws + 77000064);     // 3,200,000
  float*    a3   = (float*)(ws + 80200064);        // 12,800,000
  unsigned* hist = (unsigned*)(ws + 93000064);     // 4,096
  unsigned* sel32  = (unsigned*)(ws + 93004160);   // 16
  unsigned* krem   = (unsigned*)(ws + 93004176);   // 16
  unsigned* cnt    = (unsigned*)(ws + 93004192);   // 16
  unsigned* done   = (unsigned*)(ws + 93004208);   // 16
  unsigned* ccnt   = (unsigned*)(ws + 93004224);   // 16
  unsigned* cbelow = (unsigned*)(ws + 93004240);   // 16
  unsigned* bcnt   = (unsigned*)(ws + 93004256);   // 16
  unsigned* cntless= (unsigned*)(ws + 93004272);   // 16
  u64*      gsums  = (u64*)(ws + 93004288);        // 64
  double*   thd64  = (double*)(ws + 93004352);     // 32
  double*   trd    = (double*)(ws + 93004416);     // 64
  unsigned* blist  = (unsigned*)(ws + 93008896);   // 262,144 (BCAP*4)
  double*   bval   = (double*)(ws + 93271040);     // 524,288 (BCAP*8)
  float*    fcT    = (float*)(ws + 93795328);      // 131,072
  float*    fqT    = (float*)(ws + 93926400);      // 131,072

  // scratch inside d_out (32 MB): both fully dead before scatter2/mean write
  float* abuf = (float*)d_out;                     // 12.8 MB attn32
  float* cand = (float*)((char*)d_out + 12800000); // 12.8 MB select candidates

  hipMemsetAsync(A, 0, 200004, stream);
  hipMemsetAsync(hist, 0, 4096, stream);
  k_init<<<1, 64, 0, stream>>>(sel32, krem, cnt, done, ccnt, cbelow, bcnt, cntless, gsums);
  k_prept<<<(IN_DIM * 128 + 255) / 256, 256, 0, stream>>>(fc, fq, fcT, fqT);

  // CSR
  k_deg<<<(N_EDGES + 255) / 256, 256, 0, stream>>>(dst, A);
  k_scan<<<1, 1024, 0, stream>>>(A);
  k_fill<<<(N_EDGES + 255) / 256, 256, 0, stream>>>(dst, A, eidx);

  // single f32 GEMM -> [ft | c | q]
  dim3 gg((N_NODES + BM - 1) / BM, 3);
  k_gemm384<<<gg, 256, 0, stream>>>(h, Wl, fc, fq, fcq);

  // f32 fused edge logits + softmax (2 dst per wave)
  k_softedge32<<<(N_NODES + 7) / 8, 256, 0, stream>>>(fcq, src, A, eidx, abuf);

  // exact f32 rank select: 2 global passes, compact, 2 finish passes
  k_hp32<<<1024, 256, 0, stream>>>(abuf, sel32, krem, cnt, hist, done, 0u, 24);
  k_hp32<<<1024, 256, 0, stream>>>(abuf, sel32, krem, cnt, hist, done, 0xFF000000u, 16);
  k_compact32<<<1024, 256, 0, stream>>>(abuf, sel32, ccnt, cand);
  k_fin32<<<256, 256, 0, stream>>>(cand, ccnt, sel32, krem, cnt, hist, done, 8);
  k_fin32<<<256, 256, 0, stream>>>(cand, ccnt, sel32, krem, cnt, hist, done, 0);

  // boundary: mark, refine in f64 (block per entry, LDS weights), exact select
  k_bmark<<<1024, 256, 0, stream>>>(abuf, sel32, cbelow, bcnt, blist);
  k_brefine<<<2048, 256, 0, stream>>>(h, fcT, fqT, src, dst, A, eidx, blist, bcnt, bval);
  k_bselect<<<4, 256, 0, stream>>>(bval, blist, bcnt, cbelow, thd64, cntless);

  // sums + a3 (+ boundary fixes) + ratio
  k_sums32<<<2048, 256, 0, stream>>>(abuf, sel32, gsums, a3);
  k_bfinal<<<64, 256, 0, stream>>>(blist, bval, bcnt, thd64, gsums, a3);
  k_ratio<<<1, 64, 0, stream>>>(thd64, cntless, gsums, trd);

  // output
  k_scatter2<<<(N_NODES + 3) / 4, 256, 0, stream>>>(fcq, src, A, eidx, a3, trd, out);
  k_mean<<<(N_NODES * DH + 255) / 256, 256, 0, stream>>>(fcq, out);
}

// Round 19
// 934.949 us; speedup vs baseline: 1.6706x; 1.0329x over previous
//
#include <hip/hip_runtime.h>
#include <hip/hip_bf16.h>
#include <math.h>

#define N_NODES 50000
#define N_EDGES 800000
#define DH 32
#define IN_DIM 256
#define OUTC 160
#define LS 570400     // int(0.713 * 800000) -> exactly 570400
#define RANK0 (LS - 1)
#define DEG_CAP 160   // max in-degree supported (Poisson(16))
#define BCAP 65536    // boundary-candidate cap (expect ~1K)
#define MARG 3.0e-4   // relative margin around thd32 (~30x worst f32 error)

typedef unsigned long long u64;
#define SC_FX 1099511627776.0   // 2^40 fixed-point scale (f64 sums)
#define SC_32 4294967296.0      // 2^32 fixed-point scale (f32 softmax denom)

// ======== CSR build ========
__global__ void k_deg(const int* __restrict__ dst, unsigned* __restrict__ A){
  int e = blockIdx.x * 256 + threadIdx.x;
  if (e < N_EDGES) atomicAdd(&A[dst[e]], 1u);
}

__global__ __launch_bounds__(1024) void k_scan(unsigned* __restrict__ A){
  __shared__ unsigned ps[1024];
  int t = threadIdx.x;
  const int CH = (N_NODES + 1023) / 1024;
  int base = t * CH;
  unsigned s = 0;
  for (int i = 0; i < CH; i++){ int n = base + i; if (n < N_NODES) s += A[n]; }
  ps[t] = s;
  __syncthreads();
  for (int off = 1; off < 1024; off <<= 1){
    unsigned v = (t >= off) ? ps[t - off] : 0;
    __syncthreads();
    ps[t] += v;
    __syncthreads();
  }
  unsigned ex = (t == 0) ? 0 : ps[t - 1];
  for (int i = 0; i < CH; i++){
    int n = base + i;
    if (n < N_NODES){ unsigned dv = A[n]; A[n] = ex; ex += dv; }
  }
}

__global__ void k_fill(const int* __restrict__ dst, unsigned* __restrict__ A,
                       unsigned* __restrict__ eidx){
  int e = blockIdx.x * 256 + threadIdx.x;
  if (e < N_EDGES) eidx[atomicAdd(&A[dst[e]], 1u)] = (unsigned)e;
}
// post-fill: A[d] == offsets[d+1]; node d range = [d? A[d-1]:0, A[d])

__global__ void k_init(unsigned* __restrict__ sel32, unsigned* __restrict__ krem,
                       unsigned* __restrict__ cnt, unsigned* __restrict__ done,
                       unsigned* __restrict__ ccnt, unsigned* __restrict__ cbelow,
                       unsigned* __restrict__ bcnt, unsigned* __restrict__ cntless,
                       u64* __restrict__ gsums){
  int t = threadIdx.x;
  if (t < 4){ sel32[t]=0; krem[t]=RANK0; cnt[t]=0; ccnt[t]=0; cbelow[t]=0; cntless[t]=0; }
  if (t < 8) gsums[t] = 0;
  if (t == 0){ done[0] = 0; bcnt[0] = 0; }
}

// ======== transpose fc/fq to [col][k] for refine ========
__global__ void k_prept(const float* __restrict__ fc, const float* __restrict__ fq,
                        float* __restrict__ fcT, float* __restrict__ fqT){
  int i = blockIdx.x * 256 + threadIdx.x;
  if (i >= IN_DIM * 128) return;
  int k = i >> 7, c = i & 127;
  fcT[(size_t)c * 256 + k] = fc[i];
  fqT[(size_t)c * 256 + k] = fq[i];
}

// ======== single f32 GEMM: double-buffered LDS, 1 barrier per K-tile ========
#define BM 128
#define BK 16
__global__ __launch_bounds__(256) void k_gemm384(const float* __restrict__ A,
    const float* __restrict__ Wl, const float* __restrict__ fc,
    const float* __restrict__ fq, float* __restrict__ C){
  __shared__ float As[2][BK][BM + 4];
  __shared__ float Bs[2][BK][128 + 4];
  int tid = threadIdx.x;
  int m0 = blockIdx.x * BM;
  int n0 = blockIdx.y * 128;               // 0:ft(Wl^T)  128:fc  256:fq
  int ty = tid / 16, tx = tid % 16;
  const float* Bsrc = (n0 == 128) ? fc : fq;

  int sA0r = (tid * 2) >> 2,     sA0c = (tid * 2) & 3;
  int sA1r = (tid * 2 + 1) >> 2, sA1c = (tid * 2 + 1) & 3;
  int sB0k = (tid * 2) >> 5,     sB0c = (tid * 2) & 31;
  int sB1k = (tid * 2 + 1) >> 5, sB1c = (tid * 2 + 1) & 31;

  float acc[8][8];
  #pragma unroll
  for (int i = 0; i < 8; i++)
    #pragma unroll
    for (int j = 0; j < 8; j++) acc[i][j] = 0.f;

  float4 rA0, rA1, rB0, rB1;
  {
    int r0 = m0 + sA0r, r1 = m0 + sA1r;
    rA0 = (r0 < N_NODES) ? *(const float4*)&A[(size_t)r0 * IN_DIM + sA0c * 4] : make_float4(0,0,0,0);
    rA1 = (r1 < N_NODES) ? *(const float4*)&A[(size_t)r1 * IN_DIM + sA1c * 4] : make_float4(0,0,0,0);
    if (n0 == 0){
      rB0 = *(const float4*)&Wl[(size_t)sA0r * IN_DIM + sA0c * 4];
      rB1 = *(const float4*)&Wl[(size_t)sA1r * IN_DIM + sA1c * 4];
    } else {
      rB0 = *(const float4*)&Bsrc[(size_t)sB0k * 128 + sB0c * 4];
      rB1 = *(const float4*)&Bsrc[(size_t)sB1k * 128 + sB1c * 4];
    }
  }

  int p = 0;
  for (int k0 = 0; k0 < IN_DIM; k0 += BK){
    // publish current tile into buffer p
    As[p][sA0c * 4 + 0][sA0r] = rA0.x; As[p][sA0c * 4 + 1][sA0r] = rA0.y;
    As[p][sA0c * 4 + 2][sA0r] = rA0.z; As[p][sA0c * 4 + 3][sA0r] = rA0.w;
    As[p][sA1c * 4 + 0][sA1r] = rA1.x; As[p][sA1c * 4 + 1][sA1r] = rA1.y;
    As[p][sA1c * 4 + 2][sA1r] = rA1.z; As[p][sA1c * 4 + 3][sA1r] = rA1.w;
    if (n0 == 0){
      Bs[p][sA0c * 4 + 0][sA0r] = rB0.x; Bs[p][sA0c * 4 + 1][sA0r] = rB0.y;
      Bs[p][sA0c * 4 + 2][sA0r] = rB0.z; Bs[p][sA0c * 4 + 3][sA0r] = rB0.w;
      Bs[p][sA1c * 4 + 0][sA1r] = rB1.x; Bs[p][sA1c * 4 + 1][sA1r] = rB1.y;
      Bs[p][sA1c * 4 + 2][sA1r] = rB1.z; Bs[p][sA1c * 4 + 3][sA1r] = rB1.w;
    } else {
      *(float4*)&Bs[p][sB0k][sB0c * 4] = rB0;
      *(float4*)&Bs[p][sB1k][sB1c * 4] = rB1;
    }
    __syncthreads();
    if (k0 + BK < IN_DIM){
      int kn = k0 + BK;
      int r0 = m0 + sA0r, r1 = m0 + sA1r;
      rA0 = (r0 < N_NODES) ? *(const float4*)&A[(size_t)r0 * IN_DIM + kn + sA0c * 4] : make_float4(0,0,0,0);
      rA1 = (r1 < N_NODES) ? *(const float4*)&A[(size_t)r1 * IN_DIM + kn + sA1c * 4] : make_float4(0,0,0,0);
      if (n0 == 0){
        rB0 = *(const float4*)&Wl[(size_t)sA0r * IN_DIM + kn + sA0c * 4];
        rB1 = *(const float4*)&Wl[(size_t)sA1r * IN_DIM + kn + sA1c * 4];
      } else {
        rB0 = *(const float4*)&Bsrc[(size_t)(kn + sB0k) * 128 + sB0c * 4];
        rB1 = *(const float4*)&Bsrc[(size_t)(kn + sB1k) * 128 + sB1c * 4];
      }
    }
    #pragma unroll
    for (int kk = 0; kk < BK; kk++){
      float4 a0 = *(const float4*)&As[p][kk][ty * 4];
      float4 a1 = *(const float4*)&As[p][kk][64 + ty * 4];
      float4 b0 = *(const float4*)&Bs[p][kk][tx * 4];
      float4 b1 = *(const float4*)&Bs[p][kk][64 + tx * 4];
      float av[8] = {a0.x, a0.y, a0.z, a0.w, a1.x, a1.y, a1.z, a1.w};
      float bv[8] = {b0.x, b0.y, b0.z, b0.w, b1.x, b1.y, b1.z, b1.w};
      #pragma unroll
      for (int i = 0; i < 8; i++)
        #pragma unroll
        for (int j = 0; j < 8; j++)
          acc[i][j] = fmaf(av[i], bv[j], acc[i][j]);
    }
    p ^= 1;
  }
  #pragma unroll
  for (int i = 0; i < 8; i++){
    int r = m0 + ((i < 4) ? (ty * 4 + i) : (64 + ty * 4 + (i - 4)));
    if (r >= N_NODES) continue;
    *(float4*)&C[(size_t)r * 384 + n0 + tx * 4]      = make_float4(acc[i][0], acc[i][1], acc[i][2], acc[i][3]);
    *(float4*)&C[(size_t)r * 384 + n0 + 64 + tx * 4] = make_float4(acc[i][4], acc[i][5], acc[i][6], acc[i][7]);
  }
}

// ======== f32 fused edge logits + softmax: 2 dst per wave, float4 lanes ========
__global__ __launch_bounds__(256) void k_softedge32(const float* __restrict__ fcq,
    const int* __restrict__ src, const unsigned* __restrict__ A,
    const unsigned* __restrict__ eidx, float* __restrict__ abuf){
  __shared__ float lds_a[8][DEG_CAP * 4];
  int tid = threadIdx.x;
  int wv = tid >> 6;
  int l = tid & 63;
  int half = l >> 5;
  int ll = l & 31;
  int ds = wv * 2 + half;                 // dst slot in block (0..7)
  int d = blockIdx.x * 8 + ds;
  bool ok = (d < N_NODES);
  unsigned k0 = 0, k1 = 0;
  if (ok){ k0 = d ? A[d - 1] : 0u; k1 = A[d]; }
  unsigned deg = k1 - k0;                 // uniform within half-wave
  float4 c4 = make_float4(0.f, 0.f, 0.f, 0.f);
  float4 q4n = make_float4(0.f, 0.f, 0.f, 0.f);
  if (deg){
    c4 = *(const float4*)&fcq[(size_t)d * 384 + 128 + ll * 4];
    int sn = src[eidx[k0]];
    q4n = *(const float4*)&fcq[(size_t)sn * 384 + 256 + ll * 4];
  }
  float m = -1.0e30f;
  for (unsigned kk = 0; kk < deg; kk++){
    float4 q4 = q4n;
    if (kk + 1 < deg){
      int s2 = src[eidx[k0 + kk + 1]];
      q4n = *(const float4*)&fcq[(size_t)s2 * 384 + 256 + ll * 4];
    }
    float v = (q4.x - c4.x) * c4.x;
    v = fmaf(q4.y - c4.y, c4.y, v);
    v = fmaf(q4.z - c4.z, c4.z, v);
    v = fmaf(q4.w - c4.w, c4.w, v);
    v += __shfl_xor(v, 1);
    v += __shfl_xor(v, 2);
    v += __shfl_xor(v, 4);
    float a = (v > 0.f) ? v : expm1f(v);   // ELU; identical across 8-lane group
    m = fmaxf(m, a);
    if ((ll & 7) == 0) lds_a[ds][kk * 4 + (ll >> 3)] = a;
  }
  float mm = __shfl(m, half * 32 + (ll & 3) * 8);   // max of head (ll&3)
  unsigned nj = deg * 4;
  long long sfx = 0;
  for (unsigned jj = ll; jj < nj; jj += 32){
    float ex = __expf(lds_a[ds][jj] - mm);
    lds_a[ds][jj] = ex;
    sfx += (long long)llrintf(ex * (float)SC_32);
  }
  sfx += __shfl_xor(sfx, 4);
  sfx += __shfl_xor(sfx, 8);
  sfx += __shfl_xor(sfx, 16);
  if (deg){
    float sd = (float)((double)sfx * (1.0 / SC_32));
    for (unsigned jj = ll; jj < nj; jj += 32)
      abuf[(size_t)k0 * 4 + jj] = lds_a[ds][jj] / sd;
  }
}

// ======== f32 radix select (u32 keys; attn > 0 -> bits ordered) ========
__global__ __launch_bounds__(256) void k_hp32(const float* __restrict__ attn,
    unsigned* __restrict__ sel32, unsigned* __restrict__ krem, unsigned* __restrict__ cnt,
    unsigned* __restrict__ hist, unsigned* __restrict__ done, unsigned maskHi, int shift){
  __shared__ unsigned lh[1024];
  __shared__ unsigned ticket;
  for (int j = threadIdx.x; j < 1024; j += 256) lh[j] = 0;
  __syncthreads();
  int i0 = blockIdx.x * 256 + threadIdx.x;
  int hh = i0 & 3;
  unsigned sel = sel32[hh] & maskHi;
  const int total = N_EDGES * 4;
  for (int i = i0; i < total; i += gridDim.x * 256){
    unsigned u = __float_as_uint(attn[i]);
    if ((u & maskHi) == sel)
      atomicAdd(&lh[hh * 256 + ((u >> shift) & 255u)], 1u);
  }
  __syncthreads();
  for (int j = threadIdx.x; j < 1024; j += 256)
    if (lh[j]) atomicAdd(&hist[j], lh[j]);
  __threadfence();
  if (threadIdx.x == 0) ticket = atomicAdd(done, 1u);
  __syncthreads();
  if (ticket == gridDim.x - 1){
    __threadfence();
    for (int j = threadIdx.x; j < 1024; j += 256){ lh[j] = hist[j]; hist[j] = 0; }
    __syncthreads();
    if (threadIdx.x < 4){
      int t = threadIdx.x;
      unsigned kr = krem[t], cum = 0, b = 0;
      for (; b < 256; b++){
        unsigned c2 = lh[t * 256 + b];
        if (kr < cum + c2) break;
        cum += c2;
      }
      sel32[t] |= b << shift;
      krem[t] = kr - cum;
      cnt[t] += cum;
    }
    if (threadIdx.x == 0) *done = 0;
  }
}

__global__ __launch_bounds__(256) void k_compact32(const float* __restrict__ attn,
    const unsigned* __restrict__ sel32, unsigned* __restrict__ ccnt,
    float* __restrict__ cand){
  __shared__ unsigned lcnt[4];
  __shared__ unsigned lbase[4];
  int t = threadIdx.x;
  if (t < 4) lcnt[t] = 0;
  __syncthreads();
  int i0 = blockIdx.x * 256 + t;
  int hh = i0 & 3;
  unsigned sel = sel32[hh] & 0xFFFF0000u;
  const int total = N_EDGES * 4;
  unsigned mc = 0;
  for (int i = i0; i < total; i += gridDim.x * 256){
    unsigned u = __float_as_uint(attn[i]);
    if ((u & 0xFFFF0000u) == sel) mc++;
  }
  unsigned my_local = mc ? atomicAdd(&lcnt[hh], mc) : 0u;
  __syncthreads();
  if (t < 4) lbase[t] = lcnt[t] ? atomicAdd(&ccnt[t], lcnt[t]) : 0u;
  __syncthreads();
  if (mc == 0) return;
  unsigned pos = lbase[hh] + my_local;
  float* cp = cand + (size_t)hh * N_EDGES;
  for (int i = i0; i < total; i += gridDim.x * 256){
    float v = attn[i];
    unsigned u = __float_as_uint(v);
    if ((u & 0xFFFF0000u) == sel) cp[pos++] = v;
  }
}

__global__ __launch_bounds__(256) void k_fin32(const float* __restrict__ cand,
    const unsigned* __restrict__ ccnt, unsigned* __restrict__ sel32,
    unsigned* __restrict__ krem, unsigned* __restrict__ cnt,
    unsigned* __restrict__ hist, unsigned* __restrict__ done, int shift){
  __shared__ unsigned lh[256];
  __shared__ unsigned ticket;
  int t = threadIdx.x;
  lh[t] = 0;
  __syncthreads();
  int h = blockIdx.x & 3;
  int bidx = blockIdx.x >> 2;
  int bph = gridDim.x >> 2;
  unsigned maskHi = ~((1u << (shift + 8)) - 1u);
  unsigned sel = sel32[h] & maskHi;
  unsigned n = ccnt[h];
  const float* cp = cand + (size_t)h * N_EDGES;
  for (unsigned i = bidx * 256 + t; i < n; i += bph * 256){
    unsigned u = __float_as_uint(cp[i]);
    if ((u & maskHi) == sel) atomicAdd(&lh[(u >> shift) & 255u], 1u);
  }
  __syncthreads();
  if (lh[t]) atomicAdd(&hist[h * 256 + t], lh[t]);
  __threadfence();
  if (t == 0) ticket = atomicAdd(done, 1u);
  __syncthreads();
  if (ticket == gridDim.x - 1){
    __threadfence();
    __shared__ unsigned fh[1024];
    for (int j = t; j < 1024; j += 256){ fh[j] = hist[j]; hist[j] = 0; }
    __syncthreads();
    if (t < 4){
      unsigned kr = krem[t], cum = 0, b = 0;
      for (; b < 256; b++){
        unsigned c2 = fh[t * 256 + b];
        if (kr < cum + c2) break;
        cum += c2;
      }
      sel32[t] |= b << shift;
      krem[t] = kr - cum;
      cnt[t] += cum;
    }
    if (t == 0) *done = 0;
  }
}

// ======== fused: boundary mark + certain-edge sums + a3 (one abuf pass) ========
__global__ __launch_bounds__(256) void k_marksums(const float* __restrict__ attn,
    const unsigned* __restrict__ sel32, unsigned* __restrict__ cbelow,
    unsigned* __restrict__ bcnt, unsigned* __restrict__ blist,
    u64* __restrict__ gsums, float* __restrict__ a3){
  int t = threadIdx.x;
  int i0 = blockIdx.x * 256 + t;
  int hh = t & 3;
  double thd = (double)__uint_as_float(sel32[hh]);
  double lo = thd * (1.0 - MARG), hi = thd * (1.0 + MARG);
  double al = 0.0, ag = 0.0;
  unsigned below = 0;
  const int total = N_EDGES * 4;
  for (int i = i0; i < total; i += gridDim.x * 256){
    float vf = attn[i];
    double v = (double)vf;
    if (v < lo){ al += v; below++; a3[i] = 0.f; }
    else if (v > hi){ ag += v; a3[i] = vf; }
    else {
      unsigned p = atomicAdd(bcnt, 1u);
      if (p < BCAP) blist[p] = (unsigned)i;
      a3[i] = 0.f;                         // boundary: fixed by k_bfinal
    }
  }
  long long ql = llrint(al * SC_FX);
  long long qg = llrint(ag * SC_FX);
  #pragma unroll
  for (int m = 4; m < 64; m <<= 1){
    ql += __shfl_xor(ql, m);
    qg += __shfl_xor(qg, m);
    below += __shfl_xor(below, m);
  }
  __shared__ long long sl[16], sg[16];
  __shared__ unsigned sb[16];
  int wv = t >> 6;
  if ((t & 63) < 4){ sl[wv * 4 + hh] = ql; sg[wv * 4 + hh] = qg; sb[wv * 4 + hh] = below; }
  __syncthreads();
  if (t < 4){
    long long a = sl[t] + sl[4 + t] + sl[8 + t] + sl[12 + t];
    long long b = sg[t] + sg[4 + t] + sg[8 + t] + sg[12 + t];
    unsigned bl = sb[t] + sb[4 + t] + sb[8 + t] + sb[12 + t];
    if (a) atomicAdd(&gsums[t],     (u64)a);
    if (b) atomicAdd(&gsums[4 + t], (u64)b);
    if (bl) atomicAdd(&cbelow[t], bl);
  }
}

// ======== exact f64 boundary refine: block/entry, LDS-staged weights ========
__global__ __launch_bounds__(256) void k_brefine(const float* __restrict__ h,
    const float* __restrict__ fcT, const float* __restrict__ fqT,
    const int* __restrict__ src, const int* __restrict__ dst,
    const unsigned* __restrict__ A, const unsigned* __restrict__ eidx,
    const unsigned* __restrict__ blist, const unsigned* __restrict__ bcnt,
    double* __restrict__ bval){
  __shared__ float wqs[32][257];
  __shared__ double cs[32];
  __shared__ double la[DEG_CAP];
  int tid = threadIdx.x;
  int wv = tid >> 6;
  int l = tid & 63;
  int j = l & 31;
  int khalf = l >> 5;
  unsigned nb = *bcnt; if (nb > BCAP) nb = BCAP;
  for (unsigned idx = blockIdx.x; idx < nb; idx += gridDim.x){
    unsigned slot = blist[idx];
    unsigned kslot = slot >> 2;
    int hh = slot & 3;
    int d = dst[eidx[kslot]];
    unsigned k0 = d ? A[d - 1] : 0u, k1 = A[d];
    unsigned deg = k1 - k0;
    {
      int col = tid >> 3, seg = tid & 7;
      const float* gsrc = fqT + (size_t)(hh * 32 + col) * 256 + seg * 32;
      #pragma unroll
      for (int r = 0; r < 8; r++){
        float4 v = *(const float4*)&gsrc[r * 4];
        float* wdst = &wqs[col][seg * 32 + r * 4];
        wdst[0] = v.x; wdst[1] = v.y; wdst[2] = v.z; wdst[3] = v.w;
      }
    }
    __syncthreads();
    if (wv == 0){
      const float* hd = h + (size_t)d * 256 + khalf * 128;
      const float* wc = fcT + (size_t)(hh * 32 + j) * 256 + khalf * 128;
      double c0 = 0.0, c1 = 0.0, c2 = 0.0, c3 = 0.0;
      #pragma unroll 8
      for (int i = 0; i < 128; i += 4){
        float4 hv = *(const float4*)&hd[i];
        float4 w2 = *(const float4*)&wc[i];
        c0 = fma((double)hv.x, (double)w2.x, c0);
        c1 = fma((double)hv.y, (double)w2.y, c1);
        c2 = fma((double)hv.z, (double)w2.z, c2);
        c3 = fma((double)hv.w, (double)w2.w, c3);
      }
      double c = (c0 + c1) + (c2 + c3);
      c += __shfl_xor(c, 32);
      if (l < 32) cs[l] = c;
    }
    __syncthreads();
    double cj = cs[j];
    for (unsigned k = k0 + wv; k < k1; k += 4){
      int s = src[eidx[k]];
      const float* hs = h + (size_t)s * 256 + khalf * 128;
      const float* wr = &wqs[j][khalf * 128];
      float4 hv = *(const float4*)&hs[0];
      double q0 = 0.0, q1 = 0.0, q2 = 0.0, q3 = 0.0;
      #pragma unroll 4
      for (int i = 0; i < 128; i += 4){
        float4 cur = hv;
        if (i + 4 < 128) hv = *(const float4*)&hs[i + 4];
        q0 = fma((double)cur.x, (double)wr[i + 0], q0);
        q1 = fma((double)cur.y, (double)wr[i + 1], q1);
        q2 = fma((double)cur.z, (double)wr[i + 2], q2);
        q3 = fma((double)cur.w, (double)wr[i + 3], q3);
      }
      double q = (q0 + q1) + (q2 + q3);
      q += __shfl_xor(q, 32);
      double p = (q - cj) * cj;
      p += __shfl_xor(p, 1);
      p += __shfl_xor(p, 2);
      p += __shfl_xor(p, 4);
      p += __shfl_xor(p, 8);
      p += __shfl_xor(p, 16);
      double a = (p > 0.0) ? p : expm1(p);
      if (l == 0) la[k - k0] = a;
    }
    __syncthreads();
    if (wv == 0){
      double m = -1.0e300;
      for (unsigned kk = l; kk < deg; kk += 64) m = fmax(m, la[kk]);
      #pragma unroll
      for (int msk = 1; msk < 64; msk <<= 1) m = fmax(m, __shfl_xor(m, msk));
      long long sfx = 0;
      for (unsigned kk = l; kk < deg; kk += 64)
        sfx += llrint(exp(la[kk] - m) * SC_FX);
      #pragma unroll
      for (int msk = 1; msk < 64; msk <<= 1) sfx += __shfl_xor(sfx, msk);
      if (l == 0){
        double sd = (double)sfx * (1.0 / SC_FX);
        bval[idx] = exp(la[kslot - k0] - m) / sd;
      }
    }
    __syncthreads();
  }
}

// ======== exact f64 select among boundary (1 block per head) ========
__global__ __launch_bounds__(256) void k_bselect(const double* __restrict__ bval,
    const unsigned* __restrict__ blist, const unsigned* __restrict__ bcnt,
    const unsigned* __restrict__ cbelow, double* __restrict__ thd64,
    unsigned* __restrict__ cntless){
  __shared__ unsigned lh[256];
  __shared__ u64 s_sel;
  __shared__ unsigned s_kr, s_cnt;
  int hsel = blockIdx.x;
  int t = threadIdx.x;
  unsigned nb = *bcnt; if (nb > BCAP) nb = BCAP;
  if (t == 0){ s_sel = 0; s_kr = RANK0 - cbelow[hsel]; s_cnt = 0; }
  __syncthreads();
  for (int p = 0; p < 8; p++){
    int shift = 56 - 8 * p;
    u64 maskHi = (p == 0) ? 0ull : (~0ull) << (64 - 8 * p);
    lh[t] = 0;
    __syncthreads();
    u64 sel = s_sel;
    for (unsigned i = t; i < nb; i += 256){
      if ((int)(blist[i] & 3) == hsel){
        u64 u = (u64)__double_as_longlong(bval[i]);
        if ((u & maskHi) == sel) atomicAdd(&lh[(unsigned)((u >> shift) & 255u)], 1u);
      }
    }
    __syncthreads();
    if (t == 0){
      unsigned kr = s_kr, cum = 0, b = 0;
      for (; b < 256; b++){
        unsigned c2 = lh[b];
        if (kr < cum + c2) break;
        cum += c2;
      }
      s_sel |= ((u64)b) << shift;
      s_kr = kr - cum;
      s_cnt += cum;
    }
    __syncthreads();
  }
  if (t == 0){
    thd64[hsel] = __longlong_as_double((long long)s_sel);
    cntless[hsel] = cbelow[hsel] + s_cnt;
  }
}

// ======== finalize boundary entries: exact cut + sums + a3 ========
__global__ void k_bfinal(const unsigned* __restrict__ blist, const double* __restrict__ bval,
    const unsigned* __restrict__ bcnt, const double* __restrict__ thd64,
    u64* __restrict__ gsums, float* __restrict__ a3){
  unsigned nb = *bcnt; if (nb > BCAP) nb = BCAP;
  for (unsigned idx = blockIdx.x * 256 + threadIdx.x; idx < nb; idx += gridDim.x * 256){
    unsigned slot = blist[idx];
    int hh = slot & 3;
    double v = bval[idx];
    bool kept = (v >= thd64[hh]);
    a3[slot] = kept ? (float)v : 0.f;
    atomicAdd(&gsums[(kept ? 4 : 0) + hh], (u64)llrint(v * SC_FX));
  }
}

__global__ void k_ratio(const double* __restrict__ thd64, const unsigned* __restrict__ cntless,
                        const u64* __restrict__ gsums, double* __restrict__ trd){
  int t = threadIdx.x;
  if (t < 4){
    double sless = (double)(long long)gsums[t]     * (1.0 / SC_FX);
    double sge   = (double)(long long)gsums[4 + t] * (1.0 / SC_FX);
    double topk  = sless + (double)(LS - (int)cntless[t]) * thd64[t];
    trd[t] = thd64[t];
    trd[4 + t] = (sge + topk) / sge;
  }
}

// ======== CSR gather-scatter + fused head-mean (wave per dst) ========
__global__ __launch_bounds__(256) void k_scatter2(const float* __restrict__ fcq,
    const int* __restrict__ src, const unsigned* __restrict__ A,
    const unsigned* __restrict__ eidx, const float* __restrict__ a3,
    const double* __restrict__ trd, float* __restrict__ out){
  int d = blockIdx.x * 4 + (threadIdx.x >> 6);
  int t = threadIdx.x & 63;
  if (d >= N_NODES) return;
  int hh = t >> 4;
  double ratio = trd[4 + hh];
  unsigned k0 = d ? A[d - 1] : 0u, k1 = A[d];
  long long acc0 = 0, acc1 = 0;
  float wn = (k0 < k1) ? a3[(size_t)k0 * 4 + hh] : 0.f;
  unsigned en = (k0 < k1) ? eidx[k0] : 0u;
  for (unsigned k = k0; k < k1; k++){
    float w = wn;
    unsigned e = en;
    if (k + 1 < k1){ wn = a3[(size_t)(k + 1) * 4 + hh]; en = eidx[k + 1]; }
    if (__ballot(w != 0.f) == 0ull) continue;    // ~71% dropped
    if (w != 0.f){
      int s = src[e];
      float2 f = *(const float2*)&fcq[(size_t)s * 384 + t * 2];
      double a3r = (double)w * ratio;
      acc0 += llrint(a3r * (double)f.x * SC_FX);
      acc1 += llrint(a3r * (double)f.y * SC_FX);
    }
  }
  float* p = &out[(size_t)d * OUTC + t * 2];
  p[0] = (float)((double)acc0 * (1.0 / SC_FX));
  p[1] = (float)((double)acc1 * (1.0 / SC_FX));
  // fused head-mean: lanes 0-31 write out[d][128+t]
  if (t < 32){
    const float* pf = &fcq[(size_t)d * 384];
    out[(size_t)d * OUTC + 128 + t] = 0.25f * (pf[t] + pf[32 + t] + pf[64 + t] + pf[96 + t]);
  }
}

extern "C" void kernel_launch(void* const* d_in, const int* in_sizes, int n_in,
                              void* d_out, int out_size, void* d_ws, size_t ws_size,
                              hipStream_t stream){
  const float* h  = (const float*)d_in[0];
  const float* Wl = (const float*)d_in[1];
  const float* fc = (const float*)d_in[2];
  const float* fq = (const float*)d_in[3];
  const int* src  = (const int*)d_in[4];
  const int* dst  = (const int*)d_in[5];
  float* out = (float*)d_out;

  char* ws = (char*)d_ws;
  float*    fcq  = (float*)(ws);                   // 76,800,000
  unsigned* A    = (unsigned*)(ws + 76800000);     // 200,004 (pad to 77,000,064)
  unsigned* eidx = (unsigned*)(ws + 77000064);     // 3,200,000
  float*    a3   = (float*)(ws + 80200064);        // 12,800,000
  unsigned* hist = (unsigned*)(ws + 93000064);     // 4,096
  unsigned* sel32  = (unsigned*)(ws + 93004160);   // 16
  unsigned* krem   = (unsigned*)(ws + 93004176);   // 16
  unsigned* cnt    = (unsigned*)(ws + 93004192);   // 16
  unsigned* done   = (unsigned*)(ws + 93004208);   // 16
  unsigned* ccnt   = (unsigned*)(ws + 93004224);   // 16
  unsigned* cbelow = (unsigned*)(ws + 93004240);   // 16
  unsigned* bcnt   = (unsigned*)(ws + 93004256);   // 16
  unsigned* cntless= (unsigned*)(ws + 93004272);   // 16
  u64*      gsums  = (u64*)(ws + 93004288);        // 64
  double*   thd64  = (double*)(ws + 93004352);     // 32
  double*   trd    = (double*)(ws + 93004416);     // 64
  unsigned* blist  = (unsigned*)(ws + 93008896);   // 262,144 (BCAP*4)
  double*   bval   = (double*)(ws + 93271040);     // 524,288 (BCAP*8)
  float*    fcT    = (float*)(ws + 93795328);      // 131,072
  float*    fqT    = (float*)(ws + 93926400);      // 131,072

  // scratch inside d_out (32 MB): both fully dead before scatter2 writes
  float* abuf = (float*)d_out;                     // 12.8 MB attn32
  float* cand = (float*)((char*)d_out + 12800000); // 12.8 MB select candidates

  hipMemsetAsync(A, 0, 200004, stream);
  hipMemsetAsync(hist, 0, 4096, stream);
  k_init<<<1, 64, 0, stream>>>(sel32, krem, cnt, done, ccnt, cbelow, bcnt, cntless, gsums);
  k_prept<<<(IN_DIM * 128 + 255) / 256, 256, 0, stream>>>(fc, fq, fcT, fqT);

  // CSR
  k_deg<<<(N_EDGES + 255) / 256, 256, 0, stream>>>(dst, A);
  k_scan<<<1, 1024, 0, stream>>>(A);
  k_fill<<<(N_EDGES + 255) / 256, 256, 0, stream>>>(dst, A, eidx);

  // single f32 GEMM -> [ft | c | q]
  dim3 gg((N_NODES + BM - 1) / BM, 3);
  k_gemm384<<<gg, 256, 0, stream>>>(h, Wl, fc, fq, fcq);

  // f32 fused edge logits + softmax (2 dst per wave)
  k_softedge32<<<(N_NODES + 7) / 8, 256, 0, stream>>>(fcq, src, A, eidx, abuf);

  // exact f32 rank select: 2 global passes, compact, 2 finish passes
  k_hp32<<<1024, 256, 0, stream>>>(abuf, sel32, krem, cnt, hist, done, 0u, 24);
  k_hp32<<<1024, 256, 0, stream>>>(abuf, sel32, krem, cnt, hist, done, 0xFF000000u, 16);
  k_compact32<<<1024, 256, 0, stream>>>(abuf, sel32, ccnt, cand);
  k_fin32<<<256, 256, 0, stream>>>(cand, ccnt, sel32, krem, cnt, hist, done, 8);
  k_fin32<<<256, 256, 0, stream>>>(cand, ccnt, sel32, krem, cnt, hist, done, 0);

  // fused: boundary mark + certain sums + a3 (one pass)
  k_marksums<<<2048, 256, 0, stream>>>(abuf, sel32, cbelow, bcnt, blist, gsums, a3);

  // boundary: refine in f64 (block per entry, LDS weights), exact select
  k_brefine<<<2048, 256, 0, stream>>>(h, fcT, fqT, src, dst, A, eidx, blist, bcnt, bval);
  k_bselect<<<4, 256, 0, stream>>>(bval, blist, bcnt, cbelow, thd64, cntless);
  k_bfinal<<<64, 256, 0, stream>>>(blist, bval, bcnt, thd64, gsums, a3);
  k_ratio<<<1, 64, 0, stream>>>(thd64, cntless, gsums, trd);

  // output (scatter + fused head-mean)
  k_scatter2<<<(N_NODES + 3) / 4, 256, 0, stream>>>(fcq, src, A, eidx, a3, trd, out);
}

// Round 20
// 918.433 us; speedup vs baseline: 1.7006x; 1.0180x over previous
//
#include <hip/hip_runtime.h>
#include <hip/hip_bf16.h>
#include <math.h>

#define N_NODES 50000
#define N_EDGES 800000
#define DH 32
#define IN_DIM 256
#define OUTC 160
#define LS 570400     // int(0.713 * 800000) -> exactly 570400
#define RANK0 (LS - 1)
#define DEG_CAP 160   // max in-degree supported (Poisson(16))
#define BCAP 65536    // boundary-candidate cap (expect ~1K)
#define MARG 3.0e-4   // relative margin around thd32 (~30x worst f32 error)

typedef unsigned long long u64;
#define SC_FX 1099511627776.0   // 2^40 fixed-point scale (f64 sums)
#define SC_32 4294967296.0      // 2^32 fixed-point scale (f32 softmax denom)

// ======== CSR build ========
__global__ void k_deg(const int* __restrict__ dst, unsigned* __restrict__ A){
  int e = blockIdx.x * 256 + threadIdx.x;
  if (e < N_EDGES) atomicAdd(&A[dst[e]], 1u);
}

__global__ __launch_bounds__(1024) void k_scan(unsigned* __restrict__ A){
  __shared__ unsigned ps[1024];
  int t = threadIdx.x;
  const int CH = (N_NODES + 1023) / 1024;
  int base = t * CH;
  unsigned s = 0;
  for (int i = 0; i < CH; i++){ int n = base + i; if (n < N_NODES) s += A[n]; }
  ps[t] = s;
  __syncthreads();
  for (int off = 1; off < 1024; off <<= 1){
    unsigned v = (t >= off) ? ps[t - off] : 0;
    __syncthreads();
    ps[t] += v;
    __syncthreads();
  }
  unsigned ex = (t == 0) ? 0 : ps[t - 1];
  for (int i = 0; i < CH; i++){
    int n = base + i;
    if (n < N_NODES){ unsigned dv = A[n]; A[n] = ex; ex += dv; }
  }
}

__global__ void k_fill(const int* __restrict__ dst, unsigned* __restrict__ A,
                       unsigned* __restrict__ eidx){
  int e = blockIdx.x * 256 + threadIdx.x;
  if (e < N_EDGES) eidx[atomicAdd(&A[dst[e]], 1u)] = (unsigned)e;
}
// post-fill: A[d] == offsets[d+1]; node d range = [d? A[d-1]:0, A[d])

__global__ void k_init(unsigned* __restrict__ sel32, unsigned* __restrict__ krem,
                       unsigned* __restrict__ cnt, unsigned* __restrict__ done,
                       unsigned* __restrict__ ccnt, unsigned* __restrict__ cbelow,
                       unsigned* __restrict__ bcnt, unsigned* __restrict__ cntless,
                       u64* __restrict__ gsums){
  int t = threadIdx.x;
  if (t < 4){ sel32[t]=0; krem[t]=RANK0; cnt[t]=0; ccnt[t]=0; cbelow[t]=0; cntless[t]=0; }
  if (t < 8) gsums[t] = 0;
  if (t == 0){ done[0] = 0; bcnt[0] = 0; }
}

// ======== transpose fc/fq to [col][k] for refine ========
__global__ void k_prept(const float* __restrict__ fc, const float* __restrict__ fq,
                        float* __restrict__ fcT, float* __restrict__ fqT){
  int i = blockIdx.x * 256 + threadIdx.x;
  if (i >= IN_DIM * 128) return;
  int k = i >> 7, c = i & 127;
  fcT[(size_t)c * 256 + k] = fc[i];
  fqT[(size_t)c * 256 + k] = fq[i];
}

// ======== single f32 GEMM: double-buffered LDS, 1 barrier per K-tile ========
#define BM 128
#define BK 16
__global__ __launch_bounds__(256) void k_gemm384(const float* __restrict__ A,
    const float* __restrict__ Wl, const float* __restrict__ fc,
    const float* __restrict__ fq, float* __restrict__ C){
  __shared__ float As[2][BK][BM + 4];
  __shared__ float Bs[2][BK][128 + 4];
  int tid = threadIdx.x;
  int m0 = blockIdx.x * BM;
  int n0 = blockIdx.y * 128;               // 0:ft(Wl^T)  128:fc  256:fq
  int ty = tid / 16, tx = tid % 16;
  const float* Bsrc = (n0 == 128) ? fc : fq;

  int sA0r = (tid * 2) >> 2,     sA0c = (tid * 2) & 3;
  int sA1r = (tid * 2 + 1) >> 2, sA1c = (tid * 2 + 1) & 3;
  int sB0k = (tid * 2) >> 5,     sB0c = (tid * 2) & 31;
  int sB1k = (tid * 2 + 1) >> 5, sB1c = (tid * 2 + 1) & 31;

  float acc[8][8];
  #pragma unroll
  for (int i = 0; i < 8; i++)
    #pragma unroll
    for (int j = 0; j < 8; j++) acc[i][j] = 0.f;

  float4 rA0, rA1, rB0, rB1;
  {
    int r0 = m0 + sA0r, r1 = m0 + sA1r;
    rA0 = (r0 < N_NODES) ? *(const float4*)&A[(size_t)r0 * IN_DIM + sA0c * 4] : make_float4(0,0,0,0);
    rA1 = (r1 < N_NODES) ? *(const float4*)&A[(size_t)r1 * IN_DIM + sA1c * 4] : make_float4(0,0,0,0);
    if (n0 == 0){
      rB0 = *(const float4*)&Wl[(size_t)sA0r * IN_DIM + sA0c * 4];
      rB1 = *(const float4*)&Wl[(size_t)sA1r * IN_DIM + sA1c * 4];
    } else {
      rB0 = *(const float4*)&Bsrc[(size_t)sB0k * 128 + sB0c * 4];
      rB1 = *(const float4*)&Bsrc[(size_t)sB1k * 128 + sB1c * 4];
    }
  }

  int p = 0;
  for (int k0 = 0; k0 < IN_DIM; k0 += BK){
    As[p][sA0c * 4 + 0][sA0r] = rA0.x; As[p][sA0c * 4 + 1][sA0r] = rA0.y;
    As[p][sA0c * 4 + 2][sA0r] = rA0.z; As[p][sA0c * 4 + 3][sA0r] = rA0.w;
    As[p][sA1c * 4 + 0][sA1r] = rA1.x; As[p][sA1c * 4 + 1][sA1r] = rA1.y;
    As[p][sA1c * 4 + 2][sA1r] = rA1.z; As[p][sA1c * 4 + 3][sA1r] = rA1.w;
    if (n0 == 0){
      Bs[p][sA0c * 4 + 0][sA0r] = rB0.x; Bs[p][sA0c * 4 + 1][sA0r] = rB0.y;
      Bs[p][sA0c * 4 + 2][sA0r] = rB0.z; Bs[p][sA0c * 4 + 3][sA0r] = rB0.w;
      Bs[p][sA1c * 4 + 0][sA1r] = rB1.x; Bs[p][sA1c * 4 + 1][sA1r] = rB1.y;
      Bs[p][sA1c * 4 + 2][sA1r] = rB1.z; Bs[p][sA1c * 4 + 3][sA1r] = rB1.w;
    } else {
      *(float4*)&Bs[p][sB0k][sB0c * 4] = rB0;
      *(float4*)&Bs[p][sB1k][sB1c * 4] = rB1;
    }
    __syncthreads();
    if (k0 + BK < IN_DIM){
      int kn = k0 + BK;
      int r0 = m0 + sA0r, r1 = m0 + sA1r;
      rA0 = (r0 < N_NODES) ? *(const float4*)&A[(size_t)r0 * IN_DIM + kn + sA0c * 4] : make_float4(0,0,0,0);
      rA1 = (r1 < N_NODES) ? *(const float4*)&A[(size_t)r1 * IN_DIM + kn + sA1c * 4] : make_float4(0,0,0,0);
      if (n0 == 0){
        rB0 = *(const float4*)&Wl[(size_t)sA0r * IN_DIM + kn + sA0c * 4];
        rB1 = *(const float4*)&Wl[(size_t)sA1r * IN_DIM + kn + sA1c * 4];
      } else {
        rB0 = *(const float4*)&Bsrc[(size_t)(kn + sB0k) * 128 + sB0c * 4];
        rB1 = *(const float4*)&Bsrc[(size_t)(kn + sB1k) * 128 + sB1c * 4];
      }
    }
    #pragma unroll
    for (int kk = 0; kk < BK; kk++){
      float4 a0 = *(const float4*)&As[p][kk][ty * 4];
      float4 a1 = *(const float4*)&As[p][kk][64 + ty * 4];
      float4 b0 = *(const float4*)&Bs[p][kk][tx * 4];
      float4 b1 = *(const float4*)&Bs[p][kk][64 + tx * 4];
      float av[8] = {a0.x, a0.y, a0.z, a0.w, a1.x, a1.y, a1.z, a1.w};
      float bv[8] = {b0.x, b0.y, b0.z, b0.w, b1.x, b1.y, b1.z, b1.w};
      #pragma unroll
      for (int i = 0; i < 8; i++)
        #pragma unroll
        for (int j = 0; j < 8; j++)
          acc[i][j] = fmaf(av[i], bv[j], acc[i][j]);
    }
    p ^= 1;
  }
  #pragma unroll
  for (int i = 0; i < 8; i++){
    int r = m0 + ((i < 4) ? (ty * 4 + i) : (64 + ty * 4 + (i - 4)));
    if (r >= N_NODES) continue;
    *(float4*)&C[(size_t)r * 384 + n0 + tx * 4]      = make_float4(acc[i][0], acc[i][1], acc[i][2], acc[i][3]);
    *(float4*)&C[(size_t)r * 384 + n0 + 64 + tx * 4] = make_float4(acc[i][4], acc[i][5], acc[i][6], acc[i][7]);
  }
}

// ======== f32 fused edge logits + softmax: 2 dst per wave, float4 lanes ========
__global__ __launch_bounds__(256) void k_softedge32(const float* __restrict__ fcq,
    const int* __restrict__ src, const unsigned* __restrict__ A,
    const unsigned* __restrict__ eidx, float* __restrict__ abuf){
  __shared__ float lds_a[8][DEG_CAP * 4];
  int tid = threadIdx.x;
  int wv = tid >> 6;
  int l = tid & 63;
  int half = l >> 5;
  int ll = l & 31;
  int ds = wv * 2 + half;                 // dst slot in block (0..7)
  int d = blockIdx.x * 8 + ds;
  bool ok = (d < N_NODES);
  unsigned k0 = 0, k1 = 0;
  if (ok){ k0 = d ? A[d - 1] : 0u; k1 = A[d]; }
  unsigned deg = k1 - k0;                 // uniform within half-wave
  float4 c4 = make_float4(0.f, 0.f, 0.f, 0.f);
  float4 q4n = make_float4(0.f, 0.f, 0.f, 0.f);
  if (deg){
    c4 = *(const float4*)&fcq[(size_t)d * 384 + 128 + ll * 4];
    int sn = src[eidx[k0]];
    q4n = *(const float4*)&fcq[(size_t)sn * 384 + 256 + ll * 4];
  }
  float m = -1.0e30f;
  for (unsigned kk = 0; kk < deg; kk++){
    float4 q4 = q4n;
    if (kk + 1 < deg){
      int s2 = src[eidx[k0 + kk + 1]];
      q4n = *(const float4*)&fcq[(size_t)s2 * 384 + 256 + ll * 4];
    }
    float v = (q4.x - c4.x) * c4.x;
    v = fmaf(q4.y - c4.y, c4.y, v);
    v = fmaf(q4.z - c4.z, c4.z, v);
    v = fmaf(q4.w - c4.w, c4.w, v);
    v += __shfl_xor(v, 1);
    v += __shfl_xor(v, 2);
    v += __shfl_xor(v, 4);
    float a = (v > 0.f) ? v : expm1f(v);   // ELU; identical across 8-lane group
    m = fmaxf(m, a);
    if ((ll & 7) == 0) lds_a[ds][kk * 4 + (ll >> 3)] = a;
  }
  float mm = __shfl(m, half * 32 + (ll & 3) * 8);   // max of head (ll&3)
  unsigned nj = deg * 4;
  long long sfx = 0;
  for (unsigned jj = ll; jj < nj; jj += 32){
    float ex = __expf(lds_a[ds][jj] - mm);
    lds_a[ds][jj] = ex;
    sfx += (long long)llrintf(ex * (float)SC_32);
  }
  sfx += __shfl_xor(sfx, 4);
  sfx += __shfl_xor(sfx, 8);
  sfx += __shfl_xor(sfx, 16);
  if (deg){
    float sd = (float)((double)sfx * (1.0 / SC_32));
    for (unsigned jj = ll; jj < nj; jj += 32)
      abuf[(size_t)k0 * 4 + jj] = lds_a[ds][jj] / sd;
  }
}

// ======== f32 radix select (u32 keys; attn > 0 -> bits ordered) ========
__global__ __launch_bounds__(256) void k_hp32(const float* __restrict__ attn,
    unsigned* __restrict__ sel32, unsigned* __restrict__ krem, unsigned* __restrict__ cnt,
    unsigned* __restrict__ hist, unsigned* __restrict__ done, unsigned maskHi, int shift){
  __shared__ unsigned lh[1024];
  __shared__ unsigned ticket;
  for (int j = threadIdx.x; j < 1024; j += 256) lh[j] = 0;
  __syncthreads();
  int i0 = blockIdx.x * 256 + threadIdx.x;
  int hh = i0 & 3;
  unsigned sel = sel32[hh] & maskHi;
  const int total = N_EDGES * 4;
  for (int i = i0; i < total; i += gridDim.x * 256){
    unsigned u = __float_as_uint(attn[i]);
    if ((u & maskHi) == sel)
      atomicAdd(&lh[hh * 256 + ((u >> shift) & 255u)], 1u);
  }
  __syncthreads();
  for (int j = threadIdx.x; j < 1024; j += 256)
    if (lh[j]) atomicAdd(&hist[j], lh[j]);
  __threadfence();
  if (threadIdx.x == 0) ticket = atomicAdd(done, 1u);
  __syncthreads();
  if (ticket == gridDim.x - 1){
    __threadfence();
    for (int j = threadIdx.x; j < 1024; j += 256){ lh[j] = hist[j]; hist[j] = 0; }
    __syncthreads();
    if (threadIdx.x < 4){
      int t = threadIdx.x;
      unsigned kr = krem[t], cum = 0, b = 0;
      for (; b < 256; b++){
        unsigned c2 = lh[t * 256 + b];
        if (kr < cum + c2) break;
        cum += c2;
      }
      sel32[t] |= b << shift;
      krem[t] = kr - cum;
      cnt[t] += cum;
    }
    if (threadIdx.x == 0) *done = 0;
  }
}

__global__ __launch_bounds__(256) void k_compact32(const float* __restrict__ attn,
    const unsigned* __restrict__ sel32, unsigned* __restrict__ ccnt,
    float* __restrict__ cand){
  __shared__ unsigned lcnt[4];
  __shared__ unsigned lbase[4];
  int t = threadIdx.x;
  if (t < 4) lcnt[t] = 0;
  __syncthreads();
  int i0 = blockIdx.x * 256 + t;
  int hh = i0 & 3;
  unsigned sel = sel32[hh] & 0xFFFF0000u;
  const int total = N_EDGES * 4;
  unsigned mc = 0;
  for (int i = i0; i < total; i += gridDim.x * 256){
    unsigned u = __float_as_uint(attn[i]);
    if ((u & 0xFFFF0000u) == sel) mc++;
  }
  unsigned my_local = mc ? atomicAdd(&lcnt[hh], mc) : 0u;
  __syncthreads();
  if (t < 4) lbase[t] = lcnt[t] ? atomicAdd(&ccnt[t], lcnt[t]) : 0u;
  __syncthreads();
  if (mc == 0) return;
  unsigned pos = lbase[hh] + my_local;
  float* cp = cand + (size_t)hh * N_EDGES;
  for (int i = i0; i < total; i += gridDim.x * 256){
    float v = attn[i];
    unsigned u = __float_as_uint(v);
    if ((u & 0xFFFF0000u) == sel) cp[pos++] = v;
  }
}

__global__ __launch_bounds__(256) void k_fin32(const float* __restrict__ cand,
    const unsigned* __restrict__ ccnt, unsigned* __restrict__ sel32,
    unsigned* __restrict__ krem, unsigned* __restrict__ cnt,
    unsigned* __restrict__ hist, unsigned* __restrict__ done, int shift){
  __shared__ unsigned lh[256];
  __shared__ unsigned ticket;
  int t = threadIdx.x;
  lh[t] = 0;
  __syncthreads();
  int h = blockIdx.x & 3;
  int bidx = blockIdx.x >> 2;
  int bph = gridDim.x >> 2;
  unsigned maskHi = ~((1u << (shift + 8)) - 1u);
  unsigned sel = sel32[h] & maskHi;
  unsigned n = ccnt[h];
  const float* cp = cand + (size_t)h * N_EDGES;
  for (unsigned i = bidx * 256 + t; i < n; i += bph * 256){
    unsigned u = __float_as_uint(cp[i]);
    if ((u & maskHi) == sel) atomicAdd(&lh[(u >> shift) & 255u], 1u);
  }
  __syncthreads();
  if (lh[t]) atomicAdd(&hist[h * 256 + t], lh[t]);
  __threadfence();
  if (t == 0) ticket = atomicAdd(done, 1u);
  __syncthreads();
  if (ticket == gridDim.x - 1){
    __threadfence();
    __shared__ unsigned fh[1024];
    for (int j = t; j < 1024; j += 256){ fh[j] = hist[j]; hist[j] = 0; }
    __syncthreads();
    if (t < 4){
      unsigned kr = krem[t], cum = 0, b = 0;
      for (; b < 256; b++){
        unsigned c2 = fh[t * 256 + b];
        if (kr < cum + c2) break;
        cum += c2;
      }
      sel32[t] |= b << shift;
      krem[t] = kr - cum;
      cnt[t] += cum;
    }
    if (t == 0) *done = 0;
  }
}

// ======== fused: boundary mark + certain-edge sums + a3 (one abuf pass) ========
__global__ __launch_bounds__(256) void k_marksums(const float* __restrict__ attn,
    const unsigned* __restrict__ sel32, unsigned* __restrict__ cbelow,
    unsigned* __restrict__ bcnt, unsigned* __restrict__ blist,
    u64* __restrict__ gsums, float* __restrict__ a3){
  int t = threadIdx.x;
  int i0 = blockIdx.x * 256 + t;
  int hh = t & 3;
  double thd = (double)__uint_as_float(sel32[hh]);
  double lo = thd * (1.0 - MARG), hi = thd * (1.0 + MARG);
  double al = 0.0, ag = 0.0;
  unsigned below = 0;
  const int total = N_EDGES * 4;
  for (int i = i0; i < total; i += gridDim.x * 256){
    float vf = attn[i];
    double v = (double)vf;
    if (v < lo){ al += v; below++; a3[i] = 0.f; }
    else if (v > hi){ ag += v; a3[i] = vf; }
    else {
      unsigned p = atomicAdd(bcnt, 1u);
      if (p < BCAP) blist[p] = (unsigned)i;
      a3[i] = 0.f;                         // boundary: fixed by k_bfinal
    }
  }
  long long ql = llrint(al * SC_FX);
  long long qg = llrint(ag * SC_FX);
  #pragma unroll
  for (int m = 4; m < 64; m <<= 1){
    ql += __shfl_xor(ql, m);
    qg += __shfl_xor(qg, m);
    below += __shfl_xor(below, m);
  }
  __shared__ long long sl[16], sg[16];
  __shared__ unsigned sb[16];
  int wv = t >> 6;
  if ((t & 63) < 4){ sl[wv * 4 + hh] = ql; sg[wv * 4 + hh] = qg; sb[wv * 4 + hh] = below; }
  __syncthreads();
  if (t < 4){
    long long a = sl[t] + sl[4 + t] + sl[8 + t] + sl[12 + t];
    long long b = sg[t] + sg[4 + t] + sg[8 + t] + sg[12 + t];
    unsigned bl = sb[t] + sb[4 + t] + sb[8 + t] + sb[12 + t];
    if (a) atomicAdd(&gsums[t],     (u64)a);
    if (b) atomicAdd(&gsums[4 + t], (u64)b);
    if (bl) atomicAdd(&cbelow[t], bl);
  }
}

// ======== exact f64 boundary refine: block/entry, LDS-staged weights ========
__global__ __launch_bounds__(256) void k_brefine(const float* __restrict__ h,
    const float* __restrict__ fcT, const float* __restrict__ fqT,
    const int* __restrict__ src, const int* __restrict__ dst,
    const unsigned* __restrict__ A, const unsigned* __restrict__ eidx,
    const unsigned* __restrict__ blist, const unsigned* __restrict__ bcnt,
    double* __restrict__ bval){
  __shared__ float wqs[32][257];
  __shared__ double cs[32];
  __shared__ double la[DEG_CAP];
  int tid = threadIdx.x;
  int wv = tid >> 6;
  int l = tid & 63;
  int j = l & 31;
  int khalf = l >> 5;
  unsigned nb = *bcnt; if (nb > BCAP) nb = BCAP;
  for (unsigned idx = blockIdx.x; idx < nb; idx += gridDim.x){
    unsigned slot = blist[idx];
    unsigned kslot = slot >> 2;
    int hh = slot & 3;
    int d = dst[eidx[kslot]];
    unsigned k0 = d ? A[d - 1] : 0u, k1 = A[d];
    unsigned deg = k1 - k0;
    {
      int col = tid >> 3, seg = tid & 7;
      const float* gsrc = fqT + (size_t)(hh * 32 + col) * 256 + seg * 32;
      #pragma unroll
      for (int r = 0; r < 8; r++){
        float4 v = *(const float4*)&gsrc[r * 4];
        float* wdst = &wqs[col][seg * 32 + r * 4];
        wdst[0] = v.x; wdst[1] = v.y; wdst[2] = v.z; wdst[3] = v.w;
      }
    }
    __syncthreads();
    if (wv == 0){
      const float* hd = h + (size_t)d * 256 + khalf * 128;
      const float* wc = fcT + (size_t)(hh * 32 + j) * 256 + khalf * 128;
      double c0 = 0.0, c1 = 0.0, c2 = 0.0, c3 = 0.0;
      #pragma unroll 8
      for (int i = 0; i < 128; i += 4){
        float4 hv = *(const float4*)&hd[i];
        float4 w2 = *(const float4*)&wc[i];
        c0 = fma((double)hv.x, (double)w2.x, c0);
        c1 = fma((double)hv.y, (double)w2.y, c1);
        c2 = fma((double)hv.z, (double)w2.z, c2);
        c3 = fma((double)hv.w, (double)w2.w, c3);
      }
      double c = (c0 + c1) + (c2 + c3);
      c += __shfl_xor(c, 32);
      if (l < 32) cs[l] = c;
    }
    __syncthreads();
    double cj = cs[j];
    for (unsigned k = k0 + wv; k < k1; k += 4){
      int s = src[eidx[k]];
      const float* hs = h + (size_t)s * 256 + khalf * 128;
      const float* wr = &wqs[j][khalf * 128];
      float4 hv = *(const float4*)&hs[0];
      double q0 = 0.0, q1 = 0.0, q2 = 0.0, q3 = 0.0;
      #pragma unroll 4
      for (int i = 0; i < 128; i += 4){
        float4 cur = hv;
        if (i + 4 < 128) hv = *(const float4*)&hs[i + 4];
        q0 = fma((double)cur.x, (double)wr[i + 0], q0);
        q1 = fma((double)cur.y, (double)wr[i + 1], q1);
        q2 = fma((double)cur.z, (double)wr[i + 2], q2);
        q3 = fma((double)cur.w, (double)wr[i + 3], q3);
      }
      double q = (q0 + q1) + (q2 + q3);
      q += __shfl_xor(q, 32);
      double p = (q - cj) * cj;
      p += __shfl_xor(p, 1);
      p += __shfl_xor(p, 2);
      p += __shfl_xor(p, 4);
      p += __shfl_xor(p, 8);
      p += __shfl_xor(p, 16);
      double a = (p > 0.0) ? p : expm1(p);
      if (l == 0) la[k - k0] = a;
    }
    __syncthreads();
    if (wv == 0){
      double m = -1.0e300;
      for (unsigned kk = l; kk < deg; kk += 64) m = fmax(m, la[kk]);
      #pragma unroll
      for (int msk = 1; msk < 64; msk <<= 1) m = fmax(m, __shfl_xor(m, msk));
      long long sfx = 0;
      for (unsigned kk = l; kk < deg; kk += 64)
        sfx += llrint(exp(la[kk] - m) * SC_FX);
      #pragma unroll
      for (int msk = 1; msk < 64; msk <<= 1) sfx += __shfl_xor(sfx, msk);
      if (l == 0){
        double sd = (double)sfx * (1.0 / SC_FX);
        bval[idx] = exp(la[kslot - k0] - m) / sd;
      }
    }
    __syncthreads();
  }
}

// ======== exact f64 select among boundary (1 block per head) ========
__global__ __launch_bounds__(256) void k_bselect(const double* __restrict__ bval,
    const unsigned* __restrict__ blist, const unsigned* __restrict__ bcnt,
    const unsigned* __restrict__ cbelow, double* __restrict__ thd64,
    unsigned* __restrict__ cntless){
  __shared__ unsigned lh[256];
  __shared__ u64 s_sel;
  __shared__ unsigned s_kr, s_cnt;
  int hsel = blockIdx.x;
  int t = threadIdx.x;
  unsigned nb = *bcnt; if (nb > BCAP) nb = BCAP;
  if (t == 0){ s_sel = 0; s_kr = RANK0 - cbelow[hsel]; s_cnt = 0; }
  __syncthreads();
  for (int p = 0; p < 8; p++){
    int shift = 56 - 8 * p;
    u64 maskHi = (p == 0) ? 0ull : (~0ull) << (64 - 8 * p);
    lh[t] = 0;
    __syncthreads();
    u64 sel = s_sel;
    for (unsigned i = t; i < nb; i += 256){
      if ((int)(blist[i] & 3) == hsel){
        u64 u = (u64)__double_as_longlong(bval[i]);
        if ((u & maskHi) == sel) atomicAdd(&lh[(unsigned)((u >> shift) & 255u)], 1u);
      }
    }
    __syncthreads();
    if (t == 0){
      unsigned kr = s_kr, cum = 0, b = 0;
      for (; b < 256; b++){
        unsigned c2 = lh[b];
        if (kr < cum + c2) break;
        cum += c2;
      }
      s_sel |= ((u64)b) << shift;
      s_kr = kr - cum;
      s_cnt += cum;
    }
    __syncthreads();
  }
  if (t == 0){
    thd64[hsel] = __longlong_as_double((long long)s_sel);
    cntless[hsel] = cbelow[hsel] + s_cnt;
  }
}

// ======== finalize boundary entries: exact cut + sums + a3 ========
__global__ void k_bfinal(const unsigned* __restrict__ blist, const double* __restrict__ bval,
    const unsigned* __restrict__ bcnt, const double* __restrict__ thd64,
    u64* __restrict__ gsums, float* __restrict__ a3){
  unsigned nb = *bcnt; if (nb > BCAP) nb = BCAP;
  for (unsigned idx = blockIdx.x * 256 + threadIdx.x; idx < nb; idx += gridDim.x * 256){
    unsigned slot = blist[idx];
    int hh = slot & 3;
    double v = bval[idx];
    bool kept = (v >= thd64[hh]);
    a3[slot] = kept ? (float)v : 0.f;
    atomicAdd(&gsums[(kept ? 4 : 0) + hh], (u64)llrint(v * SC_FX));
  }
}

__global__ void k_ratio(const double* __restrict__ thd64, const unsigned* __restrict__ cntless,
                        const u64* __restrict__ gsums, double* __restrict__ trd){
  int t = threadIdx.x;
  if (t < 4){
    double sless = (double)(long long)gsums[t]     * (1.0 / SC_FX);
    double sge   = (double)(long long)gsums[4 + t] * (1.0 / SC_FX);
    double topk  = sless + (double)(LS - (int)cntless[t]) * thd64[t];
    trd[t] = thd64[t];
    trd[4 + t] = (sge + topk) / sge;
  }
}

// ======== CSR gather-scatter + fused head-mean: 2 dst per wave, float4 ========
// half-wave per dst; lane ll owns dims [4ll,4ll+4), head hh = ll>>3.
__global__ __launch_bounds__(256) void k_scatter2(const float* __restrict__ fcq,
    const int* __restrict__ src, const unsigned* __restrict__ A,
    const unsigned* __restrict__ eidx, const float* __restrict__ a3,
    const double* __restrict__ trd, float* __restrict__ out){
  int tid = threadIdx.x;
  int wv = tid >> 6;
  int l = tid & 63;
  int half = l >> 5;
  int ll = l & 31;
  int d = blockIdx.x * 8 + wv * 2 + half;
  if (d >= N_NODES) return;     // tail: whole half-wave exits together (uniform d)
  int hh = ll >> 3;
  double ratio = trd[4 + hh];
  unsigned k0 = d ? A[d - 1] : 0u, k1 = A[d];
  long long acc0 = 0, acc1 = 0, acc2 = 0, acc3 = 0;
  float wn = (k0 < k1) ? a3[(size_t)k0 * 4 + hh] : 0.f;
  unsigned en = (k0 < k1) ? eidx[k0] : 0u;
  for (unsigned k = k0; k < k1; k++){
    float w = wn;
    unsigned e = en;
    if (k + 1 < k1){ wn = a3[(size_t)(k + 1) * 4 + hh]; en = eidx[k + 1]; }
    unsigned hb = (unsigned)(__ballot(w != 0.f) >> (half * 32));
    if (hb == 0u) continue;     // all 4 heads dropped (~71% of edges)
    if (w != 0.f){
      int s = src[e];
      float4 f = *(const float4*)&fcq[(size_t)s * 384 + ll * 4];
      double a3r = (double)w * ratio;
      acc0 += llrint(a3r * (double)f.x * SC_FX);
      acc1 += llrint(a3r * (double)f.y * SC_FX);
      acc2 += llrint(a3r * (double)f.z * SC_FX);
      acc3 += llrint(a3r * (double)f.w * SC_FX);
    }
  }
  float* p = &out[(size_t)d * OUTC + ll * 4];
  p[0] = (float)((double)acc0 * (1.0 / SC_FX));
  p[1] = (float)((double)acc1 * (1.0 / SC_FX));
  p[2] = (float)((double)acc2 * (1.0 / SC_FX));
  p[3] = (float)((double)acc3 * (1.0 / SC_FX));
  // fused head-mean: each of the 32 lanes writes out[d][128+ll]
  const float* pf = &fcq[(size_t)d * 384];
  out[(size_t)d * OUTC + 128 + ll] = 0.25f * (pf[ll] + pf[32 + ll] + pf[64 + ll] + pf[96 + ll]);
}

extern "C" void kernel_launch(void* const* d_in, const int* in_sizes, int n_in,
                              void* d_out, int out_size, void* d_ws, size_t ws_size,
                              hipStream_t stream){
  const float* h  = (const float*)d_in[0];
  const float* Wl = (const float*)d_in[1];
  const float* fc = (const float*)d_in[2];
  const float* fq = (const float*)d_in[3];
  const int* src  = (const int*)d_in[4];
  const int* dst  = (const int*)d_in[5];
  float* out = (float*)d_out;

  char* ws = (char*)d_ws;
  float*    fcq  = (float*)(ws);                   // 76,800,000
  unsigned* A    = (unsigned*)(ws + 76800000);     // 200,004 (pad to 77,000,064)
  unsigned* eidx = (unsigned*)(ws + 77000064);     // 3,200,000
  float*    a3   = (float*)(ws + 80200064);        // 12,800,000
  unsigned* hist = (unsigned*)(ws + 93000064);     // 4,096
  unsigned* sel32  = (unsigned*)(ws + 93004160);   // 16
  unsigned* krem   = (unsigned*)(ws + 93004176);   // 16
  unsigned* cnt    = (unsigned*)(ws + 93004192);   // 16
  unsigned* done   = (unsigned*)(ws + 93004208);   // 16
  unsigned* ccnt   = (unsigned*)(ws + 93004224);   // 16
  unsigned* cbelow = (unsigned*)(ws + 93004240);   // 16
  unsigned* bcnt   = (unsigned*)(ws + 93004256);   // 16
  unsigned* cntless= (unsigned*)(ws + 93004272);   // 16
  u64*      gsums  = (u64*)(ws + 93004288);        // 64
  double*   thd64  = (double*)(ws + 93004352);     // 32
  double*   trd    = (double*)(ws + 93004416);     // 64
  unsigned* blist  = (unsigned*)(ws + 93008896);   // 262,144 (BCAP*4)
  double*   bval   = (double*)(ws + 93271040);     // 524,288 (BCAP*8)
  float*    fcT    = (float*)(ws + 93795328);      // 131,072
  float*    fqT    = (float*)(ws + 93926400);      // 131,072

  // scratch inside d_out (32 MB): both fully dead before scatter2 writes
  float* abuf = (float*)d_out;                     // 12.8 MB attn32
  float* cand = (float*)((char*)d_out + 12800000); // 12.8 MB select candidates

  hipMemsetAsync(A, 0, 200004, stream);
  hipMemsetAsync(hist, 0, 4096, stream);
  k_init<<<1, 64, 0, stream>>>(sel32, krem, cnt, done, ccnt, cbelow, bcnt, cntless, gsums);
  k_prept<<<(IN_DIM * 128 + 255) / 256, 256, 0, stream>>>(fc, fq, fcT, fqT);

  // CSR
  k_deg<<<(N_EDGES + 255) / 256, 256, 0, stream>>>(dst, A);
  k_scan<<<1, 1024, 0, stream>>>(A);
  k_fill<<<(N_EDGES + 255) / 256, 256, 0, stream>>>(dst, A, eidx);

  // single f32 GEMM -> [ft | c | q]
  dim3 gg((N_NODES + BM - 1) / BM, 3);
  k_gemm384<<<gg, 256, 0, stream>>>(h, Wl, fc, fq, fcq);

  // f32 fused edge logits + softmax (2 dst per wave)
  k_softedge32<<<(N_NODES + 7) / 8, 256, 0, stream>>>(fcq, src, A, eidx, abuf);

  // exact f32 rank select: 2 global passes, compact, 2 finish passes
  k_hp32<<<1024, 256, 0, stream>>>(abuf, sel32, krem, cnt, hist, done, 0u, 24);
  k_hp32<<<1024, 256, 0, stream>>>(abuf, sel32, krem, cnt, hist, done, 0xFF000000u, 16);
  k_compact32<<<1024, 256, 0, stream>>>(abuf, sel32, ccnt, cand);
  k_fin32<<<256, 256, 0, stream>>>(cand, ccnt, sel32, krem, cnt, hist, done, 8);
  k_fin32<<<256, 256, 0, stream>>>(cand, ccnt, sel32, krem, cnt, hist, done, 0);

  // fused: boundary mark + certain sums + a3 (one pass)
  k_marksums<<<2048, 256, 0, stream>>>(abuf, sel32, cbelow, bcnt, blist, gsums, a3);

  // boundary: refine in f64 (block per entry, LDS weights), exact select
  k_brefine<<<2048, 256, 0, stream>>>(h, fcT, fqT, src, dst, A, eidx, blist, bcnt, bval);
  k_bselect<<<4, 256, 0, stream>>>(bval, blist, bcnt, cbelow, thd64, cntless);
  k_bfinal<<<64, 256, 0, stream>>>(blist, bval, bcnt, thd64, gsums, a3);
  k_ratio<<<1, 64, 0, stream>>>(thd64, cntless, gsums, trd);

  // output (scatter + fused head-mean), 2 dst per wave
  k_scatter2<<<(N_NODES + 7) / 8, 256, 0, stream>>>(fcq, src, A, eidx, a3, trd, out);
}

// Round 21
// 903.348 us; speedup vs baseline: 1.7290x; 1.0167x over previous
//
#include <hip/hip_runtime.h>
#include <hip/hip_bf16.h>
#include <math.h>

#define N_NODES 50000
#define N_EDGES 800000
#define DH 32
#define IN_DIM 256
#define OUTC 160
#define LS 570400     // int(0.713 * 800000) -> exactly 570400
#define RANK0 (LS - 1)
#define DEG_CAP 160   // max in-degree supported (Poisson(16))
#define BCAP 65536    // boundary-candidate cap (expect ~1K)
#define MARG 3.0e-4   // relative margin around thd32 (~30x worst f32 error)

typedef unsigned long long u64;
#define SC_FX 1099511627776.0   // 2^40 fixed-point scale (f64 sums)
#define SC_32 4294967296.0      // 2^32 fixed-point scale (f32 softmax denom)

// ======== CSR build ========
__global__ void k_deg(const int* __restrict__ dst, unsigned* __restrict__ A){
  int e = blockIdx.x * 256 + threadIdx.x;
  if (e < N_EDGES) atomicAdd(&A[dst[e]], 1u);
}

__global__ __launch_bounds__(1024) void k_scan(unsigned* __restrict__ A){
  __shared__ unsigned ps[1024];
  int t = threadIdx.x;
  const int CH = (N_NODES + 1023) / 1024;
  int base = t * CH;
  unsigned s = 0;
  for (int i = 0; i < CH; i++){ int n = base + i; if (n < N_NODES) s += A[n]; }
  ps[t] = s;
  __syncthreads();
  for (int off = 1; off < 1024; off <<= 1){
    unsigned v = (t >= off) ? ps[t - off] : 0;
    __syncthreads();
    ps[t] += v;
    __syncthreads();
  }
  unsigned ex = (t == 0) ? 0 : ps[t - 1];
  for (int i = 0; i < CH; i++){
    int n = base + i;
    if (n < N_NODES){ unsigned dv = A[n]; A[n] = ex; ex += dv; }
  }
}

__global__ void k_fill(const int* __restrict__ dst, unsigned* __restrict__ A,
                       unsigned* __restrict__ eidx){
  int e = blockIdx.x * 256 + threadIdx.x;
  if (e < N_EDGES) eidx[atomicAdd(&A[dst[e]], 1u)] = (unsigned)e;
}
// post-fill: A[d] == offsets[d+1]; node d range = [d? A[d-1]:0, A[d])

// ======== fused init: zero A/hist, scalars, fc/fq transpose ========
__global__ void k_init2(unsigned* __restrict__ A, unsigned* __restrict__ hist,
    unsigned* __restrict__ sel32, unsigned* __restrict__ krem,
    unsigned* __restrict__ cnt, unsigned* __restrict__ done,
    unsigned* __restrict__ ccnt, unsigned* __restrict__ cbelow,
    unsigned* __restrict__ bcnt, u64* __restrict__ gsums,
    const float* __restrict__ fc, const float* __restrict__ fq,
    float* __restrict__ fcT, float* __restrict__ fqT){
  int gid = blockIdx.x * 256 + threadIdx.x;      // 65536 threads
  if (gid <= N_NODES) A[gid] = 0;
  if (gid < 1024) hist[gid] = 0;
  if (gid < 4){ sel32[gid]=0; krem[gid]=RANK0; cnt[gid]=0; ccnt[gid]=0; cbelow[gid]=0; }
  if (gid < 8) gsums[gid] = 0;
  if (gid == 0){ done[0] = 0; bcnt[0] = 0; }
  if (gid < IN_DIM * 128){
    int k = gid >> 7, c = gid & 127;
    fcT[(size_t)c * 256 + k] = fc[gid];
    fqT[(size_t)c * 256 + k] = fq[gid];
  }
}

// ======== single f32 GEMM: BK=8 double-buffered, 1 barrier per K-tile ========
#define BM 128
#define BK 8
__global__ __launch_bounds__(256) void k_gemm384(const float* __restrict__ A,
    const float* __restrict__ Wl, const float* __restrict__ fc,
    const float* __restrict__ fq, float* __restrict__ C){
  __shared__ float As[2][BK][BM + 4];
  __shared__ float Bs[2][BK][128 + 4];
  int tid = threadIdx.x;
  int m0 = blockIdx.x * BM;
  int n0 = blockIdx.y * 128;               // 0:ft(Wl^T)  128:fc  256:fq
  int ty = tid / 16, tx = tid % 16;
  const float* Bsrc = (n0 == 128) ? fc : fq;

  int aR = tid >> 1, aC = tid & 1;         // A/Wl staging: row/j = aR, k-quad = aC
  int bK = tid >> 5, bC = tid & 31;        // fc/fq staging: k = bK, col-quad = bC

  float acc[8][8];
  #pragma unroll
  for (int i = 0; i < 8; i++)
    #pragma unroll
    for (int j = 0; j < 8; j++) acc[i][j] = 0.f;

  float4 rA, rB;
  {
    int r0 = m0 + aR;
    rA = (r0 < N_NODES) ? *(const float4*)&A[(size_t)r0 * IN_DIM + aC * 4] : make_float4(0,0,0,0);
    rB = (n0 == 0) ? *(const float4*)&Wl[(size_t)aR * IN_DIM + aC * 4]
                   : *(const float4*)&Bsrc[(size_t)bK * 128 + bC * 4];
  }

  int p = 0;
  for (int k0 = 0; k0 < IN_DIM; k0 += BK){
    As[p][aC * 4 + 0][aR] = rA.x; As[p][aC * 4 + 1][aR] = rA.y;
    As[p][aC * 4 + 2][aR] = rA.z; As[p][aC * 4 + 3][aR] = rA.w;
    if (n0 == 0){
      Bs[p][aC * 4 + 0][aR] = rB.x; Bs[p][aC * 4 + 1][aR] = rB.y;
      Bs[p][aC * 4 + 2][aR] = rB.z; Bs[p][aC * 4 + 3][aR] = rB.w;
    } else {
      *(float4*)&Bs[p][bK][bC * 4] = rB;
    }
    __syncthreads();
    if (k0 + BK < IN_DIM){
      int kn = k0 + BK;
      int r0 = m0 + aR;
      rA = (r0 < N_NODES) ? *(const float4*)&A[(size_t)r0 * IN_DIM + kn + aC * 4] : make_float4(0,0,0,0);
      rB = (n0 == 0) ? *(const float4*)&Wl[(size_t)aR * IN_DIM + kn + aC * 4]
                     : *(const float4*)&Bsrc[(size_t)(kn + bK) * 128 + bC * 4];
    }
    #pragma unroll
    for (int kk = 0; kk < BK; kk++){
      float4 a0 = *(const float4*)&As[p][kk][ty * 4];
      float4 a1 = *(const float4*)&As[p][kk][64 + ty * 4];
      float4 b0 = *(const float4*)&Bs[p][kk][tx * 4];
      float4 b1 = *(const float4*)&Bs[p][kk][64 + tx * 4];
      float av[8] = {a0.x, a0.y, a0.z, a0.w, a1.x, a1.y, a1.z, a1.w};
      float bv[8] = {b0.x, b0.y, b0.z, b0.w, b1.x, b1.y, b1.z, b1.w};
      #pragma unroll
      for (int i = 0; i < 8; i++)
        #pragma unroll
        for (int j = 0; j < 8; j++)
          acc[i][j] = fmaf(av[i], bv[j], acc[i][j]);
    }
    p ^= 1;
  }
  #pragma unroll
  for (int i = 0; i < 8; i++){
    int r = m0 + ((i < 4) ? (ty * 4 + i) : (64 + ty * 4 + (i - 4)));
    if (r >= N_NODES) continue;
    *(float4*)&C[(size_t)r * 384 + n0 + tx * 4]      = make_float4(acc[i][0], acc[i][1], acc[i][2], acc[i][3]);
    *(float4*)&C[(size_t)r * 384 + n0 + 64 + tx * 4] = make_float4(acc[i][4], acc[i][5], acc[i][6], acc[i][7]);
  }
}

// ======== f32 fused edge logits + softmax: 2 dst per wave, float4 lanes ========
__global__ __launch_bounds__(256) void k_softedge32(const float* __restrict__ fcq,
    const int* __restrict__ src, const unsigned* __restrict__ A,
    const unsigned* __restrict__ eidx, float* __restrict__ abuf){
  __shared__ float lds_a[8][DEG_CAP * 4];
  int tid = threadIdx.x;
  int wv = tid >> 6;
  int l = tid & 63;
  int half = l >> 5;
  int ll = l & 31;
  int ds = wv * 2 + half;                 // dst slot in block (0..7)
  int d = blockIdx.x * 8 + ds;
  bool ok = (d < N_NODES);
  unsigned k0 = 0, k1 = 0;
  if (ok){ k0 = d ? A[d - 1] : 0u; k1 = A[d]; }
  unsigned deg = k1 - k0;                 // uniform within half-wave
  float4 c4 = make_float4(0.f, 0.f, 0.f, 0.f);
  float4 q4n = make_float4(0.f, 0.f, 0.f, 0.f);
  if (deg){
    c4 = *(const float4*)&fcq[(size_t)d * 384 + 128 + ll * 4];
    int sn = src[eidx[k0]];
    q4n = *(const float4*)&fcq[(size_t)sn * 384 + 256 + ll * 4];
  }
  float m = -1.0e30f;
  for (unsigned kk = 0; kk < deg; kk++){
    float4 q4 = q4n;
    if (kk + 1 < deg){
      int s2 = src[eidx[k0 + kk + 1]];
      q4n = *(const float4*)&fcq[(size_t)s2 * 384 + 256 + ll * 4];
    }
    float v = (q4.x - c4.x) * c4.x;
    v = fmaf(q4.y - c4.y, c4.y, v);
    v = fmaf(q4.z - c4.z, c4.z, v);
    v = fmaf(q4.w - c4.w, c4.w, v);
    v += __shfl_xor(v, 1);
    v += __shfl_xor(v, 2);
    v += __shfl_xor(v, 4);
    float a = (v > 0.f) ? v : expm1f(v);   // ELU; identical across 8-lane group
    m = fmaxf(m, a);
    if ((ll & 7) == 0) lds_a[ds][kk * 4 + (ll >> 3)] = a;
  }
  float mm = __shfl(m, half * 32 + (ll & 3) * 8);   // max of head (ll&3)
  unsigned nj = deg * 4;
  long long sfx = 0;
  for (unsigned jj = ll; jj < nj; jj += 32){
    float ex = __expf(lds_a[ds][jj] - mm);
    lds_a[ds][jj] = ex;
    sfx += (long long)llrintf(ex * (float)SC_32);
  }
  sfx += __shfl_xor(sfx, 4);
  sfx += __shfl_xor(sfx, 8);
  sfx += __shfl_xor(sfx, 16);
  if (deg){
    float sd = (float)((double)sfx * (1.0 / SC_32));
    for (unsigned jj = ll; jj < nj; jj += 32)
      abuf[(size_t)k0 * 4 + jj] = lds_a[ds][jj] / sd;
  }
}

// ======== f32 radix select (u32 keys; attn > 0 -> bits ordered) ========
__global__ __launch_bounds__(256) void k_hp32(const float* __restrict__ attn,
    unsigned* __restrict__ sel32, unsigned* __restrict__ krem, unsigned* __restrict__ cnt,
    unsigned* __restrict__ hist, unsigned* __restrict__ done, unsigned maskHi, int shift){
  __shared__ unsigned lh[1024];
  __shared__ unsigned ticket;
  for (int j = threadIdx.x; j < 1024; j += 256) lh[j] = 0;
  __syncthreads();
  int i0 = blockIdx.x * 256 + threadIdx.x;
  int hh = i0 & 3;
  unsigned sel = sel32[hh] & maskHi;
  const int total = N_EDGES * 4;
  for (int i = i0; i < total; i += gridDim.x * 256){
    unsigned u = __float_as_uint(attn[i]);
    if ((u & maskHi) == sel)
      atomicAdd(&lh[hh * 256 + ((u >> shift) & 255u)], 1u);
  }
  __syncthreads();
  for (int j = threadIdx.x; j < 1024; j += 256)
    if (lh[j]) atomicAdd(&hist[j], lh[j]);
  __threadfence();
  if (threadIdx.x == 0) ticket = atomicAdd(done, 1u);
  __syncthreads();
  if (ticket == gridDim.x - 1){
    __threadfence();
    for (int j = threadIdx.x; j < 1024; j += 256){ lh[j] = hist[j]; hist[j] = 0; }
    __syncthreads();
    if (threadIdx.x < 4){
      int t = threadIdx.x;
      unsigned kr = krem[t], cum = 0, b = 0;
      for (; b < 256; b++){
        unsigned c2 = lh[t * 256 + b];
        if (kr < cum + c2) break;
        cum += c2;
      }
      sel32[t] |= b << shift;
      krem[t] = kr - cum;
      cnt[t] += cum;
    }
    if (threadIdx.x == 0) *done = 0;
  }
}

__global__ __launch_bounds__(256) void k_compact32(const float* __restrict__ attn,
    const unsigned* __restrict__ sel32, unsigned* __restrict__ ccnt,
    float* __restrict__ cand){
  __shared__ unsigned lcnt[4];
  __shared__ unsigned lbase[4];
  int t = threadIdx.x;
  if (t < 4) lcnt[t] = 0;
  __syncthreads();
  int i0 = blockIdx.x * 256 + t;
  int hh = i0 & 3;
  unsigned sel = sel32[hh] & 0xFFFF0000u;
  const int total = N_EDGES * 4;
  unsigned mc = 0;
  for (int i = i0; i < total; i += gridDim.x * 256){
    unsigned u = __float_as_uint(attn[i]);
    if ((u & 0xFFFF0000u) == sel) mc++;
  }
  unsigned my_local = mc ? atomicAdd(&lcnt[hh], mc) : 0u;
  __syncthreads();
  if (t < 4) lbase[t] = lcnt[t] ? atomicAdd(&ccnt[t], lcnt[t]) : 0u;
  __syncthreads();
  if (mc == 0) return;
  unsigned pos = lbase[hh] + my_local;
  float* cp = cand + (size_t)hh * N_EDGES;
  for (int i = i0; i < total; i += gridDim.x * 256){
    float v = attn[i];
    unsigned u = __float_as_uint(v);
    if ((u & 0xFFFF0000u) == sel) cp[pos++] = v;
  }
}

__global__ __launch_bounds__(256) void k_fin32(const float* __restrict__ cand,
    const unsigned* __restrict__ ccnt, unsigned* __restrict__ sel32,
    unsigned* __restrict__ krem, unsigned* __restrict__ cnt,
    unsigned* __restrict__ hist, unsigned* __restrict__ done, int shift){
  __shared__ unsigned lh[256];
  __shared__ unsigned ticket;
  int t = threadIdx.x;
  lh[t] = 0;
  __syncthreads();
  int h = blockIdx.x & 3;
  int bidx = blockIdx.x >> 2;
  int bph = gridDim.x >> 2;
  unsigned maskHi = ~((1u << (shift + 8)) - 1u);
  unsigned sel = sel32[h] & maskHi;
  unsigned n = ccnt[h];
  const float* cp = cand + (size_t)h * N_EDGES;
  for (unsigned i = bidx * 256 + t; i < n; i += bph * 256){
    unsigned u = __float_as_uint(cp[i]);
    if ((u & maskHi) == sel) atomicAdd(&lh[(u >> shift) & 255u], 1u);
  }
  __syncthreads();
  if (lh[t]) atomicAdd(&hist[h * 256 + t], lh[t]);
  __threadfence();
  if (t == 0) ticket = atomicAdd(done, 1u);
  __syncthreads();
  if (ticket == gridDim.x - 1){
    __threadfence();
    __shared__ unsigned fh[1024];
    for (int j = t; j < 1024; j += 256){ fh[j] = hist[j]; hist[j] = 0; }
    __syncthreads();
    if (t < 4){
      unsigned kr = krem[t], cum = 0, b = 0;
      for (; b < 256; b++){
        unsigned c2 = fh[t * 256 + b];
        if (kr < cum + c2) break;
        cum += c2;
      }
      sel32[t] |= b << shift;
      krem[t] = kr - cum;
      cnt[t] += cum;
    }
    if (t == 0) *done = 0;
  }
}

// ======== fused: boundary mark + certain-edge sums + a3 (one abuf pass) ========
__global__ __launch_bounds__(256) void k_marksums(const float* __restrict__ attn,
    const unsigned* __restrict__ sel32, unsigned* __restrict__ cbelow,
    unsigned* __restrict__ bcnt, unsigned* __restrict__ blist,
    u64* __restrict__ gsums, float* __restrict__ a3){
  int t = threadIdx.x;
  int i0 = blockIdx.x * 256 + t;
  int hh = t & 3;
  double thd = (double)__uint_as_float(sel32[hh]);
  double lo = thd * (1.0 - MARG), hi = thd * (1.0 + MARG);
  double al = 0.0, ag = 0.0;
  unsigned below = 0;
  const int total = N_EDGES * 4;
  for (int i = i0; i < total; i += gridDim.x * 256){
    float vf = attn[i];
    double v = (double)vf;
    if (v < lo){ al += v; below++; a3[i] = 0.f; }
    else if (v > hi){ ag += v; a3[i] = vf; }
    else {
      unsigned p = atomicAdd(bcnt, 1u);
      if (p < BCAP) blist[p] = (unsigned)i;
      a3[i] = 0.f;                         // boundary: fixed by k_bfr
    }
  }
  long long ql = llrint(al * SC_FX);
  long long qg = llrint(ag * SC_FX);
  #pragma unroll
  for (int m = 4; m < 64; m <<= 1){
    ql += __shfl_xor(ql, m);
    qg += __shfl_xor(qg, m);
    below += __shfl_xor(below, m);
  }
  __shared__ long long sl[16], sg[16];
  __shared__ unsigned sb[16];
  int wv = t >> 6;
  if ((t & 63) < 4){ sl[wv * 4 + hh] = ql; sg[wv * 4 + hh] = qg; sb[wv * 4 + hh] = below; }
  __syncthreads();
  if (t < 4){
    long long a = sl[t] + sl[4 + t] + sl[8 + t] + sl[12 + t];
    long long b = sg[t] + sg[4 + t] + sg[8 + t] + sg[12 + t];
    unsigned bl = sb[t] + sb[4 + t] + sb[8 + t] + sb[12 + t];
    if (a) atomicAdd(&gsums[t],     (u64)a);
    if (b) atomicAdd(&gsums[4 + t], (u64)b);
    if (bl) atomicAdd(&cbelow[t], bl);
  }
}

// ======== exact f64 boundary refine: block/entry, LDS-staged weights ========
__global__ __launch_bounds__(256) void k_brefine(const float* __restrict__ h,
    const float* __restrict__ fcT, const float* __restrict__ fqT,
    const int* __restrict__ src, const int* __restrict__ dst,
    const unsigned* __restrict__ A, const unsigned* __restrict__ eidx,
    const unsigned* __restrict__ blist, const unsigned* __restrict__ bcnt,
    double* __restrict__ bval){
  __shared__ float wqs[32][257];
  __shared__ double cs[32];
  __shared__ double la[DEG_CAP];
  int tid = threadIdx.x;
  int wv = tid >> 6;
  int l = tid & 63;
  int j = l & 31;
  int khalf = l >> 5;
  unsigned nb = *bcnt; if (nb > BCAP) nb = BCAP;
  for (unsigned idx = blockIdx.x; idx < nb; idx += gridDim.x){
    unsigned slot = blist[idx];
    unsigned kslot = slot >> 2;
    int hh = slot & 3;
    int d = dst[eidx[kslot]];
    unsigned k0 = d ? A[d - 1] : 0u, k1 = A[d];
    unsigned deg = k1 - k0;
    {
      int col = tid >> 3, seg = tid & 7;
      const float* gsrc = fqT + (size_t)(hh * 32 + col) * 256 + seg * 32;
      #pragma unroll
      for (int r = 0; r < 8; r++){
        float4 v = *(const float4*)&gsrc[r * 4];
        float* wdst = &wqs[col][seg * 32 + r * 4];
        wdst[0] = v.x; wdst[1] = v.y; wdst[2] = v.z; wdst[3] = v.w;
      }
    }
    __syncthreads();
    if (wv == 0){
      const float* hd = h + (size_t)d * 256 + khalf * 128;
      const float* wc = fcT + (size_t)(hh * 32 + j) * 256 + khalf * 128;
      double c0 = 0.0, c1 = 0.0, c2 = 0.0, c3 = 0.0;
      #pragma unroll 8
      for (int i = 0; i < 128; i += 4){
        float4 hv = *(const float4*)&hd[i];
        float4 w2 = *(const float4*)&wc[i];
        c0 = fma((double)hv.x, (double)w2.x, c0);
        c1 = fma((double)hv.y, (double)w2.y, c1);
        c2 = fma((double)hv.z, (double)w2.z, c2);
        c3 = fma((double)hv.w, (double)w2.w, c3);
      }
      double c = (c0 + c1) + (c2 + c3);
      c += __shfl_xor(c, 32);
      if (l < 32) cs[l] = c;
    }
    __syncthreads();
    double cj = cs[j];
    for (unsigned k = k0 + wv; k < k1; k += 4){
      int s = src[eidx[k]];
      const float* hs = h + (size_t)s * 256 + khalf * 128;
      const float* wr = &wqs[j][khalf * 128];
      float4 hv = *(const float4*)&hs[0];
      double q0 = 0.0, q1 = 0.0, q2 = 0.0, q3 = 0.0;
      #pragma unroll 4
      for (int i = 0; i < 128; i += 4){
        float4 cur = hv;
        if (i + 4 < 128) hv = *(const float4*)&hs[i + 4];
        q0 = fma((double)cur.x, (double)wr[i + 0], q0);
        q1 = fma((double)cur.y, (double)wr[i + 1], q1);
        q2 = fma((double)cur.z, (double)wr[i + 2], q2);
        q3 = fma((double)cur.w, (double)wr[i + 3], q3);
      }
      double q = (q0 + q1) + (q2 + q3);
      q += __shfl_xor(q, 32);
      double p = (q - cj) * cj;
      p += __shfl_xor(p, 1);
      p += __shfl_xor(p, 2);
      p += __shfl_xor(p, 4);
      p += __shfl_xor(p, 8);
      p += __shfl_xor(p, 16);
      double a = (p > 0.0) ? p : expm1(p);
      if (l == 0) la[k - k0] = a;
    }
    __syncthreads();
    if (wv == 0){
      double m = -1.0e300;
      for (unsigned kk = l; kk < deg; kk += 64) m = fmax(m, la[kk]);
      #pragma unroll
      for (int msk = 1; msk < 64; msk <<= 1) m = fmax(m, __shfl_xor(m, msk));
      long long sfx = 0;
      for (unsigned kk = l; kk < deg; kk += 64)
        sfx += llrint(exp(la[kk] - m) * SC_FX);
      #pragma unroll
      for (int msk = 1; msk < 64; msk <<= 1) sfx += __shfl_xor(sfx, msk);
      if (l == 0){
        double sd = (double)sfx * (1.0 / SC_FX);
        bval[idx] = exp(la[kslot - k0] - m) / sd;
      }
    }
    __syncthreads();
  }
}

// ======== fused: f64 select + boundary finalize + ratio (1 block per head) ====
__global__ __launch_bounds__(256) void k_bfr(const double* __restrict__ bval,
    const unsigned* __restrict__ blist, const unsigned* __restrict__ bcnt,
    const unsigned* __restrict__ cbelow, const u64* __restrict__ gsums,
    float* __restrict__ a3, double* __restrict__ trd){
  __shared__ unsigned lh[256];
  __shared__ u64 s_sel;
  __shared__ unsigned s_kr, s_cnt;
  __shared__ long long sl[4], sg[4];
  int hsel = blockIdx.x;
  int t = threadIdx.x;
  unsigned nb = *bcnt; if (nb > BCAP) nb = BCAP;
  if (t == 0){ s_sel = 0; s_kr = RANK0 - cbelow[hsel]; s_cnt = 0; }
  __syncthreads();
  for (int p = 0; p < 8; p++){
    int shift = 56 - 8 * p;
    u64 maskHi = (p == 0) ? 0ull : (~0ull) << (64 - 8 * p);
    lh[t] = 0;
    __syncthreads();
    u64 sel = s_sel;
    for (unsigned i = t; i < nb; i += 256){
      if ((int)(blist[i] & 3) == hsel){
        u64 u = (u64)__double_as_longlong(bval[i]);
        if ((u & maskHi) == sel) atomicAdd(&lh[(unsigned)((u >> shift) & 255u)], 1u);
      }
    }
    __syncthreads();
    if (t == 0){
      unsigned kr = s_kr, cum = 0, b = 0;
      for (; b < 256; b++){
        unsigned c2 = lh[b];
        if (kr < cum + c2) break;
        cum += c2;
      }
      s_sel |= ((u64)b) << shift;
      s_kr = kr - cum;
      s_cnt += cum;
    }
    __syncthreads();
  }
  double thd = __longlong_as_double((long long)s_sel);
  // finalize boundary entries of this head + accumulate boundary sums
  long long ql = 0, qg = 0;
  for (unsigned idx = t; idx < nb; idx += 256){
    unsigned slot = blist[idx];
    if ((int)(slot & 3) == hsel){
      double v = bval[idx];
      bool kept = (v >= thd);
      a3[slot] = kept ? (float)v : 0.f;
      long long q = llrint(v * SC_FX);
      if (kept) qg += q; else ql += q;
    }
  }
  #pragma unroll
  for (int msk = 1; msk < 64; msk <<= 1){
    ql += __shfl_xor(ql, msk);
    qg += __shfl_xor(qg, msk);
  }
  int wv = t >> 6;
  if ((t & 63) == 0){ sl[wv] = ql; sg[wv] = qg; }
  __syncthreads();
  if (t == 0){
    long long bl = sl[0] + sl[1] + sl[2] + sl[3];
    long long bg = sg[0] + sg[1] + sg[2] + sg[3];
    double sless = (double)((long long)gsums[hsel]     + bl) * (1.0 / SC_FX);
    double sge   = (double)((long long)gsums[4 + hsel] + bg) * (1.0 / SC_FX);
    unsigned cl = cbelow[hsel] + s_cnt;
    double topk = sless + (double)(LS - (int)cl) * thd;
    trd[hsel] = thd;
    trd[4 + hsel] = (sge + topk) / sge;
  }
}

// ======== CSR gather-scatter + fused head-mean: 2 dst per wave, float4 ========
__global__ __launch_bounds__(256) void k_scatter2(const float* __restrict__ fcq,
    const int* __restrict__ src, const unsigned* __restrict__ A,
    const unsigned* __restrict__ eidx, const float* __restrict__ a3,
    const double* __restrict__ trd, float* __restrict__ out){
  int tid = threadIdx.x;
  int wv = tid >> 6;
  int l = tid & 63;
  int half = l >> 5;
  int ll = l & 31;
  int d = blockIdx.x * 8 + wv * 2 + half;
  if (d >= N_NODES) return;     // tail: whole half-wave exits together (uniform d)
  int hh = ll >> 3;
  double ratio = trd[4 + hh];
  unsigned k0 = d ? A[d - 1] : 0u, k1 = A[d];
  long long acc0 = 0, acc1 = 0, acc2 = 0, acc3 = 0;
  float wn = (k0 < k1) ? a3[(size_t)k0 * 4 + hh] : 0.f;
  unsigned en = (k0 < k1) ? eidx[k0] : 0u;
  for (unsigned k = k0; k < k1; k++){
    float w = wn;
    unsigned e = en;
    if (k + 1 < k1){ wn = a3[(size_t)(k + 1) * 4 + hh]; en = eidx[k + 1]; }
    unsigned hb = (unsigned)(__ballot(w != 0.f) >> (half * 32));
    if (hb == 0u) continue;     // all 4 heads dropped (~71% of edges)
    if (w != 0.f){
      int s = src[e];
      float4 f = *(const float4*)&fcq[(size_t)s * 384 + ll * 4];
      double a3r = (double)w * ratio;
      acc0 += llrint(a3r * (double)f.x * SC_FX);
      acc1 += llrint(a3r * (double)f.y * SC_FX);
      acc2 += llrint(a3r * (double)f.z * SC_FX);
      acc3 += llrint(a3r * (double)f.w * SC_FX);
    }
  }
  float* p = &out[(size_t)d * OUTC + ll * 4];
  p[0] = (float)((double)acc0 * (1.0 / SC_FX));
  p[1] = (float)((double)acc1 * (1.0 / SC_FX));
  p[2] = (float)((double)acc2 * (1.0 / SC_FX));
  p[3] = (float)((double)acc3 * (1.0 / SC_FX));
  const float* pf = &fcq[(size_t)d * 384];
  out[(size_t)d * OUTC + 128 + ll] = 0.25f * (pf[ll] + pf[32 + ll] + pf[64 + ll] + pf[96 + ll]);
}

extern "C" void kernel_launch(void* const* d_in, const int* in_sizes, int n_in,
                              void* d_out, int out_size, void* d_ws, size_t ws_size,
                              hipStream_t stream){
  const float* h  = (const float*)d_in[0];
  const float* Wl = (const float*)d_in[1];
  const float* fc = (const float*)d_in[2];
  const float* fq = (const float*)d_in[3];
  const int* src  = (const int*)d_in[4];
  const int* dst  = (const int*)d_in[5];
  float* out = (float*)d_out;

  char* ws = (char*)d_ws;
  float*    fcq  = (float*)(ws);                   // 76,800,000
  unsigned* A    = (unsigned*)(ws + 76800000);     // 200,004 (pad to 77,000,064)
  unsigned* eidx = (unsigned*)(ws + 77000064);     // 3,200,000
  float*    a3   = (float*)(ws + 80200064);        // 12,800,000
  unsigned* hist = (unsigned*)(ws + 93000064);     // 4,096
  unsigned* sel32  = (unsigned*)(ws + 93004160);   // 16
  unsigned* krem   = (unsigned*)(ws + 93004176);   // 16
  unsigned* cnt    = (unsigned*)(ws + 93004192);   // 16
  unsigned* done   = (unsigned*)(ws + 93004208);   // 16
  unsigned* ccnt   = (unsigned*)(ws + 93004224);   // 16
  unsigned* cbelow = (unsigned*)(ws + 93004240);   // 16
  unsigned* bcnt   = (unsigned*)(ws + 93004256);   // 16
  u64*      gsums  = (u64*)(ws + 93004288);        // 64
  double*   trd    = (double*)(ws + 93004416);     // 64
  unsigned* blist  = (unsigned*)(ws + 93008896);   // 262,144 (BCAP*4)
  double*   bval   = (double*)(ws + 93271040);     // 524,288 (BCAP*8)
  float*    fcT    = (float*)(ws + 93795328);      // 131,072
  float*    fqT    = (float*)(ws + 93926400);      // 131,072

  // scratch inside d_out (32 MB): both fully dead before scatter2 writes
  float* abuf = (float*)d_out;                     // 12.8 MB attn32
  float* cand = (float*)((char*)d_out + 12800000); // 12.8 MB select candidates

  // fused init (zero A/hist, scalars, fc/fq transpose)
  k_init2<<<256, 256, 0, stream>>>(A, hist, sel32, krem, cnt, done, ccnt,
                                   cbelow, bcnt, gsums, fc, fq, fcT, fqT);

  // CSR
  k_deg<<<(N_EDGES + 255) / 256, 256, 0, stream>>>(dst, A);
  k_scan<<<1, 1024, 0, stream>>>(A);
  k_fill<<<(N_EDGES + 255) / 256, 256, 0, stream>>>(dst, A, eidx);

  // single f32 GEMM -> [ft | c | q]
  dim3 gg((N_NODES + BM - 1) / BM, 3);
  k_gemm384<<<gg, 256, 0, stream>>>(h, Wl, fc, fq, fcq);

  // f32 fused edge logits + softmax (2 dst per wave)
  k_softedge32<<<(N_NODES + 7) / 8, 256, 0, stream>>>(fcq, src, A, eidx, abuf);

  // exact f32 rank select: 2 global passes, compact, 2 finish passes
  k_hp32<<<1024, 256, 0, stream>>>(abuf, sel32, krem, cnt, hist, done, 0u, 24);
  k_hp32<<<1024, 256, 0, stream>>>(abuf, sel32, krem, cnt, hist, done, 0xFF000000u, 16);
  k_compact32<<<1024, 256, 0, stream>>>(abuf, sel32, ccnt, cand);
  k_fin32<<<256, 256, 0, stream>>>(cand, ccnt, sel32, krem, cnt, hist, done, 8);
  k_fin32<<<256, 256, 0, stream>>>(cand, ccnt, sel32, krem, cnt, hist, done, 0);

  // fused: boundary mark + certain sums + a3 (one pass)
  k_marksums<<<2048, 256, 0, stream>>>(abuf, sel32, cbelow, bcnt, blist, gsums, a3);

  // boundary: refine in f64; fused select+finalize+ratio (1 block/head)
  k_brefine<<<2048, 256, 0, stream>>>(h, fcT, fqT, src, dst, A, eidx, blist, bcnt, bval);
  k_bfr<<<4, 256, 0, stream>>>(bval, blist, bcnt, cbelow, gsums, a3, trd);

  // output (scatter + fused head-mean), 2 dst per wave
  k_scatter2<<<(N_NODES + 7) / 8, 256, 0, stream>>>(fcq, src, A, eidx, a3, trd, out);
}